// Round 9
// baseline (402.372 us; speedup 1.0000x reference)
//
#include <hip/hip_runtime.h>
#include <hip/hip_fp16.h>
#include <math.h>

#define N_NODES 50000
#define EDGES   1250000
#define DIM     64
#define NLAYER  3
#define BATCH   4096

#define NBUCK 196   // coarse buckets: bucket = row >> 8 (256 rows each)
#define RPB   256   // rows per bucket
#define NABLK 128   // phase-A blocks

typedef unsigned int uint32;

static __device__ __forceinline__ ushort f2h(float f) {
    return __half_as_ushort(__float2half(f));
}
static __device__ __forceinline__ float h2f(ushort u) {
    return __half2float(__ushort_as_half(u));
}

// ---------------- Phase A1: per-block bucket histogram (+ global bucket sums) ----

__global__ __launch_bounds__(256) void bucket_hist_kernel(const int* __restrict__ rows,
                                                          int* __restrict__ bhist,
                                                          int* __restrict__ bucket_sums) {
    __shared__ int h[NBUCK];
    for (int i = threadIdx.x; i < NBUCK; i += 256) h[i] = 0;
    __syncthreads();
    int per = (EDGES + NABLK - 1) / NABLK;
    int e0 = blockIdx.x * per;
    int e1 = min(e0 + per, EDGES);
    for (int e = e0 + threadIdx.x; e < e1; e += 256)
        atomicAdd(&h[rows[e] >> 8], 1);
    __syncthreads();
    for (int i = threadIdx.x; i < NBUCK; i += 256) {
        bhist[blockIdx.x * NBUCK + i] = h[i];      // [block][bucket] for coalesced prefix
        atomicAdd(&bucket_sums[i], h[i]);
    }
}

// ---------------- prep: bucket scan + W transpose + f2h(emb) + dots layer 0 ----
// block 0: scan; blocks [1,49): transpose; [49,3174): f2h; [3174,4198): dots0

#define PB_TRANS 1
#define PB_F2H   49
#define PB_DOTS  3174
#define PB_TOTAL 4198

__global__ __launch_bounds__(256) void prep_kernel(const float* __restrict__ emb,
                                                   const float* __restrict__ w1,
                                                   const float* __restrict__ w2,
                                                   const int* __restrict__ bucket_sums,
                                                   int* __restrict__ bucket_base,
                                                   float* __restrict__ w1T,
                                                   float* __restrict__ w2T,
                                                   ushort* __restrict__ xh,
                                                   const int* __restrict__ user,
                                                   const int* __restrict__ pos,
                                                   const int* __restrict__ neg,
                                                   float* __restrict__ dots) {
    int blk = blockIdx.x;
    int tid = threadIdx.x;
    if (blk == 0) {
        // exclusive scan of bucket_sums[196] -> bucket_base[0..196]
        __shared__ int lv[256];
        __shared__ int wred[4];
        int v = (tid < NBUCK) ? bucket_sums[tid] : 0;
        int lane = tid & 63, wid = tid >> 6;
        int s = v;
#pragma unroll
        for (int off = 1; off < 64; off <<= 1) {
            int t = __shfl_up(s, off);
            if (lane >= off) s += t;
        }
        if (lane == 63) wred[wid] = s;
        __syncthreads();
        if (tid == 0) {
            int a = 0;
#pragma unroll
            for (int i = 0; i < 4; ++i) { int t = wred[i]; wred[i] = a; a += t; }
        }
        __syncthreads();
        int excl = wred[wid] + s - v;
        if (tid < NBUCK) bucket_base[tid] = excl;
        if (tid == 0) bucket_base[NBUCK] = EDGES;
        (void)lv;
    } else if (blk < PB_F2H) {
        int i = (blk - PB_TRANS) * 256 + tid;   // < 12288
        int l = i >> 12, r = i & 4095;
        int d = r >> 6, j = r & 63;
        w1T[l * 4096 + j * 64 + d] = w1[i];
        w2T[l * 4096 + j * 64 + d] = w2[i];
    } else if (blk < PB_DOTS) {
        int i = (blk - PB_F2H) * 256 + tid;     // < 800000
        if (i < N_NODES * DIM / 4) {
            float4 v = ((const float4*)emb)[i];
            ushort4 h;
            h.x = f2h(v.x); h.y = f2h(v.y); h.z = f2h(v.z); h.w = f2h(v.w);
            ((ushort4*)xh)[i] = h;
        }
    } else {
        int lane = tid & 63;
        int i = (blk - PB_DOTS) * 4 + (tid >> 6);
        int ui = user[i], pi = pos[i], ni = neg[i];
        float u = emb[(size_t)ui * DIM + lane];
        float p = emb[(size_t)pi * DIM + lane];
        float n = emb[(size_t)ni * DIM + lane];
        float v = u * (p - n);
#pragma unroll
        for (int off = 32; off; off >>= 1) v += __shfl_xor(v, off);
        if (lane == 0) dots[i] = v;
    }
}

// ---------------- Phase A3: scatter edges into bucket staging ----------------
// per-block cursors = bucket_base + prefix of bhist columns (coalesced reads)

__global__ __launch_bounds__(256) void bucket_scatter_kernel(const int* __restrict__ rows,
                                                             const int* __restrict__ cols,
                                                             const float* __restrict__ vals,
                                                             const int* __restrict__ bhist,
                                                             const int* __restrict__ bucket_base,
                                                             int2* __restrict__ staging) {
    __shared__ int cur[NBUCK];
    for (int t = threadIdx.x; t < NBUCK; t += 256) {
        int s = bucket_base[t];
        for (int k = 0; k < blockIdx.x; ++k) s += bhist[k * NBUCK + t];
        cur[t] = s;
    }
    __syncthreads();
    int per = (EDGES + NABLK - 1) / NABLK;
    int e0 = blockIdx.x * per;
    int e1 = min(e0 + per, EDGES);
    for (int e = e0 + threadIdx.x; e < e1; e += 256) {
        int r = rows[e];
        int p = atomicAdd(&cur[r >> 8], 1);
        staging[p] = make_int2(((r & 255) << 16) | cols[e], __float_as_int(vals[e]));
    }
}

// ---------------- Phase B: per-bucket row_ptr + final 4-byte CSR ----------------

__global__ __launch_bounds__(256) void csr_build_kernel(const int* __restrict__ bucket_base,
                                                        const int2* __restrict__ staging,
                                                        int* __restrict__ row_ptr,
                                                        uint32* __restrict__ csr) {
    __shared__ int rcur[RPB];
    __shared__ int wred[4];
    int b = blockIdx.x;
    int base = bucket_base[b];
    int end = bucket_base[b + 1];
    int tid = threadIdx.x;
    rcur[tid] = 0;
    __syncthreads();
    for (int p = base + tid; p < end; p += 256)
        atomicAdd(&rcur[staging[p].x >> 16], 1);
    __syncthreads();
    int lane = tid & 63, wid = tid >> 6;
    int v = rcur[tid];
    int s = v;
#pragma unroll
    for (int off = 1; off < 64; off <<= 1) {
        int t = __shfl_up(s, off);
        if (lane >= off) s += t;
    }
    if (lane == 63) wred[wid] = s;
    __syncthreads();
    if (tid == 0) {
        int a = 0;
#pragma unroll
        for (int i = 0; i < 4; ++i) { int t = wred[i]; wred[i] = a; a += t; }
    }
    __syncthreads();
    int excl = wred[wid] + s - v;
    __syncthreads();
    rcur[tid] = base + excl;
    int row = b * RPB + tid;
    if (row < N_NODES) row_ptr[row] = base + excl;
    if (b == NBUCK - 1 && tid == 0) row_ptr[N_NODES] = EDGES;
    __syncthreads();
    for (int p = base + tid; p < end; p += 256) {
        int2 e = staging[p];
        int pos = atomicAdd(&rcur[e.x >> 16], 1);
        csr[pos] = ((uint32)(e.x & 0xFFFF) << 16) | (uint32)f2h(__int_as_float(e.y));
    }
}

// ---------------- Fused layer: spmm (into LDS) + dense ----------------
// Block owns 64 nodes. Phase 1: each of 4 waves computes agg for 16 rows
// (fp16 gather from xh_in, f32 accumulate) writing into swizzled xs tile.
// Phase 2: stage x (xs += x, xc = x) then GEMM-tiled dense; epilogue
// recovers agg = xs - xc, writes y (f32) and yh (fp16 mirror for next layer).

__global__ __launch_bounds__(256) void layer_kernel(const int* __restrict__ row_ptr,
                                                    const uint32* __restrict__ csr,
                                                    const ushort* __restrict__ xh_in,
                                                    const float* __restrict__ x,
                                                    const float* __restrict__ w1T,
                                                    const float* __restrict__ w2T,
                                                    const float* __restrict__ b1,
                                                    const float* __restrict__ b2,
                                                    float* __restrict__ y,
                                                    ushort* __restrict__ yh) {
    __shared__ float xs[64 * 64];
    __shared__ float xc[64 * 64];
    __shared__ float w1s[64 * 64];
    __shared__ float w2s[64 * 64];

    int tid = threadIdx.x;
    int lane = tid & 63, w = tid >> 6;
    int n0 = blockIdx.x * 64;

    // stage W (no dependency on phase 1; covered by the phase-boundary sync)
    for (int f = tid; f < 1024; f += 256) {
        ((float4*)w1s)[f] = ((const float4*)w1T)[f];
        ((float4*)w2s)[f] = ((const float4*)w2T)[f];
    }

    // ---- phase 1: spmm for this block's 64 nodes, results into xs ----
    {
        int g = lane >> 4;
        int sl = lane & 15;
        for (int i = 0; i < 16; ++i) {
            int nl = w * 16 + i;
            int row = n0 + nl;
            float4 acc = make_float4(0.f, 0.f, 0.f, 0.f);
            if (row < N_NODES) {
                int p0 = row_ptr[row], p1 = row_ptr[row + 1];
                int p = p0;
                for (; p + 16 <= p1; p += 16) {
                    uint32 a = csr[p + g];
                    uint32 b = csr[p + 4 + g];
                    uint32 c = csr[p + 8 + g];
                    uint32 d = csr[p + 12 + g];
                    ushort4 xa = *(const ushort4*)(xh_in + (size_t)(a >> 16) * DIM + sl * 4);
                    ushort4 xb = *(const ushort4*)(xh_in + (size_t)(b >> 16) * DIM + sl * 4);
                    ushort4 xcv = *(const ushort4*)(xh_in + (size_t)(c >> 16) * DIM + sl * 4);
                    ushort4 xd = *(const ushort4*)(xh_in + (size_t)(d >> 16) * DIM + sl * 4);
                    float va = h2f((ushort)(a & 0xFFFF)), vb = h2f((ushort)(b & 0xFFFF));
                    float vc = h2f((ushort)(c & 0xFFFF)), vd = h2f((ushort)(d & 0xFFFF));
                    acc.x += va * h2f(xa.x); acc.y += va * h2f(xa.y); acc.z += va * h2f(xa.z); acc.w += va * h2f(xa.w);
                    acc.x += vb * h2f(xb.x); acc.y += vb * h2f(xb.y); acc.z += vb * h2f(xb.z); acc.w += vb * h2f(xb.w);
                    acc.x += vc * h2f(xcv.x); acc.y += vc * h2f(xcv.y); acc.z += vc * h2f(xcv.z); acc.w += vc * h2f(xcv.w);
                    acc.x += vd * h2f(xd.x); acc.y += vd * h2f(xd.y); acc.z += vd * h2f(xd.z); acc.w += vd * h2f(xd.w);
                }
                for (; p + 8 <= p1; p += 8) {
                    uint32 a = csr[p + g];
                    uint32 b = csr[p + 4 + g];
                    ushort4 xa = *(const ushort4*)(xh_in + (size_t)(a >> 16) * DIM + sl * 4);
                    ushort4 xb = *(const ushort4*)(xh_in + (size_t)(b >> 16) * DIM + sl * 4);
                    float va = h2f((ushort)(a & 0xFFFF)), vb = h2f((ushort)(b & 0xFFFF));
                    acc.x += va * h2f(xa.x); acc.y += va * h2f(xa.y); acc.z += va * h2f(xa.z); acc.w += va * h2f(xa.w);
                    acc.x += vb * h2f(xb.x); acc.y += vb * h2f(xb.y); acc.z += vb * h2f(xb.z); acc.w += vb * h2f(xb.w);
                }
                for (; p < p1; p += 4) {
                    int pe = p + g;
                    if (pe < p1) {
                        uint32 a = csr[pe];
                        ushort4 xa = *(const ushort4*)(xh_in + (size_t)(a >> 16) * DIM + sl * 4);
                        float va = h2f((ushort)(a & 0xFFFF));
                        acc.x += va * h2f(xa.x); acc.y += va * h2f(xa.y); acc.z += va * h2f(xa.z); acc.w += va * h2f(xa.w);
                    }
                }
#pragma unroll
                for (int m = 16; m <= 32; m <<= 1) {
                    acc.x += __shfl_xor(acc.x, m);
                    acc.y += __shfl_xor(acc.y, m);
                    acc.z += __shfl_xor(acc.z, m);
                    acc.w += __shfl_xor(acc.w, m);
                }
            }
            if (lane < 16) {
                float av[4] = {acc.x, acc.y, acc.z, acc.w};
#pragma unroll
                for (int dj = 0; dj < 4; ++dj) {
                    int j = sl * 4 + dj;
                    xs[j * 64 + (nl ^ ((j & 7) << 2))] = av[dj];
                }
            }
        }
    }
    __syncthreads();

    // ---- phase 2: stage x (xs += x, xc = x) ----
    {
        int q = tid & 15;
#pragma unroll
        for (int nn = 0; nn < 4; ++nn) {
            int nl = (tid >> 4) + nn * 16;
            int node = n0 + nl;
            int ncl = (node < N_NODES) ? node : (N_NODES - 1);
            const float* xrow = x + (size_t)ncl * DIM;
#pragma unroll
            for (int k = 0; k < 4; ++k) {
                int j = q + 16 * k;
                float xv = xrow[j];
                int idx = j * 64 + (nl ^ ((j & 7) << 2));
                xs[idx] += xv;
                xc[idx] = xv;
            }
        }
    }
    __syncthreads();

    // ---- phase 2b: GEMM-tiled dense ----
    int wn = w >> 1, wd = w & 1;
    int r = lane >> 3, c = lane & 7;
    int nb = wn * 32 + r * 4;
    int db = wd * 32 + c * 4;

    float s1[16] = {};
    float s2[16] = {};

#pragma unroll 2
    for (int j = 0; j < 64; ++j) {
        int swz = (j & 7) << 2;
        float4 as4 = *(const float4*)&xs[j * 64 + (nb ^ swz)];
        float4 ac4 = *(const float4*)&xc[j * 64 + (nb ^ swz)];
        float4 bw1 = *(const float4*)&w1s[j * 64 + db];
        float4 bw2 = *(const float4*)&w2s[j * 64 + db];
        float asv[4] = {as4.x, as4.y, as4.z, as4.w};
        float acv[4] = {ac4.x, ac4.y, ac4.z, ac4.w};
        float w1v[4] = {bw1.x, bw1.y, bw1.z, bw1.w};
        float w2v[4] = {bw2.x, bw2.y, bw2.z, bw2.w};
#pragma unroll
        for (int i = 0; i < 4; ++i)
#pragma unroll
            for (int k = 0; k < 4; ++k) {
                s1[i * 4 + k] += asv[i] * w1v[k];
                s2[i * 4 + k] += acv[i] * w2v[k];
            }
    }

    float4 bv1 = *(const float4*)&b1[db];
    float4 bv2 = *(const float4*)&b2[db];
    float bb1[4] = {bv1.x, bv1.y, bv1.z, bv1.w};
    float bb2[4] = {bv2.x, bv2.y, bv2.z, bv2.w};

#pragma unroll
    for (int i = 0; i < 4; ++i) {
        int nl = nb + i;
        int node = n0 + nl;
        float4 o;
        float ov[4];
#pragma unroll
        for (int k = 0; k < 4; ++k) {
            int d = db + k;
            int idx = d * 64 + (nl ^ ((d & 7) << 2));
            float ag = xs[idx] - xc[idx];
            float t = s1[i * 4 + k] + bb1[k] + ag * (s2[i * 4 + k] + bb2[k]);
            ov[k] = (t > 0.f) ? t : 0.01f * t;
        }
        o.x = ov[0]; o.y = ov[1]; o.z = ov[2]; o.w = ov[3];
        if (node < N_NODES) {
            *(float4*)&y[(size_t)node * DIM + db] = o;
            ushort4 ho;
            ho.x = f2h(ov[0]); ho.y = f2h(ov[1]); ho.z = f2h(ov[2]); ho.w = f2h(ov[3]);
            *(ushort4*)&yh[(size_t)node * DIM + db] = ho;
        }
    }
}

// ---------------- Per-layer dot contributions (layers 1,2) ----------------

__global__ __launch_bounds__(256) void gather_dots_kernel(const float* __restrict__ x,
                                                          const int* __restrict__ user,
                                                          const int* __restrict__ pos,
                                                          const int* __restrict__ neg,
                                                          float* __restrict__ dst) {
    int lane = threadIdx.x & 63;
    int i = blockIdx.x * 4 + (threadIdx.x >> 6);
    int ui = user[i], pi = pos[i], ni = neg[i];
    float u = x[(size_t)ui * DIM + lane];
    float p = x[(size_t)pi * DIM + lane];
    float n = x[(size_t)ni * DIM + lane];
    float v = u * (p - n);
#pragma unroll
    for (int off = 32; off; off >>= 1) v += __shfl_xor(v, off);
    if (lane == 0) dst[i] = v;
}

// ---------------- dots layer 3 + loss (atomic accumulate) ----------------

__global__ __launch_bounds__(256) void dots_loss_kernel(const float* __restrict__ x,
                                                        const int* __restrict__ user,
                                                        const int* __restrict__ pos,
                                                        const int* __restrict__ neg,
                                                        const float* __restrict__ dots,
                                                        float* __restrict__ out) {
    __shared__ float part[4];
    int tid = threadIdx.x;
    int lane = tid & 63;
    int i = blockIdx.x * 4 + (tid >> 6);
    int ui = user[i], pi = pos[i], ni = neg[i];
    float u = x[(size_t)ui * DIM + lane];
    float p = x[(size_t)pi * DIM + lane];
    float n = x[(size_t)ni * DIM + lane];
    float v = u * (p - n);
#pragma unroll
    for (int off = 32; off; off >>= 1) v += __shfl_xor(v, off);
    if (lane == 0) {
        float d = dots[i] + dots[BATCH + i] + dots[2 * BATCH + i] + v;
        part[tid >> 6] = fmaxf(-d, 0.f) + log1pf(expf(-fabsf(d)));
    }
    __syncthreads();
    if (tid == 0) atomicAdd(out, part[0] + part[1] + part[2] + part[3]);
}

// ---------------- Launch ----------------

extern "C" void kernel_launch(void* const* d_in, const int* in_sizes, int n_in,
                              void* d_out, int out_size, void* d_ws, size_t ws_size,
                              hipStream_t stream) {
    const float* emb  = (const float*)d_in[0];
    const float* w1_w = (const float*)d_in[1];
    const float* w1_b = (const float*)d_in[2];
    const float* w2_w = (const float*)d_in[3];
    const float* w2_b = (const float*)d_in[4];
    const float* vals = (const float*)d_in[5];
    const int* rows = (const int*)d_in[6];
    const int* cols = (const int*)d_in[7];
    const int* user = (const int*)d_in[8];
    const int* pos  = (const int*)d_in[9];
    const int* neg  = (const int*)d_in[10];
    float* out = (float*)d_out;

    char* w = (char*)d_ws;
    float* bufA = (float*)w;  w += (size_t)N_NODES * DIM * 4;   // also CSR staging
    float* bufB = (float*)w;  w += (size_t)N_NODES * DIM * 4;
    int* row_ptr = (int*)w;   w += (((size_t)(N_NODES + 1) * 4) + 255) / 256 * 256;
    uint32* csr  = (uint32*)w; w += (size_t)EDGES * 4;
    int* bhist   = (int*)w;   w += (size_t)NABLK * NBUCK * 4;
    int* bucket_sums = (int*)w; w += 256 * 4;
    int* bucket_base = (int*)w; w += 256 * 4;
    float* dots  = (float*)w; w += (size_t)3 * BATCH * 4;
    float* w1T   = (float*)w; w += (size_t)NLAYER * DIM * DIM * 4;
    float* w2T   = (float*)w; w += (size_t)NLAYER * DIM * DIM * 4;
    ushort* xhA  = (ushort*)w; w += (size_t)N_NODES * DIM * 2;
    ushort* xhB  = (ushort*)w; w += (size_t)N_NODES * DIM * 2;

    int2* staging = (int2*)bufA;   // consumed by csr_build before layer 1 writes bufA

    hipMemsetAsync(bucket_sums, 0, NBUCK * 4, stream);
    hipMemsetAsync(out, 0, 4, stream);

    bucket_hist_kernel<<<NABLK, 256, 0, stream>>>(rows, bhist, bucket_sums);
    prep_kernel<<<PB_TOTAL, 256, 0, stream>>>(emb, w1_w, w2_w, bucket_sums, bucket_base,
                                              w1T, w2T, xhA, user, pos, neg, dots);
    bucket_scatter_kernel<<<NABLK, 256, 0, stream>>>(rows, cols, vals, bhist, bucket_base, staging);
    csr_build_kernel<<<NBUCK, 256, 0, stream>>>(bucket_base, staging, row_ptr, csr);

    const int NLB = (N_NODES + 63) / 64;

    // layer 0: gather xhA(emb), x=emb -> y=bufA, yh=xhB
    layer_kernel<<<NLB, 256, 0, stream>>>(row_ptr, csr, xhA, emb,
                                          w1T + 0 * 4096, w2T + 0 * 4096,
                                          w1_b + 0 * DIM, w2_b + 0 * DIM, bufA, xhB);
    gather_dots_kernel<<<BATCH / 4, 256, 0, stream>>>(bufA, user, pos, neg, dots + BATCH);

    // layer 1: gather xhB, x=bufA -> y=bufB, yh=xhA
    layer_kernel<<<NLB, 256, 0, stream>>>(row_ptr, csr, xhB, bufA,
                                          w1T + 1 * 4096, w2T + 1 * 4096,
                                          w1_b + 1 * DIM, w2_b + 1 * DIM, bufB, xhA);
    gather_dots_kernel<<<BATCH / 4, 256, 0, stream>>>(bufB, user, pos, neg, dots + 2 * BATCH);

    // layer 2: gather xhA, x=bufB -> y=bufA, yh=xhB
    layer_kernel<<<NLB, 256, 0, stream>>>(row_ptr, csr, xhA, bufB,
                                          w1T + 2 * 4096, w2T + 2 * 4096,
                                          w1_b + 2 * DIM, w2_b + 2 * DIM, bufA, xhB);
    dots_loss_kernel<<<BATCH / 4, 256, 0, stream>>>(bufA, user, pos, neg, dots, out);
}

// Round 10
// 261.661 us; speedup vs baseline: 1.5378x; 1.5378x over previous
//
#include <hip/hip_runtime.h>
#include <hip/hip_fp16.h>
#include <math.h>

#define N_NODES 50000
#define EDGES   1250000
#define DIM     64
#define NLAYER  3
#define BATCH   4096

#define NBUCK 196   // coarse buckets: bucket = row >> 8 (256 rows each)
#define RPB   256   // rows per bucket
#define NABLK 128   // phase-A blocks

typedef unsigned int uint32;

static __device__ __forceinline__ ushort f2h(float f) {
    return __half_as_ushort(__float2half(f));
}
static __device__ __forceinline__ float h2f(ushort u) {
    return __half2float(__ushort_as_half(u));
}

// ---------------- Phase A1: per-block bucket histogram (+ global bucket sums) ----

__global__ __launch_bounds__(256) void bucket_hist_kernel(const int* __restrict__ rows,
                                                          int* __restrict__ bhist,
                                                          int* __restrict__ bucket_sums) {
    __shared__ int h[NBUCK];
    for (int i = threadIdx.x; i < NBUCK; i += 256) h[i] = 0;
    __syncthreads();
    int per = (EDGES + NABLK - 1) / NABLK;
    int e0 = blockIdx.x * per;
    int e1 = min(e0 + per, EDGES);
    for (int e = e0 + threadIdx.x; e < e1; e += 256)
        atomicAdd(&h[rows[e] >> 8], 1);
    __syncthreads();
    for (int i = threadIdx.x; i < NBUCK; i += 256) {
        bhist[blockIdx.x * NBUCK + i] = h[i];      // [block][bucket] for coalesced prefix
        atomicAdd(&bucket_sums[i], h[i]);
    }
}

// ---------------- prep: bucket scan + W transpose + f2h(emb) + dots layer 0 ----
// block 0: scan; blocks [1,49): transpose; [49,3174): f2h; [3174,4198): dots0

#define PB_TRANS 1
#define PB_F2H   49
#define PB_DOTS  3174
#define PB_TOTAL 4198

__global__ __launch_bounds__(256) void prep_kernel(const float* __restrict__ emb,
                                                   const float* __restrict__ w1,
                                                   const float* __restrict__ w2,
                                                   const int* __restrict__ bucket_sums,
                                                   int* __restrict__ bucket_base,
                                                   float* __restrict__ w1T,
                                                   float* __restrict__ w2T,
                                                   ushort* __restrict__ xh,
                                                   const int* __restrict__ user,
                                                   const int* __restrict__ pos,
                                                   const int* __restrict__ neg,
                                                   float* __restrict__ dots) {
    int blk = blockIdx.x;
    int tid = threadIdx.x;
    if (blk == 0) {
        __shared__ int wred[4];
        int v = (tid < NBUCK) ? bucket_sums[tid] : 0;
        int lane = tid & 63, wid = tid >> 6;
        int s = v;
#pragma unroll
        for (int off = 1; off < 64; off <<= 1) {
            int t = __shfl_up(s, off);
            if (lane >= off) s += t;
        }
        if (lane == 63) wred[wid] = s;
        __syncthreads();
        if (tid == 0) {
            int a = 0;
#pragma unroll
            for (int i = 0; i < 4; ++i) { int t = wred[i]; wred[i] = a; a += t; }
        }
        __syncthreads();
        int excl = wred[wid] + s - v;
        if (tid < NBUCK) bucket_base[tid] = excl;
        if (tid == 0) bucket_base[NBUCK] = EDGES;
    } else if (blk < PB_F2H) {
        int i = (blk - PB_TRANS) * 256 + tid;   // < 12288
        int l = i >> 12, r = i & 4095;
        int d = r >> 6, j = r & 63;
        w1T[l * 4096 + j * 64 + d] = w1[i];
        w2T[l * 4096 + j * 64 + d] = w2[i];
    } else if (blk < PB_DOTS) {
        int i = (blk - PB_F2H) * 256 + tid;     // < 800000
        if (i < N_NODES * DIM / 4) {
            float4 v = ((const float4*)emb)[i];
            ushort4 h;
            h.x = f2h(v.x); h.y = f2h(v.y); h.z = f2h(v.z); h.w = f2h(v.w);
            ((ushort4*)xh)[i] = h;
        }
    } else {
        int lane = tid & 63;
        int i = (blk - PB_DOTS) * 4 + (tid >> 6);
        int ui = user[i], pi = pos[i], ni = neg[i];
        float u = emb[(size_t)ui * DIM + lane];
        float p = emb[(size_t)pi * DIM + lane];
        float n = emb[(size_t)ni * DIM + lane];
        float v = u * (p - n);
#pragma unroll
        for (int off = 32; off; off >>= 1) v += __shfl_xor(v, off);
        if (lane == 0) dots[i] = v;
    }
}

// ---------------- Phase A3: scatter edges into bucket staging ----------------

__global__ __launch_bounds__(256) void bucket_scatter_kernel(const int* __restrict__ rows,
                                                             const int* __restrict__ cols,
                                                             const float* __restrict__ vals,
                                                             const int* __restrict__ bhist,
                                                             const int* __restrict__ bucket_base,
                                                             int2* __restrict__ staging) {
    __shared__ int cur[NBUCK];
    for (int t = threadIdx.x; t < NBUCK; t += 256) {
        int s = bucket_base[t];
        for (int k = 0; k < blockIdx.x; ++k) s += bhist[k * NBUCK + t];
        cur[t] = s;
    }
    __syncthreads();
    int per = (EDGES + NABLK - 1) / NABLK;
    int e0 = blockIdx.x * per;
    int e1 = min(e0 + per, EDGES);
    for (int e = e0 + threadIdx.x; e < e1; e += 256) {
        int r = rows[e];
        int p = atomicAdd(&cur[r >> 8], 1);
        staging[p] = make_int2(((r & 255) << 16) | cols[e], __float_as_int(vals[e]));
    }
}

// ---------------- Phase B: per-bucket row_ptr + final 4-byte CSR ----------------

__global__ __launch_bounds__(256) void csr_build_kernel(const int* __restrict__ bucket_base,
                                                        const int2* __restrict__ staging,
                                                        int* __restrict__ row_ptr,
                                                        uint32* __restrict__ csr) {
    __shared__ int rcur[RPB];
    __shared__ int wred[4];
    int b = blockIdx.x;
    int base = bucket_base[b];
    int end = bucket_base[b + 1];
    int tid = threadIdx.x;
    rcur[tid] = 0;
    __syncthreads();
    for (int p = base + tid; p < end; p += 256)
        atomicAdd(&rcur[staging[p].x >> 16], 1);
    __syncthreads();
    int lane = tid & 63, wid = tid >> 6;
    int v = rcur[tid];
    int s = v;
#pragma unroll
    for (int off = 1; off < 64; off <<= 1) {
        int t = __shfl_up(s, off);
        if (lane >= off) s += t;
    }
    if (lane == 63) wred[wid] = s;
    __syncthreads();
    if (tid == 0) {
        int a = 0;
#pragma unroll
        for (int i = 0; i < 4; ++i) { int t = wred[i]; wred[i] = a; a += t; }
    }
    __syncthreads();
    int excl = wred[wid] + s - v;
    __syncthreads();
    rcur[tid] = base + excl;
    int row = b * RPB + tid;
    if (row < N_NODES) row_ptr[row] = base + excl;
    if (b == NBUCK - 1 && tid == 0) row_ptr[N_NODES] = EDGES;
    __syncthreads();
    for (int p = base + tid; p < end; p += 256) {
        int2 e = staging[p];
        int pos = atomicAdd(&rcur[e.x >> 16], 1);
        csr[pos] = ((uint32)(e.x & 0xFFFF) << 16) | (uint32)f2h(__int_as_float(e.y));
    }
}

// ---------------- SpMM: fp16 gather, 4-byte CSR, one wave per row ----------------
// 4 edge-groups x 16 lanes x ushort4 (4 dims each), f32 accumulate

__global__ __launch_bounds__(256) void spmm_kernel(const int* __restrict__ row_ptr,
                                                   const uint32* __restrict__ csr,
                                                   const ushort* __restrict__ xh,
                                                   float* __restrict__ agg) {
    int lane = threadIdx.x & 63;
    int g = lane >> 4;
    int sl = lane & 15;
    int row = blockIdx.x * 4 + (threadIdx.x >> 6);
    if (row >= N_NODES) return;
    int p0 = row_ptr[row], p1 = row_ptr[row + 1];
    float4 acc = make_float4(0.f, 0.f, 0.f, 0.f);
    int p = p0;
    for (; p + 16 <= p1; p += 16) {
        uint32 a = csr[p + g];
        uint32 b = csr[p + 4 + g];
        uint32 c = csr[p + 8 + g];
        uint32 d = csr[p + 12 + g];
        ushort4 xa = *(const ushort4*)(xh + (size_t)(a >> 16) * DIM + sl * 4);
        ushort4 xb = *(const ushort4*)(xh + (size_t)(b >> 16) * DIM + sl * 4);
        ushort4 xc = *(const ushort4*)(xh + (size_t)(c >> 16) * DIM + sl * 4);
        ushort4 xd = *(const ushort4*)(xh + (size_t)(d >> 16) * DIM + sl * 4);
        float va = h2f((ushort)(a & 0xFFFF)), vb = h2f((ushort)(b & 0xFFFF));
        float vc = h2f((ushort)(c & 0xFFFF)), vd = h2f((ushort)(d & 0xFFFF));
        acc.x += va * h2f(xa.x); acc.y += va * h2f(xa.y); acc.z += va * h2f(xa.z); acc.w += va * h2f(xa.w);
        acc.x += vb * h2f(xb.x); acc.y += vb * h2f(xb.y); acc.z += vb * h2f(xb.z); acc.w += vb * h2f(xb.w);
        acc.x += vc * h2f(xc.x); acc.y += vc * h2f(xc.y); acc.z += vc * h2f(xc.z); acc.w += vc * h2f(xc.w);
        acc.x += vd * h2f(xd.x); acc.y += vd * h2f(xd.y); acc.z += vd * h2f(xd.z); acc.w += vd * h2f(xd.w);
    }
    for (; p + 8 <= p1; p += 8) {
        uint32 a = csr[p + g];
        uint32 b = csr[p + 4 + g];
        ushort4 xa = *(const ushort4*)(xh + (size_t)(a >> 16) * DIM + sl * 4);
        ushort4 xb = *(const ushort4*)(xh + (size_t)(b >> 16) * DIM + sl * 4);
        float va = h2f((ushort)(a & 0xFFFF)), vb = h2f((ushort)(b & 0xFFFF));
        acc.x += va * h2f(xa.x); acc.y += va * h2f(xa.y); acc.z += va * h2f(xa.z); acc.w += va * h2f(xa.w);
        acc.x += vb * h2f(xb.x); acc.y += vb * h2f(xb.y); acc.z += vb * h2f(xb.z); acc.w += vb * h2f(xb.w);
    }
    for (; p < p1; p += 4) {
        int pe = p + g;
        if (pe < p1) {
            uint32 a = csr[pe];
            ushort4 xa = *(const ushort4*)(xh + (size_t)(a >> 16) * DIM + sl * 4);
            float va = h2f((ushort)(a & 0xFFFF));
            acc.x += va * h2f(xa.x); acc.y += va * h2f(xa.y); acc.z += va * h2f(xa.z); acc.w += va * h2f(xa.w);
        }
    }
#pragma unroll
    for (int m = 16; m <= 32; m <<= 1) {
        acc.x += __shfl_xor(acc.x, m);
        acc.y += __shfl_xor(acc.y, m);
        acc.z += __shfl_xor(acc.z, m);
        acc.w += __shfl_xor(acc.w, m);
    }
    if (lane < 16) *(float4*)(agg + (size_t)row * DIM + lane * 4) = acc;
}

// ---------------- Dense layer: GEMM-style register tiling ----------------
// Block = 64 nodes x 64 dims, 4 waves (each a 32x32 quadrant), lane = 4x4 tile.
// Emits f32 y and fp16 mirror yh for the next layer's spmm gather.

__global__ __launch_bounds__(256) void dense_kernel(const float* __restrict__ x,
                                                    const float* __restrict__ agg,
                                                    const float* __restrict__ w1T,
                                                    const float* __restrict__ w2T,
                                                    const float* __restrict__ b1,
                                                    const float* __restrict__ b2,
                                                    float* __restrict__ y,
                                                    ushort* __restrict__ yh) {
    __shared__ float xs[64 * 64];
    __shared__ float xc[64 * 64];
    __shared__ float w1s[64 * 64];
    __shared__ float w2s[64 * 64];

    int tid = threadIdx.x;

    for (int f = tid; f < 1024; f += 256) {
        ((float4*)w1s)[f] = ((const float4*)w1T)[f];
        ((float4*)w2s)[f] = ((const float4*)w2T)[f];
    }

    int n0 = blockIdx.x * 64;
    int q = tid & 15;
#pragma unroll
    for (int nn = 0; nn < 4; ++nn) {
        int nl = (tid >> 4) + nn * 16;
        int node = n0 + nl;
        int ncl = (node < N_NODES) ? node : (N_NODES - 1);
        const float* xrow = x + (size_t)ncl * DIM;
        const float* arow = agg + (size_t)ncl * DIM;
#pragma unroll
        for (int k = 0; k < 4; ++k) {
            int j = q + 16 * k;
            float xv = xrow[j];
            float av = arow[j];
            int idx = j * 64 + (nl ^ ((j & 7) << 2));
            xs[idx] = xv + av;
            xc[idx] = xv;
        }
    }
    __syncthreads();

    int lane = tid & 63, w = tid >> 6;
    int wn = w >> 1, wd = w & 1;
    int r = lane >> 3, c = lane & 7;
    int nb = wn * 32 + r * 4;
    int db = wd * 32 + c * 4;

    float s1[16] = {};
    float s2[16] = {};

#pragma unroll 2
    for (int j = 0; j < 64; ++j) {
        int swz = (j & 7) << 2;
        float4 as4 = *(const float4*)&xs[j * 64 + (nb ^ swz)];
        float4 ac4 = *(const float4*)&xc[j * 64 + (nb ^ swz)];
        float4 bw1 = *(const float4*)&w1s[j * 64 + db];
        float4 bw2 = *(const float4*)&w2s[j * 64 + db];
        float asv[4] = {as4.x, as4.y, as4.z, as4.w};
        float acv[4] = {ac4.x, ac4.y, ac4.z, ac4.w};
        float w1v[4] = {bw1.x, bw1.y, bw1.z, bw1.w};
        float w2v[4] = {bw2.x, bw2.y, bw2.z, bw2.w};
#pragma unroll
        for (int i = 0; i < 4; ++i)
#pragma unroll
            for (int k = 0; k < 4; ++k) {
                s1[i * 4 + k] += asv[i] * w1v[k];
                s2[i * 4 + k] += acv[i] * w2v[k];
            }
    }

    float4 bv1 = *(const float4*)&b1[db];
    float4 bv2 = *(const float4*)&b2[db];
    float bb1[4] = {bv1.x, bv1.y, bv1.z, bv1.w};
    float bb2[4] = {bv2.x, bv2.y, bv2.z, bv2.w};

#pragma unroll
    for (int i = 0; i < 4; ++i) {
        int nl = nb + i;
        int node = n0 + nl;
        float4 o;
        float ov[4];
#pragma unroll
        for (int k = 0; k < 4; ++k) {
            int d = db + k;
            int idx = d * 64 + (nl ^ ((d & 7) << 2));
            float ag = xs[idx] - xc[idx];
            float t = s1[i * 4 + k] + bb1[k] + ag * (s2[i * 4 + k] + bb2[k]);
            ov[k] = (t > 0.f) ? t : 0.01f * t;
        }
        o.x = ov[0]; o.y = ov[1]; o.z = ov[2]; o.w = ov[3];
        if (node < N_NODES) {
            *(float4*)&y[(size_t)node * DIM + db] = o;
            ushort4 ho;
            ho.x = f2h(ov[0]); ho.y = f2h(ov[1]); ho.z = f2h(ov[2]); ho.w = f2h(ov[3]);
            *(ushort4*)&yh[(size_t)node * DIM + db] = ho;
        }
    }
}

// ---------------- Per-layer dot contributions (layers 1,2) ----------------

__global__ __launch_bounds__(256) void gather_dots_kernel(const float* __restrict__ x,
                                                          const int* __restrict__ user,
                                                          const int* __restrict__ pos,
                                                          const int* __restrict__ neg,
                                                          float* __restrict__ dst) {
    int lane = threadIdx.x & 63;
    int i = blockIdx.x * 4 + (threadIdx.x >> 6);
    int ui = user[i], pi = pos[i], ni = neg[i];
    float u = x[(size_t)ui * DIM + lane];
    float p = x[(size_t)pi * DIM + lane];
    float n = x[(size_t)ni * DIM + lane];
    float v = u * (p - n);
#pragma unroll
    for (int off = 32; off; off >>= 1) v += __shfl_xor(v, off);
    if (lane == 0) dst[i] = v;
}

// ---------------- dots layer 3 + loss (atomic accumulate) ----------------

__global__ __launch_bounds__(256) void dots_loss_kernel(const float* __restrict__ x,
                                                        const int* __restrict__ user,
                                                        const int* __restrict__ pos,
                                                        const int* __restrict__ neg,
                                                        const float* __restrict__ dots,
                                                        float* __restrict__ out) {
    __shared__ float part[4];
    int tid = threadIdx.x;
    int lane = tid & 63;
    int i = blockIdx.x * 4 + (tid >> 6);
    int ui = user[i], pi = pos[i], ni = neg[i];
    float u = x[(size_t)ui * DIM + lane];
    float p = x[(size_t)pi * DIM + lane];
    float n = x[(size_t)ni * DIM + lane];
    float v = u * (p - n);
#pragma unroll
    for (int off = 32; off; off >>= 1) v += __shfl_xor(v, off);
    if (lane == 0) {
        float d = dots[i] + dots[BATCH + i] + dots[2 * BATCH + i] + v;
        part[tid >> 6] = fmaxf(-d, 0.f) + log1pf(expf(-fabsf(d)));
    }
    __syncthreads();
    if (tid == 0) atomicAdd(out, part[0] + part[1] + part[2] + part[3]);
}

// ---------------- Launch ----------------

extern "C" void kernel_launch(void* const* d_in, const int* in_sizes, int n_in,
                              void* d_out, int out_size, void* d_ws, size_t ws_size,
                              hipStream_t stream) {
    const float* emb  = (const float*)d_in[0];
    const float* w1_w = (const float*)d_in[1];
    const float* w1_b = (const float*)d_in[2];
    const float* w2_w = (const float*)d_in[3];
    const float* w2_b = (const float*)d_in[4];
    const float* vals = (const float*)d_in[5];
    const int* rows = (const int*)d_in[6];
    const int* cols = (const int*)d_in[7];
    const int* user = (const int*)d_in[8];
    const int* pos  = (const int*)d_in[9];
    const int* neg  = (const int*)d_in[10];
    float* out = (float*)d_out;

    char* w = (char*)d_ws;
    float* bufA = (float*)w;  w += (size_t)N_NODES * DIM * 4;   // also CSR staging
    float* bufB = (float*)w;  w += (size_t)N_NODES * DIM * 4;
    float* agg  = (float*)w;  w += (size_t)N_NODES * DIM * 4;
    int* row_ptr = (int*)w;   w += (((size_t)(N_NODES + 1) * 4) + 255) / 256 * 256;
    uint32* csr  = (uint32*)w; w += (size_t)EDGES * 4;
    int* bhist   = (int*)w;   w += (size_t)NABLK * NBUCK * 4;
    int* bucket_sums = (int*)w; w += 256 * 4;
    int* bucket_base = (int*)w; w += 256 * 4;
    float* dots  = (float*)w; w += (size_t)3 * BATCH * 4;
    float* w1T   = (float*)w; w += (size_t)NLAYER * DIM * DIM * 4;
    float* w2T   = (float*)w; w += (size_t)NLAYER * DIM * DIM * 4;
    ushort* xhA  = (ushort*)w; w += (size_t)N_NODES * DIM * 2;
    ushort* xhB  = (ushort*)w; w += (size_t)N_NODES * DIM * 2;

    int2* staging = (int2*)bufA;   // consumed by csr_build before dense0 writes bufA

    hipMemsetAsync(bucket_sums, 0, NBUCK * 4, stream);
    hipMemsetAsync(out, 0, 4, stream);

    bucket_hist_kernel<<<NABLK, 256, 0, stream>>>(rows, bhist, bucket_sums);
    prep_kernel<<<PB_TOTAL, 256, 0, stream>>>(emb, w1_w, w2_w, bucket_sums, bucket_base,
                                              w1T, w2T, xhA, user, pos, neg, dots);
    bucket_scatter_kernel<<<NABLK, 256, 0, stream>>>(rows, cols, vals, bhist, bucket_base, staging);
    csr_build_kernel<<<NBUCK, 256, 0, stream>>>(bucket_base, staging, row_ptr, csr);

    const int NSB = (N_NODES + 3) / 4;
    const int NDB = (N_NODES + 63) / 64;

    // layer 0: spmm gathers xhA (mirror of emb); dense x=emb -> bufA + xhB
    spmm_kernel<<<NSB, 256, 0, stream>>>(row_ptr, csr, xhA, agg);
    dense_kernel<<<NDB, 256, 0, stream>>>(emb, agg, w1T + 0 * 4096, w2T + 0 * 4096,
                                          w1_b + 0 * DIM, w2_b + 0 * DIM, bufA, xhB);
    gather_dots_kernel<<<BATCH / 4, 256, 0, stream>>>(bufA, user, pos, neg, dots + BATCH);

    // layer 1: spmm gathers xhB; dense x=bufA -> bufB + xhA
    spmm_kernel<<<NSB, 256, 0, stream>>>(row_ptr, csr, xhB, agg);
    dense_kernel<<<NDB, 256, 0, stream>>>(bufA, agg, w1T + 1 * 4096, w2T + 1 * 4096,
                                          w1_b + 1 * DIM, w2_b + 1 * DIM, bufB, xhA);
    gather_dots_kernel<<<BATCH / 4, 256, 0, stream>>>(bufB, user, pos, neg, dots + 2 * BATCH);

    // layer 2: spmm gathers xhA; dense x=bufB -> bufA + xhB
    spmm_kernel<<<NSB, 256, 0, stream>>>(row_ptr, csr, xhA, agg);
    dense_kernel<<<NDB, 256, 0, stream>>>(bufB, agg, w1T + 2 * 4096, w2T + 2 * 4096,
                                          w1_b + 2 * DIM, w2_b + 2 * DIM, bufA, xhB);
    dots_loss_kernel<<<BATCH / 4, 256, 0, stream>>>(bufA, user, pos, neg, dots, out);
}

// Round 11
// 241.546 us; speedup vs baseline: 1.6658x; 1.0833x over previous
//
#include <hip/hip_runtime.h>
#include <hip/hip_fp16.h>
#include <math.h>

#define N_NODES 50000
#define EDGES   1250000
#define DIM     64
#define NLAYER  3
#define BATCH   4096

#define NBUCK 196   // coarse buckets: bucket = row >> 8 (256 rows each)
#define RPB   256   // rows per bucket
#define NABLK 256   // phase-A blocks

typedef unsigned int uint32;

static __device__ __forceinline__ ushort f2h(float f) {
    return __half_as_ushort(__float2half(f));
}
static __device__ __forceinline__ float h2f(ushort u) {
    return __half2float(__ushort_as_half(u));
}

// ---------------- Phase A1: per-block bucket histogram (+ global bucket sums) ----

__global__ __launch_bounds__(256) void bucket_hist_kernel(const int* __restrict__ rows,
                                                          int* __restrict__ bhist,
                                                          int* __restrict__ bucket_sums) {
    __shared__ int h[NBUCK];
    for (int i = threadIdx.x; i < NBUCK; i += 256) h[i] = 0;
    __syncthreads();
    int per = (EDGES + NABLK - 1) / NABLK;
    int e0 = blockIdx.x * per;
    int e1 = min(e0 + per, EDGES);
    for (int e = e0 + threadIdx.x; e < e1; e += 256)
        atomicAdd(&h[rows[e] >> 8], 1);
    __syncthreads();
    for (int i = threadIdx.x; i < NBUCK; i += 256) {
        bhist[blockIdx.x * NBUCK + i] = h[i];      // [block][bucket]
        atomicAdd(&bucket_sums[i], h[i]);
    }
}

// ---------------- boffs: per-bucket parallel prefix over the NABLK blocks ----
// block b: base_b = excl-scan(bucket_sums)[b]; boffs[b][k] = base_b + excl-scan_k(bhist[k][b])

__global__ __launch_bounds__(NABLK) void boffs_kernel(const int* __restrict__ bhist,
                                                      const int* __restrict__ bucket_sums,
                                                      int* __restrict__ boffs) {
    __shared__ int sbase[256];
    __shared__ int wred[NABLK / 64];
    int b = blockIdx.x;
    int tid = threadIdx.x;
    int lane = tid & 63, wid = tid >> 6;

    // 1) exclusive scan of bucket_sums[196] -> sbase
    {
        int v = (tid < NBUCK) ? bucket_sums[tid] : 0;
        int s = v;
#pragma unroll
        for (int off = 1; off < 64; off <<= 1) {
            int t = __shfl_up(s, off);
            if (lane >= off) s += t;
        }
        if (lane == 63) wred[wid] = s;
        __syncthreads();
        if (tid == 0) {
            int a = 0;
#pragma unroll
            for (int i = 0; i < NABLK / 64; ++i) { int t = wred[i]; wred[i] = a; a += t; }
        }
        __syncthreads();
        sbase[tid] = wred[wid] + s - v;
        __syncthreads();
    }
    int base = sbase[b];
    __syncthreads();

    // 2) exclusive scan of this bucket's per-block counts
    int v = bhist[tid * NBUCK + b];
    int s = v;
#pragma unroll
    for (int off = 1; off < 64; off <<= 1) {
        int t = __shfl_up(s, off);
        if (lane >= off) s += t;
    }
    if (lane == 63) wred[wid] = s;
    __syncthreads();
    if (tid == 0) {
        int a = 0;
#pragma unroll
        for (int i = 0; i < NABLK / 64; ++i) { int t = wred[i]; wred[i] = a; a += t; }
    }
    __syncthreads();
    boffs[b * NABLK + tid] = base + wred[wid] + s - v;
}

// ---------------- prep: W transpose + f2h(emb) + dots layer 0 ----------------
// blocks [0,48): transpose; [48,3173): f2h; [3173,4197): dots0

#define PB_F2H   48
#define PB_DOTS  3173
#define PB_TOTAL 4197

__global__ __launch_bounds__(256) void prep_kernel(const float* __restrict__ emb,
                                                   const float* __restrict__ w1,
                                                   const float* __restrict__ w2,
                                                   float* __restrict__ w1T,
                                                   float* __restrict__ w2T,
                                                   ushort* __restrict__ xh,
                                                   const int* __restrict__ user,
                                                   const int* __restrict__ pos,
                                                   const int* __restrict__ neg,
                                                   float* __restrict__ dots) {
    int blk = blockIdx.x;
    int tid = threadIdx.x;
    if (blk < PB_F2H) {
        int i = blk * 256 + tid;   // < 12288
        int l = i >> 12, r = i & 4095;
        int d = r >> 6, j = r & 63;
        w1T[l * 4096 + j * 64 + d] = w1[i];
        w2T[l * 4096 + j * 64 + d] = w2[i];
    } else if (blk < PB_DOTS) {
        int i = (blk - PB_F2H) * 256 + tid;     // < 800000
        if (i < N_NODES * DIM / 4) {
            float4 v = ((const float4*)emb)[i];
            ushort4 h;
            h.x = f2h(v.x); h.y = f2h(v.y); h.z = f2h(v.z); h.w = f2h(v.w);
            ((ushort4*)xh)[i] = h;
        }
    } else {
        int lane = tid & 63;
        int i = (blk - PB_DOTS) * 4 + (tid >> 6);
        int ui = user[i], pi = pos[i], ni = neg[i];
        float u = emb[(size_t)ui * DIM + lane];
        float p = emb[(size_t)pi * DIM + lane];
        float n = emb[(size_t)ni * DIM + lane];
        float v = u * (p - n);
#pragma unroll
        for (int off = 32; off; off >>= 1) v += __shfl_xor(v, off);
        if (lane == 0) dots[i] = v;
    }
}

// ---------------- Phase A3: scatter edges into bucket staging ----------------

__global__ __launch_bounds__(256) void bucket_scatter_kernel(const int* __restrict__ rows,
                                                             const int* __restrict__ cols,
                                                             const float* __restrict__ vals,
                                                             const int* __restrict__ boffs,
                                                             int2* __restrict__ staging) {
    __shared__ int cur[NBUCK];
    for (int t = threadIdx.x; t < NBUCK; t += 256)
        cur[t] = boffs[t * NABLK + blockIdx.x];
    __syncthreads();
    int per = (EDGES + NABLK - 1) / NABLK;
    int e0 = blockIdx.x * per;
    int e1 = min(e0 + per, EDGES);
    for (int e = e0 + threadIdx.x; e < e1; e += 256) {
        int r = rows[e];
        int p = atomicAdd(&cur[r >> 8], 1);
        staging[p] = make_int2(((r & 255) << 16) | cols[e], __float_as_int(vals[e]));
    }
}

// ---------------- Phase B: per-bucket row_ptr + final 4-byte CSR ----------------

__global__ __launch_bounds__(256) void csr_build_kernel(const int* __restrict__ boffs,
                                                        const int2* __restrict__ staging,
                                                        int* __restrict__ row_ptr,
                                                        uint32* __restrict__ csr) {
    __shared__ int rcur[RPB];
    __shared__ int wred[4];
    int b = blockIdx.x;
    int base = boffs[b * NABLK];
    int end = (b == NBUCK - 1) ? EDGES : boffs[(b + 1) * NABLK];
    int tid = threadIdx.x;
    rcur[tid] = 0;
    __syncthreads();
    for (int p = base + tid; p < end; p += 256)
        atomicAdd(&rcur[staging[p].x >> 16], 1);
    __syncthreads();
    int lane = tid & 63, wid = tid >> 6;
    int v = rcur[tid];
    int s = v;
#pragma unroll
    for (int off = 1; off < 64; off <<= 1) {
        int t = __shfl_up(s, off);
        if (lane >= off) s += t;
    }
    if (lane == 63) wred[wid] = s;
    __syncthreads();
    if (tid == 0) {
        int a = 0;
#pragma unroll
        for (int i = 0; i < 4; ++i) { int t = wred[i]; wred[i] = a; a += t; }
    }
    __syncthreads();
    int excl = wred[wid] + s - v;
    __syncthreads();
    rcur[tid] = base + excl;
    int row = b * RPB + tid;
    if (row < N_NODES) row_ptr[row] = base + excl;
    if (b == NBUCK - 1 && tid == 0) row_ptr[N_NODES] = EDGES;
    __syncthreads();
    for (int p = base + tid; p < end; p += 256) {
        int2 e = staging[p];
        int pos = atomicAdd(&rcur[e.x >> 16], 1);
        csr[pos] = ((uint32)(e.x & 0xFFFF) << 16) | (uint32)f2h(__int_as_float(e.y));
    }
}

// ---------------- SpMM: fp16 gather, 4-byte CSR, one wave per row ----------------

__global__ __launch_bounds__(256) void spmm_kernel(const int* __restrict__ row_ptr,
                                                   const uint32* __restrict__ csr,
                                                   const ushort* __restrict__ xh,
                                                   float* __restrict__ agg) {
    int lane = threadIdx.x & 63;
    int g = lane >> 4;
    int sl = lane & 15;
    int row = blockIdx.x * 4 + (threadIdx.x >> 6);
    if (row >= N_NODES) return;
    int p0 = row_ptr[row], p1 = row_ptr[row + 1];
    float4 acc = make_float4(0.f, 0.f, 0.f, 0.f);
    int p = p0;
    for (; p + 16 <= p1; p += 16) {
        uint32 a = csr[p + g];
        uint32 b = csr[p + 4 + g];
        uint32 c = csr[p + 8 + g];
        uint32 d = csr[p + 12 + g];
        ushort4 xa = *(const ushort4*)(xh + (size_t)(a >> 16) * DIM + sl * 4);
        ushort4 xb = *(const ushort4*)(xh + (size_t)(b >> 16) * DIM + sl * 4);
        ushort4 xc = *(const ushort4*)(xh + (size_t)(c >> 16) * DIM + sl * 4);
        ushort4 xd = *(const ushort4*)(xh + (size_t)(d >> 16) * DIM + sl * 4);
        float va = h2f((ushort)(a & 0xFFFF)), vb = h2f((ushort)(b & 0xFFFF));
        float vc = h2f((ushort)(c & 0xFFFF)), vd = h2f((ushort)(d & 0xFFFF));
        acc.x += va * h2f(xa.x); acc.y += va * h2f(xa.y); acc.z += va * h2f(xa.z); acc.w += va * h2f(xa.w);
        acc.x += vb * h2f(xb.x); acc.y += vb * h2f(xb.y); acc.z += vb * h2f(xb.z); acc.w += vb * h2f(xb.w);
        acc.x += vc * h2f(xc.x); acc.y += vc * h2f(xc.y); acc.z += vc * h2f(xc.z); acc.w += vc * h2f(xc.w);
        acc.x += vd * h2f(xd.x); acc.y += vd * h2f(xd.y); acc.z += vd * h2f(xd.z); acc.w += vd * h2f(xd.w);
    }
    for (; p + 8 <= p1; p += 8) {
        uint32 a = csr[p + g];
        uint32 b = csr[p + 4 + g];
        ushort4 xa = *(const ushort4*)(xh + (size_t)(a >> 16) * DIM + sl * 4);
        ushort4 xb = *(const ushort4*)(xh + (size_t)(b >> 16) * DIM + sl * 4);
        float va = h2f((ushort)(a & 0xFFFF)), vb = h2f((ushort)(b & 0xFFFF));
        acc.x += va * h2f(xa.x); acc.y += va * h2f(xa.y); acc.z += va * h2f(xa.z); acc.w += va * h2f(xa.w);
        acc.x += vb * h2f(xb.x); acc.y += vb * h2f(xb.y); acc.z += vb * h2f(xb.z); acc.w += vb * h2f(xb.w);
    }
    for (; p < p1; p += 4) {
        int pe = p + g;
        if (pe < p1) {
            uint32 a = csr[pe];
            ushort4 xa = *(const ushort4*)(xh + (size_t)(a >> 16) * DIM + sl * 4);
            float va = h2f((ushort)(a & 0xFFFF));
            acc.x += va * h2f(xa.x); acc.y += va * h2f(xa.y); acc.z += va * h2f(xa.z); acc.w += va * h2f(xa.w);
        }
    }
#pragma unroll
    for (int m = 16; m <= 32; m <<= 1) {
        acc.x += __shfl_xor(acc.x, m);
        acc.y += __shfl_xor(acc.y, m);
        acc.z += __shfl_xor(acc.z, m);
        acc.w += __shfl_xor(acc.w, m);
    }
    if (lane < 16) *(float4*)(agg + (size_t)row * DIM + lane * 4) = acc;
}

// ---------------- Dense layer: GEMM-style register tiling ----------------

__global__ __launch_bounds__(256) void dense_kernel(const float* __restrict__ x,
                                                    const float* __restrict__ agg,
                                                    const float* __restrict__ w1T,
                                                    const float* __restrict__ w2T,
                                                    const float* __restrict__ b1,
                                                    const float* __restrict__ b2,
                                                    float* __restrict__ y,
                                                    ushort* __restrict__ yh) {
    __shared__ float xs[64 * 64];
    __shared__ float xc[64 * 64];
    __shared__ float w1s[64 * 64];
    __shared__ float w2s[64 * 64];

    int tid = threadIdx.x;

    for (int f = tid; f < 1024; f += 256) {
        ((float4*)w1s)[f] = ((const float4*)w1T)[f];
        ((float4*)w2s)[f] = ((const float4*)w2T)[f];
    }

    int n0 = blockIdx.x * 64;
    int q = tid & 15;
#pragma unroll
    for (int nn = 0; nn < 4; ++nn) {
        int nl = (tid >> 4) + nn * 16;
        int node = n0 + nl;
        int ncl = (node < N_NODES) ? node : (N_NODES - 1);
        const float* xrow = x + (size_t)ncl * DIM;
        const float* arow = agg + (size_t)ncl * DIM;
#pragma unroll
        for (int k = 0; k < 4; ++k) {
            int j = q + 16 * k;
            float xv = xrow[j];
            float av = arow[j];
            int idx = j * 64 + (nl ^ ((j & 7) << 2));
            xs[idx] = xv + av;
            xc[idx] = xv;
        }
    }
    __syncthreads();

    int lane = tid & 63, w = tid >> 6;
    int wn = w >> 1, wd = w & 1;
    int r = lane >> 3, c = lane & 7;
    int nb = wn * 32 + r * 4;
    int db = wd * 32 + c * 4;

    float s1[16] = {};
    float s2[16] = {};

#pragma unroll 2
    for (int j = 0; j < 64; ++j) {
        int swz = (j & 7) << 2;
        float4 as4 = *(const float4*)&xs[j * 64 + (nb ^ swz)];
        float4 ac4 = *(const float4*)&xc[j * 64 + (nb ^ swz)];
        float4 bw1 = *(const float4*)&w1s[j * 64 + db];
        float4 bw2 = *(const float4*)&w2s[j * 64 + db];
        float asv[4] = {as4.x, as4.y, as4.z, as4.w};
        float acv[4] = {ac4.x, ac4.y, ac4.z, ac4.w};
        float w1v[4] = {bw1.x, bw1.y, bw1.z, bw1.w};
        float w2v[4] = {bw2.x, bw2.y, bw2.z, bw2.w};
#pragma unroll
        for (int i = 0; i < 4; ++i)
#pragma unroll
            for (int k = 0; k < 4; ++k) {
                s1[i * 4 + k] += asv[i] * w1v[k];
                s2[i * 4 + k] += acv[i] * w2v[k];
            }
    }

    float4 bv1 = *(const float4*)&b1[db];
    float4 bv2 = *(const float4*)&b2[db];
    float bb1[4] = {bv1.x, bv1.y, bv1.z, bv1.w};
    float bb2[4] = {bv2.x, bv2.y, bv2.z, bv2.w};

#pragma unroll
    for (int i = 0; i < 4; ++i) {
        int nl = nb + i;
        int node = n0 + nl;
        float4 o;
        float ov[4];
#pragma unroll
        for (int k = 0; k < 4; ++k) {
            int d = db + k;
            int idx = d * 64 + (nl ^ ((d & 7) << 2));
            float ag = xs[idx] - xc[idx];
            float t = s1[i * 4 + k] + bb1[k] + ag * (s2[i * 4 + k] + bb2[k]);
            ov[k] = (t > 0.f) ? t : 0.01f * t;
        }
        o.x = ov[0]; o.y = ov[1]; o.z = ov[2]; o.w = ov[3];
        if (node < N_NODES) {
            *(float4*)&y[(size_t)node * DIM + db] = o;
            ushort4 ho;
            ho.x = f2h(ov[0]); ho.y = f2h(ov[1]); ho.z = f2h(ov[2]); ho.w = f2h(ov[3]);
            *(ushort4*)&yh[(size_t)node * DIM + db] = ho;
        }
    }
}

// ---------------- Per-layer dot contributions (layers 1,2) ----------------

__global__ __launch_bounds__(256) void gather_dots_kernel(const float* __restrict__ x,
                                                          const int* __restrict__ user,
                                                          const int* __restrict__ pos,
                                                          const int* __restrict__ neg,
                                                          float* __restrict__ dst) {
    int lane = threadIdx.x & 63;
    int i = blockIdx.x * 4 + (threadIdx.x >> 6);
    int ui = user[i], pi = pos[i], ni = neg[i];
    float u = x[(size_t)ui * DIM + lane];
    float p = x[(size_t)pi * DIM + lane];
    float n = x[(size_t)ni * DIM + lane];
    float v = u * (p - n);
#pragma unroll
    for (int off = 32; off; off >>= 1) v += __shfl_xor(v, off);
    if (lane == 0) dst[i] = v;
}

// ---------------- dots layer 3 + loss (atomic accumulate) ----------------

__global__ __launch_bounds__(256) void dots_loss_kernel(const float* __restrict__ x,
                                                        const int* __restrict__ user,
                                                        const int* __restrict__ pos,
                                                        const int* __restrict__ neg,
                                                        const float* __restrict__ dots,
                                                        float* __restrict__ out) {
    __shared__ float part[4];
    int tid = threadIdx.x;
    int lane = tid & 63;
    int i = blockIdx.x * 4 + (tid >> 6);
    int ui = user[i], pi = pos[i], ni = neg[i];
    float u = x[(size_t)ui * DIM + lane];
    float p = x[(size_t)pi * DIM + lane];
    float n = x[(size_t)ni * DIM + lane];
    float v = u * (p - n);
#pragma unroll
    for (int off = 32; off; off >>= 1) v += __shfl_xor(v, off);
    if (lane == 0) {
        float d = dots[i] + dots[BATCH + i] + dots[2 * BATCH + i] + v;
        part[tid >> 6] = fmaxf(-d, 0.f) + log1pf(expf(-fabsf(d)));
    }
    __syncthreads();
    if (tid == 0) atomicAdd(out, part[0] + part[1] + part[2] + part[3]);
}

// ---------------- Launch ----------------

extern "C" void kernel_launch(void* const* d_in, const int* in_sizes, int n_in,
                              void* d_out, int out_size, void* d_ws, size_t ws_size,
                              hipStream_t stream) {
    const float* emb  = (const float*)d_in[0];
    const float* w1_w = (const float*)d_in[1];
    const float* w1_b = (const float*)d_in[2];
    const float* w2_w = (const float*)d_in[3];
    const float* w2_b = (const float*)d_in[4];
    const float* vals = (const float*)d_in[5];
    const int* rows = (const int*)d_in[6];
    const int* cols = (const int*)d_in[7];
    const int* user = (const int*)d_in[8];
    const int* pos  = (const int*)d_in[9];
    const int* neg  = (const int*)d_in[10];
    float* out = (float*)d_out;

    char* w = (char*)d_ws;
    float* bufA = (float*)w;  w += (size_t)N_NODES * DIM * 4;   // also CSR staging
    float* bufB = (float*)w;  w += (size_t)N_NODES * DIM * 4;
    float* agg  = (float*)w;  w += (size_t)N_NODES * DIM * 4;
    int* row_ptr = (int*)w;   w += (((size_t)(N_NODES + 1) * 4) + 255) / 256 * 256;
    uint32* csr  = (uint32*)w; w += (size_t)EDGES * 4;
    int* bhist   = (int*)w;   w += (size_t)NABLK * NBUCK * 4;
    int* boffs   = (int*)w;   w += (size_t)NBUCK * NABLK * 4;
    int* bucket_sums = (int*)w; w += 256 * 4;
    float* dots  = (float*)w; w += (size_t)3 * BATCH * 4;
    float* w1T   = (float*)w; w += (size_t)NLAYER * DIM * DIM * 4;
    float* w2T   = (float*)w; w += (size_t)NLAYER * DIM * DIM * 4;
    ushort* xhA  = (ushort*)w; w += (size_t)N_NODES * DIM * 2;
    ushort* xhB  = (ushort*)w; w += (size_t)N_NODES * DIM * 2;

    int2* staging = (int2*)bufA;   // consumed by csr_build before dense0 writes bufA

    hipMemsetAsync(bucket_sums, 0, NBUCK * 4, stream);
    hipMemsetAsync(out, 0, 4, stream);

    bucket_hist_kernel<<<NABLK, 256, 0, stream>>>(rows, bhist, bucket_sums);
    boffs_kernel<<<NBUCK, NABLK, 0, stream>>>(bhist, bucket_sums, boffs);
    prep_kernel<<<PB_TOTAL, 256, 0, stream>>>(emb, w1_w, w2_w, w1T, w2T, xhA,
                                              user, pos, neg, dots);
    bucket_scatter_kernel<<<NABLK, 256, 0, stream>>>(rows, cols, vals, boffs, staging);
    csr_build_kernel<<<NBUCK, 256, 0, stream>>>(boffs, staging, row_ptr, csr);

    const int NSB = (N_NODES + 3) / 4;
    const int NDB = (N_NODES + 63) / 64;

    // layer 0: spmm gathers xhA (mirror of emb); dense x=emb -> bufA + xhB
    spmm_kernel<<<NSB, 256, 0, stream>>>(row_ptr, csr, xhA, agg);
    dense_kernel<<<NDB, 256, 0, stream>>>(emb, agg, w1T + 0 * 4096, w2T + 0 * 4096,
                                          w1_b + 0 * DIM, w2_b + 0 * DIM, bufA, xhB);
    gather_dots_kernel<<<BATCH / 4, 256, 0, stream>>>(bufA, user, pos, neg, dots + BATCH);

    // layer 1: spmm gathers xhB; dense x=bufA -> bufB + xhA
    spmm_kernel<<<NSB, 256, 0, stream>>>(row_ptr, csr, xhB, agg);
    dense_kernel<<<NDB, 256, 0, stream>>>(bufA, agg, w1T + 1 * 4096, w2T + 1 * 4096,
                                          w1_b + 1 * DIM, w2_b + 1 * DIM, bufB, xhA);
    gather_dots_kernel<<<BATCH / 4, 256, 0, stream>>>(bufB, user, pos, neg, dots + 2 * BATCH);

    // layer 2: spmm gathers xhA; dense x=bufB -> bufA + xhB
    spmm_kernel<<<NSB, 256, 0, stream>>>(row_ptr, csr, xhA, agg);
    dense_kernel<<<NDB, 256, 0, stream>>>(bufB, agg, w1T + 2 * 4096, w2T + 2 * 4096,
                                          w1_b + 2 * DIM, w2_b + 2 * DIM, bufA, xhB);
    dots_loss_kernel<<<BATCH / 4, 256, 0, stream>>>(bufA, user, pos, neg, dots, out);
}

// Round 12
// 222.743 us; speedup vs baseline: 1.8064x; 1.0844x over previous
//
#include <hip/hip_runtime.h>
#include <hip/hip_fp16.h>
#include <math.h>

#define N_NODES 50000
#define EDGES   1250000
#define DIM     64
#define NLAYER  3
#define BATCH   4096

#define NBUCK 196   // coarse buckets: bucket = row >> 8 (256 rows each)
#define RPB   256   // rows per bucket
#define NABLK 256   // phase-A blocks

typedef unsigned int uint32;

static __device__ __forceinline__ ushort f2h(float f) {
    return __half_as_ushort(__float2half(f));
}
static __device__ __forceinline__ float h2f(ushort u) {
    return __half2float(__ushort_as_half(u));
}

// ---------------- histprep: bucket hist + W transpose + f2h(emb) + dots0 ----
// blocks [0,256): hist; [256,304): transpose; [304,3429): f2h; [3429,4453): dots0

#define HP_TRANS 256
#define HP_F2H   304
#define HP_DOTS  3429
#define HP_TOTAL 4453

__global__ __launch_bounds__(256) void histprep_kernel(const int* __restrict__ rows,
                                                       int* __restrict__ bhist,
                                                       const float* __restrict__ emb,
                                                       const float* __restrict__ w1,
                                                       const float* __restrict__ w2,
                                                       float* __restrict__ w1T,
                                                       float* __restrict__ w2T,
                                                       ushort* __restrict__ xh,
                                                       const int* __restrict__ user,
                                                       const int* __restrict__ pos,
                                                       const int* __restrict__ neg,
                                                       float* __restrict__ dots) {
    __shared__ int h[NBUCK];
    int blk = blockIdx.x;
    int tid = threadIdx.x;
    if (blk < HP_TRANS) {
        // bucket histogram; bhist layout [bucket][block] (bucket-major)
        for (int i = tid; i < NBUCK; i += 256) h[i] = 0;
        __syncthreads();
        int per = (EDGES + NABLK - 1) / NABLK;
        int e0 = blk * per;
        int e1 = min(e0 + per, EDGES);
        for (int e = e0 + tid; e < e1; e += 256)
            atomicAdd(&h[rows[e] >> 8], 1);
        __syncthreads();
        for (int i = tid; i < NBUCK; i += 256)
            bhist[i * NABLK + blk] = h[i];
    } else if (blk < HP_F2H) {
        int i = (blk - HP_TRANS) * 256 + tid;   // < 12288
        int l = i >> 12, r = i & 4095;
        int d = r >> 6, j = r & 63;
        w1T[l * 4096 + j * 64 + d] = w1[i];
        w2T[l * 4096 + j * 64 + d] = w2[i];
    } else if (blk < HP_DOTS) {
        int i = (blk - HP_F2H) * 256 + tid;     // < 800000 exactly
        float4 v = ((const float4*)emb)[i];
        ushort4 hh;
        hh.x = f2h(v.x); hh.y = f2h(v.y); hh.z = f2h(v.z); hh.w = f2h(v.w);
        ((ushort4*)xh)[i] = hh;
    } else {
        int lane = tid & 63;
        int i = (blk - HP_DOTS) * 4 + (tid >> 6);
        int ui = user[i], pi = pos[i], ni = neg[i];
        float u = emb[(size_t)ui * DIM + lane];
        float p = emb[(size_t)pi * DIM + lane];
        float n = emb[(size_t)ni * DIM + lane];
        float v = u * (p - n);
#pragma unroll
        for (int off = 32; off; off >>= 1) v += __shfl_xor(v, off);
        if (lane == 0) dots[i] = v;
    }
}

// ---------------- boffs: per-bucket parallel prefix (self-computed totals) ----
// block b: tot[t] = sum_k bhist[t][k]; base_b = excl-scan(tot)[b];
// boffs[b][k] = base_b + excl-scan_k(bhist[b][k]).  All layouts bucket-major.

__global__ __launch_bounds__(256) void boffs_kernel(const int* __restrict__ bhist,
                                                    int* __restrict__ boffs) {
    __shared__ int sbase[256];
    __shared__ int wred[4];
    int b = blockIdx.x;
    int tid = threadIdx.x;
    int lane = tid & 63, wid = tid >> 6;

    // A: totals per bucket (contiguous 256-int row sums)
    int t = 0;
    if (tid < NBUCK) {
        const int* p = bhist + (size_t)tid * NABLK;
        for (int k = 0; k < NABLK; ++k) t += p[k];
    }
    // B: exclusive scan of totals -> sbase
    {
        int s = t;
#pragma unroll
        for (int off = 1; off < 64; off <<= 1) {
            int tt = __shfl_up(s, off);
            if (lane >= off) s += tt;
        }
        if (lane == 63) wred[wid] = s;
        __syncthreads();
        if (tid == 0) {
            int a = 0;
#pragma unroll
            for (int i = 0; i < 4; ++i) { int tt = wred[i]; wred[i] = a; a += tt; }
        }
        __syncthreads();
        sbase[tid] = wred[wid] + s - t;
        __syncthreads();
    }
    int base = sbase[b];
    __syncthreads();

    // C: exclusive scan of this bucket's per-block counts (coalesced row)
    int v = bhist[(size_t)b * NABLK + tid];
    int s = v;
#pragma unroll
    for (int off = 1; off < 64; off <<= 1) {
        int tt = __shfl_up(s, off);
        if (lane >= off) s += tt;
    }
    if (lane == 63) wred[wid] = s;
    __syncthreads();
    if (tid == 0) {
        int a = 0;
#pragma unroll
        for (int i = 0; i < 4; ++i) { int tt = wred[i]; wred[i] = a; a += tt; }
    }
    __syncthreads();
    boffs[(size_t)b * NABLK + tid] = base + wred[wid] + s - v;
}

// ---------------- Phase A3: scatter edges into bucket staging ----------------

__global__ __launch_bounds__(256) void bucket_scatter_kernel(const int* __restrict__ rows,
                                                             const int* __restrict__ cols,
                                                             const float* __restrict__ vals,
                                                             const int* __restrict__ boffs,
                                                             int2* __restrict__ staging) {
    __shared__ int cur[NBUCK];
    for (int t = threadIdx.x; t < NBUCK; t += 256)
        cur[t] = boffs[(size_t)t * NABLK + blockIdx.x];
    __syncthreads();
    int per = (EDGES + NABLK - 1) / NABLK;
    int e0 = blockIdx.x * per;
    int e1 = min(e0 + per, EDGES);
    for (int e = e0 + threadIdx.x; e < e1; e += 256) {
        int r = rows[e];
        int p = atomicAdd(&cur[r >> 8], 1);
        staging[p] = make_int2(((r & 255) << 16) | cols[e], __float_as_int(vals[e]));
    }
}

// ---------------- Phase B: per-bucket row_ptr + final 4-byte CSR ----------------

__global__ __launch_bounds__(256) void csr_build_kernel(const int* __restrict__ boffs,
                                                        const int2* __restrict__ staging,
                                                        int* __restrict__ row_ptr,
                                                        uint32* __restrict__ csr) {
    __shared__ int rcur[RPB];
    __shared__ int wred[4];
    int b = blockIdx.x;
    int base = boffs[(size_t)b * NABLK];
    int end = (b == NBUCK - 1) ? EDGES : boffs[(size_t)(b + 1) * NABLK];
    int tid = threadIdx.x;
    rcur[tid] = 0;
    __syncthreads();
    for (int p = base + tid; p < end; p += 256)
        atomicAdd(&rcur[staging[p].x >> 16], 1);
    __syncthreads();
    int lane = tid & 63, wid = tid >> 6;
    int v = rcur[tid];
    int s = v;
#pragma unroll
    for (int off = 1; off < 64; off <<= 1) {
        int t = __shfl_up(s, off);
        if (lane >= off) s += t;
    }
    if (lane == 63) wred[wid] = s;
    __syncthreads();
    if (tid == 0) {
        int a = 0;
#pragma unroll
        for (int i = 0; i < 4; ++i) { int t = wred[i]; wred[i] = a; a += t; }
    }
    __syncthreads();
    int excl = wred[wid] + s - v;
    __syncthreads();
    rcur[tid] = base + excl;
    int row = b * RPB + tid;
    if (row < N_NODES) row_ptr[row] = base + excl;
    if (b == NBUCK - 1 && tid == 0) row_ptr[N_NODES] = EDGES;
    __syncthreads();
    for (int p = base + tid; p < end; p += 256) {
        int2 e = staging[p];
        int pos = atomicAdd(&rcur[e.x >> 16], 1);
        csr[pos] = ((uint32)(e.x & 0xFFFF) << 16) | (uint32)f2h(__int_as_float(e.y));
    }
}

// ---------------- SpMM: 8 edge-groups x 8 lanes x uint4 (16B) gathers ----------
// + optional dots tail blocks (blockIdx >= nsb): per-batch-item dot diffs.

__global__ __launch_bounds__(256) void spmm_kernel(const int* __restrict__ row_ptr,
                                                   const uint32* __restrict__ csr,
                                                   const ushort* __restrict__ xh,
                                                   float* __restrict__ agg,
                                                   const int* __restrict__ user,
                                                   const int* __restrict__ pos,
                                                   const int* __restrict__ neg,
                                                   float* __restrict__ dots,
                                                   int nsb) {
    int lane = threadIdx.x & 63;
    if ((int)blockIdx.x >= nsb) {
        int i = (blockIdx.x - nsb) * 4 + (threadIdx.x >> 6);
        int ui = user[i], pi = pos[i], ni = neg[i];
        float u = h2f(xh[(size_t)ui * DIM + lane]);
        float p = h2f(xh[(size_t)pi * DIM + lane]);
        float n = h2f(xh[(size_t)ni * DIM + lane]);
        float v = u * (p - n);
#pragma unroll
        for (int off = 32; off; off >>= 1) v += __shfl_xor(v, off);
        if (lane == 0) dots[i] = v;
        return;
    }
    int g = lane >> 3;     // edge group 0..7
    int sl = lane & 7;     // dim octant (8 halves)
    int row = blockIdx.x * 4 + (threadIdx.x >> 6);
    int p0 = row_ptr[row], p1 = row_ptr[row + 1];
    float a0 = 0, a1 = 0, a2 = 0, a3 = 0, a4 = 0, a5 = 0, a6 = 0, a7 = 0;
    int p = p0;
#define SPMM_ACC(E, X)                                                     \
    {                                                                      \
        float vv = h2f((ushort)((E) & 0xFFFF));                            \
        a0 += vv * h2f((ushort)((X).x & 0xFFFF));                          \
        a1 += vv * h2f((ushort)((X).x >> 16));                             \
        a2 += vv * h2f((ushort)((X).y & 0xFFFF));                          \
        a3 += vv * h2f((ushort)((X).y >> 16));                             \
        a4 += vv * h2f((ushort)((X).z & 0xFFFF));                          \
        a5 += vv * h2f((ushort)((X).z >> 16));                             \
        a6 += vv * h2f((ushort)((X).w & 0xFFFF));                          \
        a7 += vv * h2f((ushort)((X).w >> 16));                             \
    }
    for (; p + 16 <= p1; p += 16) {
        uint32 ea = csr[p + g];
        uint32 eb = csr[p + 8 + g];
        uint4 xa = *(const uint4*)(xh + (size_t)(ea >> 16) * DIM + sl * 8);
        uint4 xb = *(const uint4*)(xh + (size_t)(eb >> 16) * DIM + sl * 8);
        SPMM_ACC(ea, xa);
        SPMM_ACC(eb, xb);
    }
    for (; p + 8 <= p1; p += 8) {
        uint32 ea = csr[p + g];
        uint4 xa = *(const uint4*)(xh + (size_t)(ea >> 16) * DIM + sl * 8);
        SPMM_ACC(ea, xa);
    }
    if (p + g < p1) {
        uint32 ea = csr[p + g];
        uint4 xa = *(const uint4*)(xh + (size_t)(ea >> 16) * DIM + sl * 8);
        SPMM_ACC(ea, xa);
    }
#undef SPMM_ACC
#pragma unroll
    for (int m = 8; m <= 32; m <<= 1) {
        a0 += __shfl_xor(a0, m); a1 += __shfl_xor(a1, m);
        a2 += __shfl_xor(a2, m); a3 += __shfl_xor(a3, m);
        a4 += __shfl_xor(a4, m); a5 += __shfl_xor(a5, m);
        a6 += __shfl_xor(a6, m); a7 += __shfl_xor(a7, m);
    }
    if (lane < 8) {
        float* dst = agg + (size_t)row * DIM + lane * 8;
        *(float4*)dst = make_float4(a0, a1, a2, a3);
        *(float4*)(dst + 4) = make_float4(a4, a5, a6, a7);
    }
}

// ---------------- Dense layer: GEMM register tiling, fp16 in / fp16 out ----------
// Block = 64 nodes x 64 dims, 4 waves, lane = 4x4 tile. x from fp16 mirror;
// agg f32; output only the fp16 mirror yh (next layer + dots consume fp16).

__global__ __launch_bounds__(256) void dense_kernel(const ushort* __restrict__ xh_in,
                                                    const float* __restrict__ agg,
                                                    const float* __restrict__ w1T,
                                                    const float* __restrict__ w2T,
                                                    const float* __restrict__ b1,
                                                    const float* __restrict__ b2,
                                                    ushort* __restrict__ yh) {
    __shared__ float xs[64 * 64];
    __shared__ float xc[64 * 64];
    __shared__ float w1s[64 * 64];
    __shared__ float w2s[64 * 64];

    int tid = threadIdx.x;

    for (int f = tid; f < 1024; f += 256) {
        ((float4*)w1s)[f] = ((const float4*)w1T)[f];
        ((float4*)w2s)[f] = ((const float4*)w2T)[f];
    }

    int n0 = blockIdx.x * 64;
    int q = tid & 15;
#pragma unroll
    for (int nn = 0; nn < 4; ++nn) {
        int nl = (tid >> 4) + nn * 16;
        int node = n0 + nl;
        int ncl = (node < N_NODES) ? node : (N_NODES - 1);
        const ushort* xrow = xh_in + (size_t)ncl * DIM;
        const float* arow = agg + (size_t)ncl * DIM;
#pragma unroll
        for (int k = 0; k < 4; ++k) {
            int j = q + 16 * k;
            float xv = h2f(xrow[j]);
            float av = arow[j];
            int idx = j * 64 + (nl ^ ((j & 7) << 2));
            xs[idx] = xv + av;
            xc[idx] = xv;
        }
    }
    __syncthreads();

    int lane = tid & 63, w = tid >> 6;
    int wn = w >> 1, wd = w & 1;
    int r = lane >> 3, c = lane & 7;
    int nb = wn * 32 + r * 4;
    int db = wd * 32 + c * 4;

    float s1[16] = {};
    float s2[16] = {};

#pragma unroll 2
    for (int j = 0; j < 64; ++j) {
        int swz = (j & 7) << 2;
        float4 as4 = *(const float4*)&xs[j * 64 + (nb ^ swz)];
        float4 ac4 = *(const float4*)&xc[j * 64 + (nb ^ swz)];
        float4 bw1 = *(const float4*)&w1s[j * 64 + db];
        float4 bw2 = *(const float4*)&w2s[j * 64 + db];
        float asv[4] = {as4.x, as4.y, as4.z, as4.w};
        float acv[4] = {ac4.x, ac4.y, ac4.z, ac4.w};
        float w1v[4] = {bw1.x, bw1.y, bw1.z, bw1.w};
        float w2v[4] = {bw2.x, bw2.y, bw2.z, bw2.w};
#pragma unroll
        for (int i = 0; i < 4; ++i)
#pragma unroll
            for (int k = 0; k < 4; ++k) {
                s1[i * 4 + k] += asv[i] * w1v[k];
                s2[i * 4 + k] += acv[i] * w2v[k];
            }
    }

    float4 bv1 = *(const float4*)&b1[db];
    float4 bv2 = *(const float4*)&b2[db];
    float bb1[4] = {bv1.x, bv1.y, bv1.z, bv1.w};
    float bb2[4] = {bv2.x, bv2.y, bv2.z, bv2.w};

#pragma unroll
    for (int i = 0; i < 4; ++i) {
        int nl = nb + i;
        int node = n0 + nl;
        float ov[4];
#pragma unroll
        for (int k = 0; k < 4; ++k) {
            int d = db + k;
            int idx = d * 64 + (nl ^ ((d & 7) << 2));
            float ag = xs[idx] - xc[idx];
            float t = s1[i * 4 + k] + bb1[k] + ag * (s2[i * 4 + k] + bb2[k]);
            ov[k] = (t > 0.f) ? t : 0.01f * t;
        }
        if (node < N_NODES) {
            ushort4 ho;
            ho.x = f2h(ov[0]); ho.y = f2h(ov[1]); ho.z = f2h(ov[2]); ho.w = f2h(ov[3]);
            *(ushort4*)&yh[(size_t)node * DIM + db] = ho;
        }
    }
}

// ---------------- dots layer 3 + loss (atomic accumulate) ----------------

__global__ __launch_bounds__(256) void dots_loss_kernel(const ushort* __restrict__ xh,
                                                        const int* __restrict__ user,
                                                        const int* __restrict__ pos,
                                                        const int* __restrict__ neg,
                                                        const float* __restrict__ dots,
                                                        float* __restrict__ out) {
    __shared__ float part[4];
    int tid = threadIdx.x;
    int lane = tid & 63;
    int i = blockIdx.x * 4 + (tid >> 6);
    int ui = user[i], pi = pos[i], ni = neg[i];
    float u = h2f(xh[(size_t)ui * DIM + lane]);
    float p = h2f(xh[(size_t)pi * DIM + lane]);
    float n = h2f(xh[(size_t)ni * DIM + lane]);
    float v = u * (p - n);
#pragma unroll
    for (int off = 32; off; off >>= 1) v += __shfl_xor(v, off);
    if (lane == 0) {
        float d = dots[i] + dots[BATCH + i] + dots[2 * BATCH + i] + v;
        part[tid >> 6] = fmaxf(-d, 0.f) + log1pf(expf(-fabsf(d)));
    }
    __syncthreads();
    if (tid == 0) atomicAdd(out, part[0] + part[1] + part[2] + part[3]);
}

// ---------------- Launch ----------------

extern "C" void kernel_launch(void* const* d_in, const int* in_sizes, int n_in,
                              void* d_out, int out_size, void* d_ws, size_t ws_size,
                              hipStream_t stream) {
    const float* emb  = (const float*)d_in[0];
    const float* w1_w = (const float*)d_in[1];
    const float* w1_b = (const float*)d_in[2];
    const float* w2_w = (const float*)d_in[3];
    const float* w2_b = (const float*)d_in[4];
    const float* vals = (const float*)d_in[5];
    const int* rows = (const int*)d_in[6];
    const int* cols = (const int*)d_in[7];
    const int* user = (const int*)d_in[8];
    const int* pos  = (const int*)d_in[9];
    const int* neg  = (const int*)d_in[10];
    float* out = (float*)d_out;

    char* w = (char*)d_ws;
    float* agg  = (float*)w;  w += (size_t)N_NODES * DIM * 4;   // aliases CSR staging (10MB<12.8MB)
    int* row_ptr = (int*)w;   w += (((size_t)(N_NODES + 1) * 4) + 255) / 256 * 256;
    uint32* csr  = (uint32*)w; w += (size_t)EDGES * 4;
    int* bhist   = (int*)w;   w += (size_t)NBUCK * NABLK * 4;
    int* boffs   = (int*)w;   w += (size_t)NBUCK * NABLK * 4;
    float* dots  = (float*)w; w += (size_t)3 * BATCH * 4;
    float* w1T   = (float*)w; w += (size_t)NLAYER * DIM * DIM * 4;
    float* w2T   = (float*)w; w += (size_t)NLAYER * DIM * DIM * 4;
    ushort* xhA  = (ushort*)w; w += (size_t)N_NODES * DIM * 2;
    ushort* xhB  = (ushort*)w; w += (size_t)N_NODES * DIM * 2;

    int2* staging = (int2*)agg;   // consumed by csr_build before spmm0 writes agg

    hipMemsetAsync(out, 0, 4, stream);

    histprep_kernel<<<HP_TOTAL, 256, 0, stream>>>(rows, bhist, emb, w1_w, w2_w,
                                                  w1T, w2T, xhA, user, pos, neg, dots);
    boffs_kernel<<<NBUCK, 256, 0, stream>>>(bhist, boffs);
    bucket_scatter_kernel<<<NABLK, 256, 0, stream>>>(rows, cols, vals, boffs, staging);
    csr_build_kernel<<<NBUCK, 256, 0, stream>>>(boffs, staging, row_ptr, csr);

    const int NSB = N_NODES / 4;          // 12500
    const int NTB = BATCH / 4;            // 1024 dots tail blocks
    const int NDB = (N_NODES + 63) / 64;  // 782

    // layer 0: spmm gathers xhA (emb mirror); dense x=xhA -> yh=xhB
    spmm_kernel<<<NSB, 256, 0, stream>>>(row_ptr, csr, xhA, agg, user, pos, neg, dots, NSB);
    dense_kernel<<<NDB, 256, 0, stream>>>(xhA, agg, w1T + 0 * 4096, w2T + 0 * 4096,
                                          w1_b + 0 * DIM, w2_b + 0 * DIM, xhB);

    // layer 1: spmm gathers xhB + dots1 tail (layer-1 output = xhB); dense -> xhA
    spmm_kernel<<<NSB + NTB, 256, 0, stream>>>(row_ptr, csr, xhB, agg, user, pos, neg,
                                               dots + BATCH, NSB);
    dense_kernel<<<NDB, 256, 0, stream>>>(xhB, agg, w1T + 1 * 4096, w2T + 1 * 4096,
                                          w1_b + 1 * DIM, w2_b + 1 * DIM, xhA);

    // layer 2: spmm gathers xhA + dots2 tail; dense -> xhB
    spmm_kernel<<<NSB + NTB, 256, 0, stream>>>(row_ptr, csr, xhA, agg, user, pos, neg,
                                               dots + 2 * BATCH, NSB);
    dense_kernel<<<NDB, 256, 0, stream>>>(xhA, agg, w1T + 2 * 4096, w2T + 2 * 4096,
                                          w1_b + 2 * DIM, w2_b + 2 * DIM, xhB);

    dots_loss_kernel<<<NTB, 256, 0, stream>>>(xhB, user, pos, neg, dots, out);
}

// Round 13
// 218.234 us; speedup vs baseline: 1.8438x; 1.0207x over previous
//
#include <hip/hip_runtime.h>
#include <hip/hip_fp16.h>
#include <math.h>

#define N_NODES 50000
#define EDGES   1250000
#define DIM     64
#define NLAYER  3
#define BATCH   4096

#define NBUCK 196   // coarse buckets: bucket = row >> 8 (256 rows each)
#define RPB   256   // rows per bucket
#define NABLK 512   // phase-A blocks

typedef unsigned int uint32;

static __device__ __forceinline__ ushort f2h(float f) {
    return __half_as_ushort(__float2half(f));
}
static __device__ __forceinline__ float h2f(ushort u) {
    return __half2float(__ushort_as_half(u));
}

// ---------------- histprep: bucket hist + W transpose + f2h(emb) + dots0 ----
// blocks [0,512): hist; [512,560): transpose; [560,3685): f2h; [3685,4709): dots0

#define HP_TRANS 512
#define HP_F2H   560
#define HP_DOTS  3685
#define HP_TOTAL 4709

__global__ __launch_bounds__(256) void histprep_kernel(const int* __restrict__ rows,
                                                       int* __restrict__ bhist,
                                                       const float* __restrict__ emb,
                                                       const float* __restrict__ w1,
                                                       const float* __restrict__ w2,
                                                       float* __restrict__ w1T,
                                                       float* __restrict__ w2T,
                                                       ushort* __restrict__ xh,
                                                       const int* __restrict__ user,
                                                       const int* __restrict__ pos,
                                                       const int* __restrict__ neg,
                                                       float* __restrict__ dots,
                                                       float* __restrict__ out) {
    __shared__ int h[NBUCK];
    int blk = blockIdx.x;
    int tid = threadIdx.x;
    if (blk < HP_TRANS) {
        if (blk == 0 && tid == 0) out[0] = 0.f;
        // bucket histogram; bhist layout [bucket][block] (bucket-major)
        for (int i = tid; i < NBUCK; i += 256) h[i] = 0;
        __syncthreads();
        int per = (EDGES + NABLK - 1) / NABLK;
        int e0 = blk * per;
        int e1 = min(e0 + per, EDGES);
        for (int e = e0 + tid; e < e1; e += 256)
            atomicAdd(&h[rows[e] >> 8], 1);
        __syncthreads();
        for (int i = tid; i < NBUCK; i += 256)
            bhist[(size_t)i * NABLK + blk] = h[i];
    } else if (blk < HP_F2H) {
        int i = (blk - HP_TRANS) * 256 + tid;   // < 12288
        int l = i >> 12, r = i & 4095;
        int d = r >> 6, j = r & 63;
        w1T[l * 4096 + j * 64 + d] = w1[i];
        w2T[l * 4096 + j * 64 + d] = w2[i];
    } else if (blk < HP_DOTS) {
        int i = (blk - HP_F2H) * 256 + tid;     // < 800000 exactly
        float4 v = ((const float4*)emb)[i];
        ushort4 hh;
        hh.x = f2h(v.x); hh.y = f2h(v.y); hh.z = f2h(v.z); hh.w = f2h(v.w);
        ((ushort4*)xh)[i] = hh;
    } else {
        int lane = tid & 63;
        int i = (blk - HP_DOTS) * 4 + (tid >> 6);
        int ui = user[i], pi = pos[i], ni = neg[i];
        float u = emb[(size_t)ui * DIM + lane];
        float p = emb[(size_t)pi * DIM + lane];
        float n = emb[(size_t)ni * DIM + lane];
        float v = u * (p - n);
#pragma unroll
        for (int off = 32; off; off >>= 1) v += __shfl_xor(v, off);
        if (lane == 0) dots[i] = v;
    }
}

// ---------------- boffs: per-bucket parallel prefix (self-computed totals) ----
// block b (512 thr): tot[t] = sum_k bhist[t][k]; base_b = excl-scan(tot)[b];
// boffs[b][k] = base_b + excl-scan_k(bhist[b][k]).

__global__ __launch_bounds__(512) void boffs_kernel(const int* __restrict__ bhist,
                                                    int* __restrict__ boffs) {
    __shared__ int sbase[256];
    __shared__ int wred[8];
    int b = blockIdx.x;
    int tid = threadIdx.x;
    int lane = tid & 63, wid = tid >> 6;

    // A: totals per bucket (threads 0..195, contiguous row sums)
    int tot = 0;
    if (tid < NBUCK) {
        const int* p = bhist + (size_t)tid * NABLK;
        for (int k = 0; k < NABLK; ++k) tot += p[k];
    }
    // B: exclusive scan of totals (first 256 threads, 4 waves)
    int sB = tot;
    if (tid < 256) {
#pragma unroll
        for (int off = 1; off < 64; off <<= 1) {
            int tt = __shfl_up(sB, off);
            if (lane >= off) sB += tt;
        }
        if (lane == 63) wred[wid] = sB;
    }
    __syncthreads();
    if (tid == 0) {
        int a = 0;
#pragma unroll
        for (int i = 0; i < 4; ++i) { int tt = wred[i]; wred[i] = a; a += tt; }
    }
    __syncthreads();
    if (tid < 256) sbase[tid] = wred[wid] + sB - tot;
    __syncthreads();
    int base = sbase[b];
    __syncthreads();   // wred reuse barrier

    // C: exclusive scan of this bucket's 512 per-block counts (8 waves)
    int v = bhist[(size_t)b * NABLK + tid];
    int s = v;
#pragma unroll
    for (int off = 1; off < 64; off <<= 1) {
        int tt = __shfl_up(s, off);
        if (lane >= off) s += tt;
    }
    if (lane == 63) wred[wid] = s;
    __syncthreads();
    if (tid == 0) {
        int a = 0;
#pragma unroll
        for (int i = 0; i < 8; ++i) { int tt = wred[i]; wred[i] = a; a += tt; }
    }
    __syncthreads();
    boffs[(size_t)b * NABLK + tid] = base + wred[wid] + s - v;
}

// ---------------- Phase A3: scatter edges into bucket staging ----------------

__global__ __launch_bounds__(256) void bucket_scatter_kernel(const int* __restrict__ rows,
                                                             const int* __restrict__ cols,
                                                             const float* __restrict__ vals,
                                                             const int* __restrict__ boffs,
                                                             int2* __restrict__ staging) {
    __shared__ int cur[NBUCK];
    for (int t = threadIdx.x; t < NBUCK; t += 256)
        cur[t] = boffs[(size_t)t * NABLK + blockIdx.x];
    __syncthreads();
    int per = (EDGES + NABLK - 1) / NABLK;
    int e0 = blockIdx.x * per;
    int e1 = min(e0 + per, EDGES);
    for (int e = e0 + threadIdx.x; e < e1; e += 256) {
        int r = rows[e];
        int p = atomicAdd(&cur[r >> 8], 1);
        staging[p] = make_int2(((r & 255) << 16) | cols[e], __float_as_int(vals[e]));
    }
}

// ---------------- Phase B: per-bucket row_ptr + final 4-byte CSR ----------------

__global__ __launch_bounds__(512) void csr_build_kernel(const int* __restrict__ boffs,
                                                        const int2* __restrict__ staging,
                                                        int* __restrict__ row_ptr,
                                                        uint32* __restrict__ csr) {
    __shared__ int rcur[RPB];
    __shared__ int wred[4];
    int b = blockIdx.x;
    int base = boffs[(size_t)b * NABLK];
    int end = (b == NBUCK - 1) ? EDGES : boffs[(size_t)(b + 1) * NABLK];
    int tid = threadIdx.x;
    int lane = tid & 63, wid = tid >> 6;
    if (tid < RPB) rcur[tid] = 0;
    __syncthreads();
    for (int p = base + tid; p < end; p += 512)
        atomicAdd(&rcur[staging[p].x >> 16], 1);
    __syncthreads();
    int v = 0, s = 0;
    if (tid < RPB) {
        v = rcur[tid];
        s = v;
#pragma unroll
        for (int off = 1; off < 64; off <<= 1) {
            int t = __shfl_up(s, off);
            if (lane >= off) s += t;
        }
        if (lane == 63) wred[wid] = s;
    }
    __syncthreads();
    if (tid == 0) {
        int a = 0;
#pragma unroll
        for (int i = 0; i < 4; ++i) { int t = wred[i]; wred[i] = a; a += t; }
    }
    __syncthreads();
    if (tid < RPB) {
        int excl = wred[wid] + s - v;
        rcur[tid] = base + excl;
        int row = b * RPB + tid;
        if (row < N_NODES) row_ptr[row] = base + excl;
    }
    if (b == NBUCK - 1 && tid == 0) row_ptr[N_NODES] = EDGES;
    __syncthreads();
    for (int p = base + tid; p < end; p += 512) {
        int2 e = staging[p];
        int pos = atomicAdd(&rcur[e.x >> 16], 1);
        csr[pos] = ((uint32)(e.x & 0xFFFF) << 16) | (uint32)f2h(__int_as_float(e.y));
    }
}

// ---------------- SpMM: 8 edge-groups x 8 lanes x uint4 (16B) gathers ----------
// 32-edge unroll (4 CSR words + 4 gathers in flight); dots tail blocks optional.

__global__ __launch_bounds__(256) void spmm_kernel(const int* __restrict__ row_ptr,
                                                   const uint32* __restrict__ csr,
                                                   const ushort* __restrict__ xh,
                                                   float* __restrict__ agg,
                                                   const int* __restrict__ user,
                                                   const int* __restrict__ pos,
                                                   const int* __restrict__ neg,
                                                   float* __restrict__ dots,
                                                   int nsb) {
    int lane = threadIdx.x & 63;
    if ((int)blockIdx.x >= nsb) {
        int i = (blockIdx.x - nsb) * 4 + (threadIdx.x >> 6);
        int ui = user[i], pi = pos[i], ni = neg[i];
        float u = h2f(xh[(size_t)ui * DIM + lane]);
        float p = h2f(xh[(size_t)pi * DIM + lane]);
        float n = h2f(xh[(size_t)ni * DIM + lane]);
        float v = u * (p - n);
#pragma unroll
        for (int off = 32; off; off >>= 1) v += __shfl_xor(v, off);
        if (lane == 0) dots[i] = v;
        return;
    }
    int g = lane >> 3;     // edge group 0..7
    int sl = lane & 7;     // dim octant (8 halves)
    int row = blockIdx.x * 4 + (threadIdx.x >> 6);
    int p0 = row_ptr[row], p1 = row_ptr[row + 1];
    float a0 = 0, a1 = 0, a2 = 0, a3 = 0, a4 = 0, a5 = 0, a6 = 0, a7 = 0;
    int p = p0;
#define SPMM_ACC(E, X)                                                     \
    {                                                                      \
        float vv = h2f((ushort)((E) & 0xFFFF));                            \
        a0 += vv * h2f((ushort)((X).x & 0xFFFF));                          \
        a1 += vv * h2f((ushort)((X).x >> 16));                             \
        a2 += vv * h2f((ushort)((X).y & 0xFFFF));                          \
        a3 += vv * h2f((ushort)((X).y >> 16));                             \
        a4 += vv * h2f((ushort)((X).z & 0xFFFF));                          \
        a5 += vv * h2f((ushort)((X).z >> 16));                             \
        a6 += vv * h2f((ushort)((X).w & 0xFFFF));                          \
        a7 += vv * h2f((ushort)((X).w >> 16));                             \
    }
    for (; p + 32 <= p1; p += 32) {
        uint32 e0 = csr[p + g];
        uint32 e1 = csr[p + 8 + g];
        uint32 e2 = csr[p + 16 + g];
        uint32 e3 = csr[p + 24 + g];
        uint4 x0 = *(const uint4*)(xh + (size_t)(e0 >> 16) * DIM + sl * 8);
        uint4 x1 = *(const uint4*)(xh + (size_t)(e1 >> 16) * DIM + sl * 8);
        uint4 x2 = *(const uint4*)(xh + (size_t)(e2 >> 16) * DIM + sl * 8);
        uint4 x3 = *(const uint4*)(xh + (size_t)(e3 >> 16) * DIM + sl * 8);
        SPMM_ACC(e0, x0);
        SPMM_ACC(e1, x1);
        SPMM_ACC(e2, x2);
        SPMM_ACC(e3, x3);
    }
    for (; p + 8 <= p1; p += 8) {
        uint32 ea = csr[p + g];
        uint4 xa = *(const uint4*)(xh + (size_t)(ea >> 16) * DIM + sl * 8);
        SPMM_ACC(ea, xa);
    }
    if (p + g < p1) {
        uint32 ea = csr[p + g];
        uint4 xa = *(const uint4*)(xh + (size_t)(ea >> 16) * DIM + sl * 8);
        SPMM_ACC(ea, xa);
    }
#undef SPMM_ACC
#pragma unroll
    for (int m = 8; m <= 32; m <<= 1) {
        a0 += __shfl_xor(a0, m); a1 += __shfl_xor(a1, m);
        a2 += __shfl_xor(a2, m); a3 += __shfl_xor(a3, m);
        a4 += __shfl_xor(a4, m); a5 += __shfl_xor(a5, m);
        a6 += __shfl_xor(a6, m); a7 += __shfl_xor(a7, m);
    }
    if (lane < 8) {
        float* dst = agg + (size_t)row * DIM + lane * 8;
        *(float4*)dst = make_float4(a0, a1, a2, a3);
        *(float4*)(dst + 4) = make_float4(a4, a5, a6, a7);
    }
}

// ---------------- Dense layer: GEMM register tiling, fp16 in / fp16 out ----------

__global__ __launch_bounds__(256) void dense_kernel(const ushort* __restrict__ xh_in,
                                                    const float* __restrict__ agg,
                                                    const float* __restrict__ w1T,
                                                    const float* __restrict__ w2T,
                                                    const float* __restrict__ b1,
                                                    const float* __restrict__ b2,
                                                    ushort* __restrict__ yh) {
    __shared__ float xs[64 * 64];
    __shared__ float xc[64 * 64];
    __shared__ float w1s[64 * 64];
    __shared__ float w2s[64 * 64];

    int tid = threadIdx.x;

    for (int f = tid; f < 1024; f += 256) {
        ((float4*)w1s)[f] = ((const float4*)w1T)[f];
        ((float4*)w2s)[f] = ((const float4*)w2T)[f];
    }

    int n0 = blockIdx.x * 64;
    int q = tid & 15;
#pragma unroll
    for (int nn = 0; nn < 4; ++nn) {
        int nl = (tid >> 4) + nn * 16;
        int node = n0 + nl;
        int ncl = (node < N_NODES) ? node : (N_NODES - 1);
        const ushort* xrow = xh_in + (size_t)ncl * DIM;
        const float* arow = agg + (size_t)ncl * DIM;
#pragma unroll
        for (int k = 0; k < 4; ++k) {
            int j = q + 16 * k;
            float xv = h2f(xrow[j]);
            float av = arow[j];
            int idx = j * 64 + (nl ^ ((j & 7) << 2));
            xs[idx] = xv + av;
            xc[idx] = xv;
        }
    }
    __syncthreads();

    int lane = tid & 63, w = tid >> 6;
    int wn = w >> 1, wd = w & 1;
    int r = lane >> 3, c = lane & 7;
    int nb = wn * 32 + r * 4;
    int db = wd * 32 + c * 4;

    float s1[16] = {};
    float s2[16] = {};

#pragma unroll 2
    for (int j = 0; j < 64; ++j) {
        int swz = (j & 7) << 2;
        float4 as4 = *(const float4*)&xs[j * 64 + (nb ^ swz)];
        float4 ac4 = *(const float4*)&xc[j * 64 + (nb ^ swz)];
        float4 bw1 = *(const float4*)&w1s[j * 64 + db];
        float4 bw2 = *(const float4*)&w2s[j * 64 + db];
        float asv[4] = {as4.x, as4.y, as4.z, as4.w};
        float acv[4] = {ac4.x, ac4.y, ac4.z, ac4.w};
        float w1v[4] = {bw1.x, bw1.y, bw1.z, bw1.w};
        float w2v[4] = {bw2.x, bw2.y, bw2.z, bw2.w};
#pragma unroll
        for (int i = 0; i < 4; ++i)
#pragma unroll
            for (int k = 0; k < 4; ++k) {
                s1[i * 4 + k] += asv[i] * w1v[k];
                s2[i * 4 + k] += acv[i] * w2v[k];
            }
    }

    float4 bv1 = *(const float4*)&b1[db];
    float4 bv2 = *(const float4*)&b2[db];
    float bb1[4] = {bv1.x, bv1.y, bv1.z, bv1.w};
    float bb2[4] = {bv2.x, bv2.y, bv2.z, bv2.w};

#pragma unroll
    for (int i = 0; i < 4; ++i) {
        int nl = nb + i;
        int node = n0 + nl;
        float ov[4];
#pragma unroll
        for (int k = 0; k < 4; ++k) {
            int d = db + k;
            int idx = d * 64 + (nl ^ ((d & 7) << 2));
            float ag = xs[idx] - xc[idx];
            float t = s1[i * 4 + k] + bb1[k] + ag * (s2[i * 4 + k] + bb2[k]);
            ov[k] = (t > 0.f) ? t : 0.01f * t;
        }
        if (node < N_NODES) {
            ushort4 ho;
            ho.x = f2h(ov[0]); ho.y = f2h(ov[1]); ho.z = f2h(ov[2]); ho.w = f2h(ov[3]);
            *(ushort4*)&yh[(size_t)node * DIM + db] = ho;
        }
    }
}

// ---------------- dots layer 3 + loss (atomic accumulate) ----------------

__global__ __launch_bounds__(256) void dots_loss_kernel(const ushort* __restrict__ xh,
                                                        const int* __restrict__ user,
                                                        const int* __restrict__ pos,
                                                        const int* __restrict__ neg,
                                                        const float* __restrict__ dots,
                                                        float* __restrict__ out) {
    __shared__ float part[4];
    int tid = threadIdx.x;
    int lane = tid & 63;
    int i = blockIdx.x * 4 + (tid >> 6);
    int ui = user[i], pi = pos[i], ni = neg[i];
    float u = h2f(xh[(size_t)ui * DIM + lane]);
    float p = h2f(xh[(size_t)pi * DIM + lane]);
    float n = h2f(xh[(size_t)ni * DIM + lane]);
    float v = u * (p - n);
#pragma unroll
    for (int off = 32; off; off >>= 1) v += __shfl_xor(v, off);
    if (lane == 0) {
        float d = dots[i] + dots[BATCH + i] + dots[2 * BATCH + i] + v;
        part[tid >> 6] = fmaxf(-d, 0.f) + log1pf(expf(-fabsf(d)));
    }
    __syncthreads();
    if (tid == 0) atomicAdd(out, part[0] + part[1] + part[2] + part[3]);
}

// ---------------- Launch ----------------

extern "C" void kernel_launch(void* const* d_in, const int* in_sizes, int n_in,
                              void* d_out, int out_size, void* d_ws, size_t ws_size,
                              hipStream_t stream) {
    const float* emb  = (const float*)d_in[0];
    const float* w1_w = (const float*)d_in[1];
    const float* w1_b = (const float*)d_in[2];
    const float* w2_w = (const float*)d_in[3];
    const float* w2_b = (const float*)d_in[4];
    const float* vals = (const float*)d_in[5];
    const int* rows = (const int*)d_in[6];
    const int* cols = (const int*)d_in[7];
    const int* user = (const int*)d_in[8];
    const int* pos  = (const int*)d_in[9];
    const int* neg  = (const int*)d_in[10];
    float* out = (float*)d_out;

    char* w = (char*)d_ws;
    float* agg  = (float*)w;  w += (size_t)N_NODES * DIM * 4;   // aliases CSR staging (10MB<12.8MB)
    int* row_ptr = (int*)w;   w += (((size_t)(N_NODES + 1) * 4) + 255) / 256 * 256;
    uint32* csr  = (uint32*)w; w += (size_t)EDGES * 4;
    int* bhist   = (int*)w;   w += (size_t)NBUCK * NABLK * 4;
    int* boffs   = (int*)w;   w += (size_t)NBUCK * NABLK * 4;
    float* dots  = (float*)w; w += (size_t)3 * BATCH * 4;
    float* w1T   = (float*)w; w += (size_t)NLAYER * DIM * DIM * 4;
    float* w2T   = (float*)w; w += (size_t)NLAYER * DIM * DIM * 4;
    ushort* xhA  = (ushort*)w; w += (size_t)N_NODES * DIM * 2;
    ushort* xhB  = (ushort*)w; w += (size_t)N_NODES * DIM * 2;

    int2* staging = (int2*)agg;   // consumed by csr_build before spmm0 writes agg

    histprep_kernel<<<HP_TOTAL, 256, 0, stream>>>(rows, bhist, emb, w1_w, w2_w,
                                                  w1T, w2T, xhA, user, pos, neg, dots, out);
    boffs_kernel<<<NBUCK, 512, 0, stream>>>(bhist, boffs);
    bucket_scatter_kernel<<<NABLK, 256, 0, stream>>>(rows, cols, vals, boffs, staging);
    csr_build_kernel<<<NBUCK, 512, 0, stream>>>(boffs, staging, row_ptr, csr);

    const int NSB = N_NODES / 4;          // 12500
    const int NTB = BATCH / 4;            // 1024 dots tail blocks
    const int NDB = (N_NODES + 63) / 64;  // 782

    // layer 0: spmm gathers xhA (emb mirror); dense x=xhA -> yh=xhB
    spmm_kernel<<<NSB, 256, 0, stream>>>(row_ptr, csr, xhA, agg, user, pos, neg, dots, NSB);
    dense_kernel<<<NDB, 256, 0, stream>>>(xhA, agg, w1T + 0 * 4096, w2T + 0 * 4096,
                                          w1_b + 0 * DIM, w2_b + 0 * DIM, xhB);

    // layer 1: spmm gathers xhB + dots1 tail; dense -> xhA
    spmm_kernel<<<NSB + NTB, 256, 0, stream>>>(row_ptr, csr, xhB, agg, user, pos, neg,
                                               dots + BATCH, NSB);
    dense_kernel<<<NDB, 256, 0, stream>>>(xhB, agg, w1T + 1 * 4096, w2T + 1 * 4096,
                                          w1_b + 1 * DIM, w2_b + 1 * DIM, xhA);

    // layer 2: spmm gathers xhA + dots2 tail; dense -> xhB
    spmm_kernel<<<NSB + NTB, 256, 0, stream>>>(row_ptr, csr, xhA, agg, user, pos, neg,
                                               dots + 2 * BATCH, NSB);
    dense_kernel<<<NDB, 256, 0, stream>>>(xhA, agg, w1T + 2 * 4096, w2T + 2 * 4096,
                                          w1_b + 2 * DIM, w2_b + 2 * DIM, xhB);

    dots_loss_kernel<<<NTB, 256, 0, stream>>>(xhB, user, pos, neg, dots, out);
}

// Round 14
// 183.015 us; speedup vs baseline: 2.1986x; 1.1924x over previous
//
#include <hip/hip_runtime.h>
#include <hip/hip_fp16.h>
#include <math.h>

#define N_NODES 50000
#define EDGES   1250000
#define DIM     64
#define NLAYER  3
#define BATCH   4096

#define NBUCK 196   // coarse buckets: bucket = row >> 8 (256 rows each)
#define RPB   256   // rows per bucket
#define NABLK 512   // phase-A blocks

typedef unsigned int uint32;
typedef _Float16 f16x8 __attribute__((ext_vector_type(8)));
typedef float f32x4 __attribute__((ext_vector_type(4)));

static __device__ __forceinline__ ushort f2h(float f) {
    return __half_as_ushort(__float2half(f));
}
static __device__ __forceinline__ float h2f(ushort u) {
    return __half2float(__ushort_as_half(u));
}

// ---------------- histprep: bucket hist + f2h(emb) + dots0 ----------------
// blocks [0,512): hist; [512,3637): f2h; [3637,4661): dots0

#define HP_F2H   512
#define HP_DOTS  3637
#define HP_TOTAL 4661

__global__ __launch_bounds__(256) void histprep_kernel(const int* __restrict__ rows,
                                                       int* __restrict__ bhist,
                                                       const float* __restrict__ emb,
                                                       ushort* __restrict__ xh,
                                                       const int* __restrict__ user,
                                                       const int* __restrict__ pos,
                                                       const int* __restrict__ neg,
                                                       float* __restrict__ dots,
                                                       float* __restrict__ out) {
    __shared__ int h[NBUCK];
    int blk = blockIdx.x;
    int tid = threadIdx.x;
    if (blk < HP_F2H) {
        if (blk == 0 && tid == 0) out[0] = 0.f;
        for (int i = tid; i < NBUCK; i += 256) h[i] = 0;
        __syncthreads();
        int per = (EDGES + NABLK - 1) / NABLK;
        int e0 = blk * per;
        int e1 = min(e0 + per, EDGES);
        for (int e = e0 + tid; e < e1; e += 256)
            atomicAdd(&h[rows[e] >> 8], 1);
        __syncthreads();
        for (int i = tid; i < NBUCK; i += 256)
            bhist[(size_t)i * NABLK + blk] = h[i];
    } else if (blk < HP_DOTS) {
        int i = (blk - HP_F2H) * 256 + tid;     // < 800000 exactly
        float4 v = ((const float4*)emb)[i];
        ushort4 hh;
        hh.x = f2h(v.x); hh.y = f2h(v.y); hh.z = f2h(v.z); hh.w = f2h(v.w);
        ((ushort4*)xh)[i] = hh;
    } else {
        int lane = tid & 63;
        int i = (blk - HP_DOTS) * 4 + (tid >> 6);
        int ui = user[i], pi = pos[i], ni = neg[i];
        float u = emb[(size_t)ui * DIM + lane];
        float p = emb[(size_t)pi * DIM + lane];
        float n = emb[(size_t)ni * DIM + lane];
        float v = u * (p - n);
#pragma unroll
        for (int off = 32; off; off >>= 1) v += __shfl_xor(v, off);
        if (lane == 0) dots[i] = v;
    }
}

// ---------------- boffs: per-bucket parallel prefix ----------------

__global__ __launch_bounds__(512) void boffs_kernel(const int* __restrict__ bhist,
                                                    int* __restrict__ boffs) {
    __shared__ int sbase[256];
    __shared__ int wred[8];
    int b = blockIdx.x;
    int tid = threadIdx.x;
    int lane = tid & 63, wid = tid >> 6;

    int tot = 0;
    if (tid < NBUCK) {
        const int* p = bhist + (size_t)tid * NABLK;
        for (int k = 0; k < NABLK; ++k) tot += p[k];
    }
    int sB = tot;
    if (tid < 256) {
#pragma unroll
        for (int off = 1; off < 64; off <<= 1) {
            int tt = __shfl_up(sB, off);
            if (lane >= off) sB += tt;
        }
        if (lane == 63) wred[wid] = sB;
    }
    __syncthreads();
    if (tid == 0) {
        int a = 0;
#pragma unroll
        for (int i = 0; i < 4; ++i) { int tt = wred[i]; wred[i] = a; a += tt; }
    }
    __syncthreads();
    if (tid < 256) sbase[tid] = wred[wid] + sB - tot;
    __syncthreads();
    int base = sbase[b];
    __syncthreads();

    int v = bhist[(size_t)b * NABLK + tid];
    int s = v;
#pragma unroll
    for (int off = 1; off < 64; off <<= 1) {
        int tt = __shfl_up(s, off);
        if (lane >= off) s += tt;
    }
    if (lane == 63) wred[wid] = s;
    __syncthreads();
    if (tid == 0) {
        int a = 0;
#pragma unroll
        for (int i = 0; i < 8; ++i) { int tt = wred[i]; wred[i] = a; a += tt; }
    }
    __syncthreads();
    boffs[(size_t)b * NABLK + tid] = base + wred[wid] + s - v;
}

// ---------------- Phase A3: scatter edges into bucket staging ----------------

__global__ __launch_bounds__(256) void bucket_scatter_kernel(const int* __restrict__ rows,
                                                             const int* __restrict__ cols,
                                                             const float* __restrict__ vals,
                                                             const int* __restrict__ boffs,
                                                             int2* __restrict__ staging) {
    __shared__ int cur[NBUCK];
    for (int t = threadIdx.x; t < NBUCK; t += 256)
        cur[t] = boffs[(size_t)t * NABLK + blockIdx.x];
    __syncthreads();
    int per = (EDGES + NABLK - 1) / NABLK;
    int e0 = blockIdx.x * per;
    int e1 = min(e0 + per, EDGES);
    for (int e = e0 + threadIdx.x; e < e1; e += 256) {
        int r = rows[e];
        int p = atomicAdd(&cur[r >> 8], 1);
        staging[p] = make_int2(((r & 255) << 16) | cols[e], __float_as_int(vals[e]));
    }
}

// ---------------- Phase B: per-bucket row_ptr + final 4-byte CSR ----------------

__global__ __launch_bounds__(512) void csr_build_kernel(const int* __restrict__ boffs,
                                                        const int2* __restrict__ staging,
                                                        int* __restrict__ row_ptr,
                                                        uint32* __restrict__ csr) {
    __shared__ int rcur[RPB];
    __shared__ int wred[4];
    int b = blockIdx.x;
    int base = boffs[(size_t)b * NABLK];
    int end = (b == NBUCK - 1) ? EDGES : boffs[(size_t)(b + 1) * NABLK];
    int tid = threadIdx.x;
    int lane = tid & 63, wid = tid >> 6;
    if (tid < RPB) rcur[tid] = 0;
    __syncthreads();
    for (int p = base + tid; p < end; p += 512)
        atomicAdd(&rcur[staging[p].x >> 16], 1);
    __syncthreads();
    int v = 0, s = 0;
    if (tid < RPB) {
        v = rcur[tid];
        s = v;
#pragma unroll
        for (int off = 1; off < 64; off <<= 1) {
            int t = __shfl_up(s, off);
            if (lane >= off) s += t;
        }
        if (lane == 63) wred[wid] = s;
    }
    __syncthreads();
    if (tid == 0) {
        int a = 0;
#pragma unroll
        for (int i = 0; i < 4; ++i) { int t = wred[i]; wred[i] = a; a += t; }
    }
    __syncthreads();
    if (tid < RPB) {
        int excl = wred[wid] + s - v;
        rcur[tid] = base + excl;
        int row = b * RPB + tid;
        if (row < N_NODES) row_ptr[row] = base + excl;
    }
    if (b == NBUCK - 1 && tid == 0) row_ptr[N_NODES] = EDGES;
    __syncthreads();
    for (int p = base + tid; p < end; p += 512) {
        int2 e = staging[p];
        int pos = atomicAdd(&rcur[e.x >> 16], 1);
        csr[pos] = ((uint32)(e.x & 0xFFFF) << 16) | (uint32)f2h(__int_as_float(e.y));
    }
}

// ---------------- SpMM: 8 edge-groups x 8 lanes x uint4 (16B) gathers ----------

__global__ __launch_bounds__(256) void spmm_kernel(const int* __restrict__ row_ptr,
                                                   const uint32* __restrict__ csr,
                                                   const ushort* __restrict__ xh,
                                                   float* __restrict__ agg,
                                                   const int* __restrict__ user,
                                                   const int* __restrict__ pos,
                                                   const int* __restrict__ neg,
                                                   float* __restrict__ dots,
                                                   int nsb) {
    int lane = threadIdx.x & 63;
    if ((int)blockIdx.x >= nsb) {
        int i = (blockIdx.x - nsb) * 4 + (threadIdx.x >> 6);
        int ui = user[i], pi = pos[i], ni = neg[i];
        float u = h2f(xh[(size_t)ui * DIM + lane]);
        float p = h2f(xh[(size_t)pi * DIM + lane]);
        float n = h2f(xh[(size_t)ni * DIM + lane]);
        float v = u * (p - n);
#pragma unroll
        for (int off = 32; off; off >>= 1) v += __shfl_xor(v, off);
        if (lane == 0) dots[i] = v;
        return;
    }
    int g = lane >> 3;
    int sl = lane & 7;
    int row = blockIdx.x * 4 + (threadIdx.x >> 6);
    int p0 = row_ptr[row], p1 = row_ptr[row + 1];
    float a0 = 0, a1 = 0, a2 = 0, a3 = 0, a4 = 0, a5 = 0, a6 = 0, a7 = 0;
    int p = p0;
#define SPMM_ACC(E, X)                                                     \
    {                                                                      \
        float vv = h2f((ushort)((E) & 0xFFFF));                            \
        a0 += vv * h2f((ushort)((X).x & 0xFFFF));                          \
        a1 += vv * h2f((ushort)((X).x >> 16));                             \
        a2 += vv * h2f((ushort)((X).y & 0xFFFF));                          \
        a3 += vv * h2f((ushort)((X).y >> 16));                             \
        a4 += vv * h2f((ushort)((X).z & 0xFFFF));                          \
        a5 += vv * h2f((ushort)((X).z >> 16));                             \
        a6 += vv * h2f((ushort)((X).w & 0xFFFF));                          \
        a7 += vv * h2f((ushort)((X).w >> 16));                             \
    }
    for (; p + 32 <= p1; p += 32) {
        uint32 e0 = csr[p + g];
        uint32 e1 = csr[p + 8 + g];
        uint32 e2 = csr[p + 16 + g];
        uint32 e3 = csr[p + 24 + g];
        uint4 x0 = *(const uint4*)(xh + (size_t)(e0 >> 16) * DIM + sl * 8);
        uint4 x1 = *(const uint4*)(xh + (size_t)(e1 >> 16) * DIM + sl * 8);
        uint4 x2 = *(const uint4*)(xh + (size_t)(e2 >> 16) * DIM + sl * 8);
        uint4 x3 = *(const uint4*)(xh + (size_t)(e3 >> 16) * DIM + sl * 8);
        SPMM_ACC(e0, x0);
        SPMM_ACC(e1, x1);
        SPMM_ACC(e2, x2);
        SPMM_ACC(e3, x3);
    }
    for (; p + 8 <= p1; p += 8) {
        uint32 ea = csr[p + g];
        uint4 xa = *(const uint4*)(xh + (size_t)(ea >> 16) * DIM + sl * 8);
        SPMM_ACC(ea, xa);
    }
    if (p + g < p1) {
        uint32 ea = csr[p + g];
        uint4 xa = *(const uint4*)(xh + (size_t)(ea >> 16) * DIM + sl * 8);
        SPMM_ACC(ea, xa);
    }
#undef SPMM_ACC
#pragma unroll
    for (int m = 8; m <= 32; m <<= 1) {
        a0 += __shfl_xor(a0, m); a1 += __shfl_xor(a1, m);
        a2 += __shfl_xor(a2, m); a3 += __shfl_xor(a3, m);
        a4 += __shfl_xor(a4, m); a5 += __shfl_xor(a5, m);
        a6 += __shfl_xor(a6, m); a7 += __shfl_xor(a7, m);
    }
    if (lane < 8) {
        float* dst = agg + (size_t)row * DIM + lane * 8;
        *(float4*)dst = make_float4(a0, a1, a2, a3);
        *(float4*)(dst + 4) = make_float4(a4, a5, a6, a7);
    }
}

// ---------------- Dense layer: fp16 MFMA (16x16x32), f32 accumulate ----------
// Block = 64 nodes x 64 dims, 4 waves; wave w owns node band [w*16, w*16+16).
// LDS tiles fp16 [row][64] with 16B-block XOR swizzle blk^=(row&7):
//   xs[n][j] = fp16(agg+x), xc[n][j] = x, w1s/w2s[d][j] from original W layout.
// s1 tile = A(xs) @ B(w1), s2 = A(xc) @ B(w2); epilogue agg = xs - xc.

__global__ __launch_bounds__(256) void dense_kernel(const ushort* __restrict__ xh_in,
                                                    const float* __restrict__ agg,
                                                    const float* __restrict__ w1,
                                                    const float* __restrict__ w2,
                                                    const float* __restrict__ b1,
                                                    const float* __restrict__ b2,
                                                    ushort* __restrict__ yh) {
    __shared__ ushort xs[64 * 64];
    __shared__ ushort xc[64 * 64];
    __shared__ ushort w1s[64 * 64];
    __shared__ ushort w2s[64 * 64];

    int tid = threadIdx.x;
    int n0 = blockIdx.x * 64;

    // ---- staging: thread -> row r = tid>>2, 16 elems at jq = (tid&3)*16 ----
    {
        int rr = tid >> 2;
        int jq = (tid & 3) << 4;
        int sw = rr & 7;
        int b0 = jq >> 3;            // first 8-elem block index
        int o0 = rr * 64 + (((b0 + 0) ^ sw) << 3);
        int o1 = rr * 64 + (((b0 + 1) ^ sw) << 3);

        // W1/W2: read f32 [d][j] directly (original layout), convert
        {
            const float* w1r = w1 + rr * 64 + jq;
            const float* w2r = w2 + rr * 64 + jq;
            ushort t1[16], t2[16];
#pragma unroll
            for (int k = 0; k < 4; ++k) {
                float4 a = ((const float4*)w1r)[k];
                float4 b = ((const float4*)w2r)[k];
                t1[k * 4 + 0] = f2h(a.x); t1[k * 4 + 1] = f2h(a.y);
                t1[k * 4 + 2] = f2h(a.z); t1[k * 4 + 3] = f2h(a.w);
                t2[k * 4 + 0] = f2h(b.x); t2[k * 4 + 1] = f2h(b.y);
                t2[k * 4 + 2] = f2h(b.z); t2[k * 4 + 3] = f2h(b.w);
            }
            *(uint4*)&w1s[o0] = *(uint4*)&t1[0];
            *(uint4*)&w1s[o1] = *(uint4*)&t1[8];
            *(uint4*)&w2s[o0] = *(uint4*)&t2[0];
            *(uint4*)&w2s[o1] = *(uint4*)&t2[8];
        }
        // xs/xc
        {
            int node = n0 + rr;
            int ncl = (node < N_NODES) ? node : (N_NODES - 1);
            const float* ar = agg + (size_t)ncl * DIM + jq;
            const ushort* xr = xh_in + (size_t)ncl * DIM + jq;
            ushort txs[16], txc[16];
#pragma unroll
            for (int k = 0; k < 2; ++k) {
                uint4 xv = ((const uint4*)xr)[k];
                uint32 xw[4] = {xv.x, xv.y, xv.z, xv.w};
#pragma unroll
                for (int q = 0; q < 4; ++q) {
                    ushort lo = (ushort)(xw[q] & 0xFFFF);
                    ushort hi = (ushort)(xw[q] >> 16);
                    int e = k * 8 + q * 2;
                    txc[e] = lo; txc[e + 1] = hi;
                    txs[e] = f2h(h2f(lo) + ar[e]);
                    txs[e + 1] = f2h(h2f(hi) + ar[e + 1]);
                }
            }
            *(uint4*)&xs[o0] = *(uint4*)&txs[0];
            *(uint4*)&xs[o1] = *(uint4*)&txs[8];
            *(uint4*)&xc[o0] = *(uint4*)&txc[0];
            *(uint4*)&xc[o1] = *(uint4*)&txc[8];
        }
    }
    __syncthreads();

    int lane = tid & 63, w = tid >> 6;
    int nb = w << 4;               // wave's 16-node band
    int lm = lane & 15;            // A-row (node) / B-col (d) / D-col (d)
    int le = lane >> 4;            // k-group

    // A fragments: node = nb+lm, j = k*32 + le*8 .. +8
    f16x8 axs[2], axc[2];
#pragma unroll
    for (int k = 0; k < 2; ++k) {
        int n = nb + lm;
        int blk = k * 4 + le;
        int off = n * 64 + ((blk ^ (n & 7)) << 3);
        axs[k] = *(const f16x8*)&xs[off];
        axc[k] = *(const f16x8*)&xc[off];
    }

#pragma unroll
    for (int dt = 0; dt < 4; ++dt) {
        int d = dt * 16 + lm;
        f16x8 bf1[2], bf2[2];
#pragma unroll
        for (int k = 0; k < 2; ++k) {
            int blk = k * 4 + le;
            int off = d * 64 + ((blk ^ (d & 7)) << 3);
            bf1[k] = *(const f16x8*)&w1s[off];
            bf2[k] = *(const f16x8*)&w2s[off];
        }
        f32x4 acc1 = {0.f, 0.f, 0.f, 0.f};
        f32x4 acc2 = {0.f, 0.f, 0.f, 0.f};
        acc1 = __builtin_amdgcn_mfma_f32_16x16x32_f16(axs[0], bf1[0], acc1, 0, 0, 0);
        acc1 = __builtin_amdgcn_mfma_f32_16x16x32_f16(axs[1], bf1[1], acc1, 0, 0, 0);
        acc2 = __builtin_amdgcn_mfma_f32_16x16x32_f16(axc[0], bf2[0], acc2, 0, 0, 0);
        acc2 = __builtin_amdgcn_mfma_f32_16x16x32_f16(axc[1], bf2[1], acc2, 0, 0, 0);

        float b1v = b1[d], b2v = b2[d];
        int bb = d >> 3;
#pragma unroll
        for (int i = 0; i < 4; ++i) {
            int nl = nb + (le << 2) + i;       // D row = (lane>>4)*4 + i
            int node = n0 + nl;
            int off = nl * 64 + ((bb ^ (nl & 7)) << 3) + (d & 7);
            float ag = h2f(xs[off]) - h2f(xc[off]);
            float t = acc1[i] + b1v + ag * (acc2[i] + b2v);
            t = (t > 0.f) ? t : 0.01f * t;
            if (node < N_NODES) yh[(size_t)node * DIM + d] = f2h(t);
        }
    }
}

// ---------------- dots layer 3 + loss (atomic accumulate) ----------------

__global__ __launch_bounds__(256) void dots_loss_kernel(const ushort* __restrict__ xh,
                                                        const int* __restrict__ user,
                                                        const int* __restrict__ pos,
                                                        const int* __restrict__ neg,
                                                        const float* __restrict__ dots,
                                                        float* __restrict__ out) {
    __shared__ float part[4];
    int tid = threadIdx.x;
    int lane = tid & 63;
    int i = blockIdx.x * 4 + (tid >> 6);
    int ui = user[i], pi = pos[i], ni = neg[i];
    float u = h2f(xh[(size_t)ui * DIM + lane]);
    float p = h2f(xh[(size_t)pi * DIM + lane]);
    float n = h2f(xh[(size_t)ni * DIM + lane]);
    float v = u * (p - n);
#pragma unroll
    for (int off = 32; off; off >>= 1) v += __shfl_xor(v, off);
    if (lane == 0) {
        float d = dots[i] + dots[BATCH + i] + dots[2 * BATCH + i] + v;
        part[tid >> 6] = fmaxf(-d, 0.f) + log1pf(expf(-fabsf(d)));
    }
    __syncthreads();
    if (tid == 0) atomicAdd(out, part[0] + part[1] + part[2] + part[3]);
}

// ---------------- Launch ----------------

extern "C" void kernel_launch(void* const* d_in, const int* in_sizes, int n_in,
                              void* d_out, int out_size, void* d_ws, size_t ws_size,
                              hipStream_t stream) {
    const float* emb  = (const float*)d_in[0];
    const float* w1_w = (const float*)d_in[1];
    const float* w1_b = (const float*)d_in[2];
    const float* w2_w = (const float*)d_in[3];
    const float* w2_b = (const float*)d_in[4];
    const float* vals = (const float*)d_in[5];
    const int* rows = (const int*)d_in[6];
    const int* cols = (const int*)d_in[7];
    const int* user = (const int*)d_in[8];
    const int* pos  = (const int*)d_in[9];
    const int* neg  = (const int*)d_in[10];
    float* out = (float*)d_out;

    char* w = (char*)d_ws;
    float* agg  = (float*)w;  w += (size_t)N_NODES * DIM * 4;   // aliases CSR staging
    int* row_ptr = (int*)w;   w += (((size_t)(N_NODES + 1) * 4) + 255) / 256 * 256;
    uint32* csr  = (uint32*)w; w += (size_t)EDGES * 4;
    int* bhist   = (int*)w;   w += (size_t)NBUCK * NABLK * 4;
    int* boffs   = (int*)w;   w += (size_t)NBUCK * NABLK * 4;
    float* dots  = (float*)w; w += (size_t)3 * BATCH * 4;
    ushort* xhA  = (ushort*)w; w += (size_t)N_NODES * DIM * 2;
    ushort* xhB  = (ushort*)w; w += (size_t)N_NODES * DIM * 2;

    int2* staging = (int2*)agg;   // consumed by csr_build before spmm0 writes agg

    histprep_kernel<<<HP_TOTAL, 256, 0, stream>>>(rows, bhist, emb, xhA,
                                                  user, pos, neg, dots, out);
    boffs_kernel<<<NBUCK, 512, 0, stream>>>(bhist, boffs);
    bucket_scatter_kernel<<<NABLK, 256, 0, stream>>>(rows, cols, vals, boffs, staging);
    csr_build_kernel<<<NBUCK, 512, 0, stream>>>(boffs, staging, row_ptr, csr);

    const int NSB = N_NODES / 4;          // 12500
    const int NTB = BATCH / 4;            // 1024
    const int NDB = (N_NODES + 63) / 64;  // 782

    // layer 0
    spmm_kernel<<<NSB, 256, 0, stream>>>(row_ptr, csr, xhA, agg, user, pos, neg, dots, NSB);
    dense_kernel<<<NDB, 256, 0, stream>>>(xhA, agg, w1_w + 0 * 4096, w2_w + 0 * 4096,
                                          w1_b + 0 * DIM, w2_b + 0 * DIM, xhB);
    // layer 1 (+ dots1 tail on xhB)
    spmm_kernel<<<NSB + NTB, 256, 0, stream>>>(row_ptr, csr, xhB, agg, user, pos, neg,
                                               dots + BATCH, NSB);
    dense_kernel<<<NDB, 256, 0, stream>>>(xhB, agg, w1_w + 1 * 4096, w2_w + 1 * 4096,
                                          w1_b + 1 * DIM, w2_b + 1 * DIM, xhA);
    // layer 2 (+ dots2 tail on xhA)
    spmm_kernel<<<NSB + NTB, 256, 0, stream>>>(row_ptr, csr, xhA, agg, user, pos, neg,
                                               dots + 2 * BATCH, NSB);
    dense_kernel<<<NDB, 256, 0, stream>>>(xhA, agg, w1_w + 2 * 4096, w2_w + 2 * 4096,
                                          w1_b + 2 * DIM, w2_b + 2 * DIM, xhB);

    dots_loss_kernel<<<NTB, 256, 0, stream>>>(xhB, user, pos, neg, dots, out);
}

// Round 15
// 177.636 us; speedup vs baseline: 2.2651x; 1.0303x over previous
//
#include <hip/hip_runtime.h>
#include <hip/hip_fp16.h>
#include <math.h>

#define N_NODES 50000
#define EDGES   1250000
#define DIM     64
#define NLAYER  3
#define BATCH   4096

#define NBUCK 196   // coarse buckets: bucket = row >> 8 (256 rows each)
#define RPB   256   // rows per bucket
#define NABLK 512   // phase-A blocks
#define BCAP  7424  // LDS bucket cache (58 KB); mean bucket 6377, +13 sigma

typedef unsigned int uint32;
typedef _Float16 f16x8 __attribute__((ext_vector_type(8)));
typedef float f32x4 __attribute__((ext_vector_type(4)));

static __device__ __forceinline__ ushort f2h(float f) {
    return __half_as_ushort(__float2half(f));
}
static __device__ __forceinline__ float h2f(ushort u) {
    return __half2float(__ushort_as_half(u));
}

// ---------------- histprep: bucket hist + f2h(emb) + dots0 ----------------
// blocks [0,512): hist; [512,3637): f2h; [3637,4661): dots0

#define HP_F2H   512
#define HP_DOTS  3637
#define HP_TOTAL 4661

__global__ __launch_bounds__(256) void histprep_kernel(const int* __restrict__ rows,
                                                       int* __restrict__ bhist,
                                                       const float* __restrict__ emb,
                                                       ushort* __restrict__ xh,
                                                       const int* __restrict__ user,
                                                       const int* __restrict__ pos,
                                                       const int* __restrict__ neg,
                                                       float* __restrict__ dots,
                                                       float* __restrict__ out) {
    __shared__ int h[NBUCK];
    int blk = blockIdx.x;
    int tid = threadIdx.x;
    if (blk < HP_F2H) {
        if (blk == 0 && tid == 0) out[0] = 0.f;
        for (int i = tid; i < NBUCK; i += 256) h[i] = 0;
        __syncthreads();
        int per = (EDGES + NABLK - 1) / NABLK;
        int e0 = blk * per;
        int e1 = min(e0 + per, EDGES);
        for (int e = e0 + tid; e < e1; e += 256)
            atomicAdd(&h[rows[e] >> 8], 1);
        __syncthreads();
        for (int i = tid; i < NBUCK; i += 256)
            bhist[(size_t)i * NABLK + blk] = h[i];
    } else if (blk < HP_DOTS) {
        int i = (blk - HP_F2H) * 256 + tid;     // < 800000 exactly
        float4 v = ((const float4*)emb)[i];
        ushort4 hh;
        hh.x = f2h(v.x); hh.y = f2h(v.y); hh.z = f2h(v.z); hh.w = f2h(v.w);
        ((ushort4*)xh)[i] = hh;
    } else {
        int lane = tid & 63;
        int i = (blk - HP_DOTS) * 4 + (tid >> 6);
        int ui = user[i], pi = pos[i], ni = neg[i];
        float u = emb[(size_t)ui * DIM + lane];
        float p = emb[(size_t)pi * DIM + lane];
        float n = emb[(size_t)ni * DIM + lane];
        float v = u * (p - n);
#pragma unroll
        for (int off = 32; off; off >>= 1) v += __shfl_xor(v, off);
        if (lane == 0) dots[i] = v;
    }
}

// ---------------- boffs: per-bucket parallel prefix ----------------

__global__ __launch_bounds__(512) void boffs_kernel(const int* __restrict__ bhist,
                                                    int* __restrict__ boffs) {
    __shared__ int sbase[256];
    __shared__ int wred[8];
    int b = blockIdx.x;
    int tid = threadIdx.x;
    int lane = tid & 63, wid = tid >> 6;

    int tot = 0;
    if (tid < NBUCK) {
        const int* p = bhist + (size_t)tid * NABLK;
        for (int k = 0; k < NABLK; ++k) tot += p[k];
    }
    int sB = tot;
    if (tid < 256) {
#pragma unroll
        for (int off = 1; off < 64; off <<= 1) {
            int tt = __shfl_up(sB, off);
            if (lane >= off) sB += tt;
        }
        if (lane == 63) wred[wid] = sB;
    }
    __syncthreads();
    if (tid == 0) {
        int a = 0;
#pragma unroll
        for (int i = 0; i < 4; ++i) { int tt = wred[i]; wred[i] = a; a += tt; }
    }
    __syncthreads();
    if (tid < 256) sbase[tid] = wred[wid] + sB - tot;
    __syncthreads();
    int base = sbase[b];
    __syncthreads();

    int v = bhist[(size_t)b * NABLK + tid];
    int s = v;
#pragma unroll
    for (int off = 1; off < 64; off <<= 1) {
        int tt = __shfl_up(s, off);
        if (lane >= off) s += tt;
    }
    if (lane == 63) wred[wid] = s;
    __syncthreads();
    if (tid == 0) {
        int a = 0;
#pragma unroll
        for (int i = 0; i < 8; ++i) { int tt = wred[i]; wred[i] = a; a += tt; }
    }
    __syncthreads();
    boffs[(size_t)b * NABLK + tid] = base + wred[wid] + s - v;
}

// ---------------- Phase A3: scatter edges into bucket staging ----------------

__global__ __launch_bounds__(256) void bucket_scatter_kernel(const int* __restrict__ rows,
                                                             const int* __restrict__ cols,
                                                             const float* __restrict__ vals,
                                                             const int* __restrict__ boffs,
                                                             int2* __restrict__ staging) {
    __shared__ int cur[NBUCK];
    for (int t = threadIdx.x; t < NBUCK; t += 256)
        cur[t] = boffs[(size_t)t * NABLK + blockIdx.x];
    __syncthreads();
    int per = (EDGES + NABLK - 1) / NABLK;
    int e0 = blockIdx.x * per;
    int e1 = min(e0 + per, EDGES);
    for (int e = e0 + threadIdx.x; e < e1; e += 256) {
        int r = rows[e];
        int p = atomicAdd(&cur[r >> 8], 1);
        staging[p] = make_int2(((r & 255) << 16) | cols[e], __float_as_int(vals[e]));
    }
}

// ---------------- Phase B: LDS-cached bucket -> row_ptr + 4-byte CSR ----------

__global__ __launch_bounds__(512) void csr_build_kernel(const int* __restrict__ boffs,
                                                        const int2* __restrict__ staging,
                                                        int* __restrict__ row_ptr,
                                                        uint32* __restrict__ csr) {
    __shared__ int2 sedge[BCAP];
    __shared__ int rcur[RPB];
    __shared__ int wred[4];
    int b = blockIdx.x;
    int base = boffs[(size_t)b * NABLK];
    int end = (b == NBUCK - 1) ? EDGES : boffs[(size_t)(b + 1) * NABLK];
    int cnt = end - base;
    bool inlds = (cnt <= BCAP);
    int tid = threadIdx.x;
    int lane = tid & 63, wid = tid >> 6;
    if (tid < RPB) rcur[tid] = 0;
    __syncthreads();
    if (inlds) {
        for (int p = tid; p < cnt; p += 512) {
            int2 e = staging[base + p];
            sedge[p] = e;
            atomicAdd(&rcur[e.x >> 16], 1);
        }
    } else {
        for (int p = base + tid; p < end; p += 512)
            atomicAdd(&rcur[staging[p].x >> 16], 1);
    }
    __syncthreads();
    int v = 0, s = 0;
    if (tid < RPB) {
        v = rcur[tid];
        s = v;
#pragma unroll
        for (int off = 1; off < 64; off <<= 1) {
            int t = __shfl_up(s, off);
            if (lane >= off) s += t;
        }
        if (lane == 63) wred[wid] = s;
    }
    __syncthreads();
    if (tid == 0) {
        int a = 0;
#pragma unroll
        for (int i = 0; i < 4; ++i) { int t = wred[i]; wred[i] = a; a += t; }
    }
    __syncthreads();
    if (tid < RPB) {
        int excl = wred[wid] + s - v;
        rcur[tid] = base + excl;
        int row = b * RPB + tid;
        if (row < N_NODES) row_ptr[row] = base + excl;
    }
    if (b == NBUCK - 1 && tid == 0) row_ptr[N_NODES] = EDGES;
    __syncthreads();
    if (inlds) {
        for (int p = tid; p < cnt; p += 512) {
            int2 e = sedge[p];
            int pos = atomicAdd(&rcur[e.x >> 16], 1);
            csr[pos] = ((uint32)(e.x & 0xFFFF) << 16) | (uint32)f2h(__int_as_float(e.y));
        }
    } else {
        for (int p = base + tid; p < end; p += 512) {
            int2 e = staging[p];
            int pos = atomicAdd(&rcur[e.x >> 16], 1);
            csr[pos] = ((uint32)(e.x & 0xFFFF) << 16) | (uint32)f2h(__int_as_float(e.y));
        }
    }
}

// ---------------- SpMM: 8 edge-groups x 8 lanes x uint4 gathers, fp16 agg out ----

__global__ __launch_bounds__(256) void spmm_kernel(const int* __restrict__ row_ptr,
                                                   const uint32* __restrict__ csr,
                                                   const ushort* __restrict__ xh,
                                                   ushort* __restrict__ aggh,
                                                   const int* __restrict__ user,
                                                   const int* __restrict__ pos,
                                                   const int* __restrict__ neg,
                                                   float* __restrict__ dots,
                                                   int nsb) {
    int lane = threadIdx.x & 63;
    if ((int)blockIdx.x >= nsb) {
        int i = (blockIdx.x - nsb) * 4 + (threadIdx.x >> 6);
        int ui = user[i], pi = pos[i], ni = neg[i];
        float u = h2f(xh[(size_t)ui * DIM + lane]);
        float p = h2f(xh[(size_t)pi * DIM + lane]);
        float n = h2f(xh[(size_t)ni * DIM + lane]);
        float v = u * (p - n);
#pragma unroll
        for (int off = 32; off; off >>= 1) v += __shfl_xor(v, off);
        if (lane == 0) dots[i] = v;
        return;
    }
    int g = lane >> 3;
    int sl = lane & 7;
    int row = blockIdx.x * 4 + (threadIdx.x >> 6);
    int p0 = row_ptr[row], p1 = row_ptr[row + 1];
    float a0 = 0, a1 = 0, a2 = 0, a3 = 0, a4 = 0, a5 = 0, a6 = 0, a7 = 0;
    int p = p0;
#define SPMM_ACC(E, X)                                                     \
    {                                                                      \
        float vv = h2f((ushort)((E) & 0xFFFF));                            \
        a0 += vv * h2f((ushort)((X).x & 0xFFFF));                          \
        a1 += vv * h2f((ushort)((X).x >> 16));                             \
        a2 += vv * h2f((ushort)((X).y & 0xFFFF));                          \
        a3 += vv * h2f((ushort)((X).y >> 16));                             \
        a4 += vv * h2f((ushort)((X).z & 0xFFFF));                          \
        a5 += vv * h2f((ushort)((X).z >> 16));                             \
        a6 += vv * h2f((ushort)((X).w & 0xFFFF));                          \
        a7 += vv * h2f((ushort)((X).w >> 16));                             \
    }
    for (; p + 32 <= p1; p += 32) {
        uint32 e0 = csr[p + g];
        uint32 e1 = csr[p + 8 + g];
        uint32 e2 = csr[p + 16 + g];
        uint32 e3 = csr[p + 24 + g];
        uint4 x0 = *(const uint4*)(xh + (size_t)(e0 >> 16) * DIM + sl * 8);
        uint4 x1 = *(const uint4*)(xh + (size_t)(e1 >> 16) * DIM + sl * 8);
        uint4 x2 = *(const uint4*)(xh + (size_t)(e2 >> 16) * DIM + sl * 8);
        uint4 x3 = *(const uint4*)(xh + (size_t)(e3 >> 16) * DIM + sl * 8);
        SPMM_ACC(e0, x0);
        SPMM_ACC(e1, x1);
        SPMM_ACC(e2, x2);
        SPMM_ACC(e3, x3);
    }
    for (; p + 8 <= p1; p += 8) {
        uint32 ea = csr[p + g];
        uint4 xa = *(const uint4*)(xh + (size_t)(ea >> 16) * DIM + sl * 8);
        SPMM_ACC(ea, xa);
    }
    if (p + g < p1) {
        uint32 ea = csr[p + g];
        uint4 xa = *(const uint4*)(xh + (size_t)(ea >> 16) * DIM + sl * 8);
        SPMM_ACC(ea, xa);
    }
#undef SPMM_ACC
#pragma unroll
    for (int m = 8; m <= 32; m <<= 1) {
        a0 += __shfl_xor(a0, m); a1 += __shfl_xor(a1, m);
        a2 += __shfl_xor(a2, m); a3 += __shfl_xor(a3, m);
        a4 += __shfl_xor(a4, m); a5 += __shfl_xor(a5, m);
        a6 += __shfl_xor(a6, m); a7 += __shfl_xor(a7, m);
    }
    if (lane < 8) {
        ushort t[8];
        t[0] = f2h(a0); t[1] = f2h(a1); t[2] = f2h(a2); t[3] = f2h(a3);
        t[4] = f2h(a4); t[5] = f2h(a5); t[6] = f2h(a6); t[7] = f2h(a7);
        *(uint4*)(aggh + (size_t)row * DIM + lane * 8) = *(uint4*)t;
    }
}

// ---------------- Dense layer: fp16 MFMA (16x16x32), f32 accumulate ----------

__global__ __launch_bounds__(256) void dense_kernel(const ushort* __restrict__ xh_in,
                                                    const ushort* __restrict__ aggh,
                                                    const float* __restrict__ w1,
                                                    const float* __restrict__ w2,
                                                    const float* __restrict__ b1,
                                                    const float* __restrict__ b2,
                                                    ushort* __restrict__ yh) {
    __shared__ ushort xs[64 * 64];
    __shared__ ushort xc[64 * 64];
    __shared__ ushort w1s[64 * 64];
    __shared__ ushort w2s[64 * 64];

    int tid = threadIdx.x;
    int n0 = blockIdx.x * 64;

    // ---- staging: thread -> row r = tid>>2, 16 elems at jq = (tid&3)*16 ----
    {
        int rr = tid >> 2;
        int jq = (tid & 3) << 4;
        int sw = rr & 7;
        int b0 = jq >> 3;
        int o0 = rr * 64 + (((b0 + 0) ^ sw) << 3);
        int o1 = rr * 64 + (((b0 + 1) ^ sw) << 3);

        {
            const float* w1r = w1 + rr * 64 + jq;
            const float* w2r = w2 + rr * 64 + jq;
            ushort t1[16], t2[16];
#pragma unroll
            for (int k = 0; k < 4; ++k) {
                float4 a = ((const float4*)w1r)[k];
                float4 b = ((const float4*)w2r)[k];
                t1[k * 4 + 0] = f2h(a.x); t1[k * 4 + 1] = f2h(a.y);
                t1[k * 4 + 2] = f2h(a.z); t1[k * 4 + 3] = f2h(a.w);
                t2[k * 4 + 0] = f2h(b.x); t2[k * 4 + 1] = f2h(b.y);
                t2[k * 4 + 2] = f2h(b.z); t2[k * 4 + 3] = f2h(b.w);
            }
            *(uint4*)&w1s[o0] = *(uint4*)&t1[0];
            *(uint4*)&w1s[o1] = *(uint4*)&t1[8];
            *(uint4*)&w2s[o0] = *(uint4*)&t2[0];
            *(uint4*)&w2s[o1] = *(uint4*)&t2[8];
        }
        {
            int node = n0 + rr;
            int ncl = (node < N_NODES) ? node : (N_NODES - 1);
            const ushort* ar = aggh + (size_t)ncl * DIM + jq;
            const ushort* xr = xh_in + (size_t)ncl * DIM + jq;
            ushort txs[16], txc[16];
#pragma unroll
            for (int k = 0; k < 2; ++k) {
                uint4 xv = ((const uint4*)xr)[k];
                uint4 av = ((const uint4*)ar)[k];
                uint32 xw[4] = {xv.x, xv.y, xv.z, xv.w};
                uint32 aw[4] = {av.x, av.y, av.z, av.w};
#pragma unroll
                for (int q = 0; q < 4; ++q) {
                    ushort xlo = (ushort)(xw[q] & 0xFFFF);
                    ushort xhi = (ushort)(xw[q] >> 16);
                    ushort alo = (ushort)(aw[q] & 0xFFFF);
                    ushort ahi = (ushort)(aw[q] >> 16);
                    int e = k * 8 + q * 2;
                    txc[e] = xlo; txc[e + 1] = xhi;
                    txs[e] = f2h(h2f(xlo) + h2f(alo));
                    txs[e + 1] = f2h(h2f(xhi) + h2f(ahi));
                }
            }
            *(uint4*)&xs[o0] = *(uint4*)&txs[0];
            *(uint4*)&xs[o1] = *(uint4*)&txs[8];
            *(uint4*)&xc[o0] = *(uint4*)&txc[0];
            *(uint4*)&xc[o1] = *(uint4*)&txc[8];
        }
    }
    __syncthreads();

    int lane = tid & 63, w = tid >> 6;
    int nb = w << 4;
    int lm = lane & 15;
    int le = lane >> 4;

    f16x8 axs[2], axc[2];
#pragma unroll
    for (int k = 0; k < 2; ++k) {
        int n = nb + lm;
        int blk = k * 4 + le;
        int off = n * 64 + ((blk ^ (n & 7)) << 3);
        axs[k] = *(const f16x8*)&xs[off];
        axc[k] = *(const f16x8*)&xc[off];
    }

#pragma unroll
    for (int dt = 0; dt < 4; ++dt) {
        int d = dt * 16 + lm;
        f16x8 bf1[2], bf2[2];
#pragma unroll
        for (int k = 0; k < 2; ++k) {
            int blk = k * 4 + le;
            int off = d * 64 + ((blk ^ (d & 7)) << 3);
            bf1[k] = *(const f16x8*)&w1s[off];
            bf2[k] = *(const f16x8*)&w2s[off];
        }
        f32x4 acc1 = {0.f, 0.f, 0.f, 0.f};
        f32x4 acc2 = {0.f, 0.f, 0.f, 0.f};
        acc1 = __builtin_amdgcn_mfma_f32_16x16x32_f16(axs[0], bf1[0], acc1, 0, 0, 0);
        acc1 = __builtin_amdgcn_mfma_f32_16x16x32_f16(axs[1], bf1[1], acc1, 0, 0, 0);
        acc2 = __builtin_amdgcn_mfma_f32_16x16x32_f16(axc[0], bf2[0], acc2, 0, 0, 0);
        acc2 = __builtin_amdgcn_mfma_f32_16x16x32_f16(axc[1], bf2[1], acc2, 0, 0, 0);

        float b1v = b1[d], b2v = b2[d];
        int bb = d >> 3;
#pragma unroll
        for (int i = 0; i < 4; ++i) {
            int nl = nb + (le << 2) + i;
            int node = n0 + nl;
            int off = nl * 64 + ((bb ^ (nl & 7)) << 3) + (d & 7);
            float ag = h2f(xs[off]) - h2f(xc[off]);
            float t = acc1[i] + b1v + ag * (acc2[i] + b2v);
            t = (t > 0.f) ? t : 0.01f * t;
            if (node < N_NODES) yh[(size_t)node * DIM + d] = f2h(t);
        }
    }
}

// ---------------- dots layer 3 + loss (atomic accumulate) ----------------

__global__ __launch_bounds__(256) void dots_loss_kernel(const ushort* __restrict__ xh,
                                                        const int* __restrict__ user,
                                                        const int* __restrict__ pos,
                                                        const int* __restrict__ neg,
                                                        const float* __restrict__ dots,
                                                        float* __restrict__ out) {
    __shared__ float part[4];
    int tid = threadIdx.x;
    int lane = tid & 63;
    int i = blockIdx.x * 4 + (tid >> 6);
    int ui = user[i], pi = pos[i], ni = neg[i];
    float u = h2f(xh[(size_t)ui * DIM + lane]);
    float p = h2f(xh[(size_t)pi * DIM + lane]);
    float n = h2f(xh[(size_t)ni * DIM + lane]);
    float v = u * (p - n);
#pragma unroll
    for (int off = 32; off; off >>= 1) v += __shfl_xor(v, off);
    if (lane == 0) {
        float d = dots[i] + dots[BATCH + i] + dots[2 * BATCH + i] + v;
        part[tid >> 6] = fmaxf(-d, 0.f) + log1pf(expf(-fabsf(d)));
    }
    __syncthreads();
    if (tid == 0) atomicAdd(out, part[0] + part[1] + part[2] + part[3]);
}

// ---------------- Launch ----------------

extern "C" void kernel_launch(void* const* d_in, const int* in_sizes, int n_in,
                              void* d_out, int out_size, void* d_ws, size_t ws_size,
                              hipStream_t stream) {
    const float* emb  = (const float*)d_in[0];
    const float* w1_w = (const float*)d_in[1];
    const float* w1_b = (const float*)d_in[2];
    const float* w2_w = (const float*)d_in[3];
    const float* w2_b = (const float*)d_in[4];
    const float* vals = (const float*)d_in[5];
    const int* rows = (const int*)d_in[6];
    const int* cols = (const int*)d_in[7];
    const int* user = (const int*)d_in[8];
    const int* pos  = (const int*)d_in[9];
    const int* neg  = (const int*)d_in[10];
    float* out = (float*)d_out;

    char* w = (char*)d_ws;
    // 12.8 MB region: CSR staging (10 MB) first, then fp16 agg (6.4 MB)
    char* region = w;          w += (size_t)N_NODES * DIM * 4;
    ushort* aggh = (ushort*)region;
    int2* staging = (int2*)region;
    int* row_ptr = (int*)w;   w += (((size_t)(N_NODES + 1) * 4) + 255) / 256 * 256;
    uint32* csr  = (uint32*)w; w += (size_t)EDGES * 4;
    int* bhist   = (int*)w;   w += (size_t)NBUCK * NABLK * 4;
    int* boffs   = (int*)w;   w += (size_t)NBUCK * NABLK * 4;
    float* dots  = (float*)w; w += (size_t)3 * BATCH * 4;
    ushort* xhA  = (ushort*)w; w += (size_t)N_NODES * DIM * 2;
    ushort* xhB  = (ushort*)w; w += (size_t)N_NODES * DIM * 2;

    histprep_kernel<<<HP_TOTAL, 256, 0, stream>>>(rows, bhist, emb, xhA,
                                                  user, pos, neg, dots, out);
    boffs_kernel<<<NBUCK, 512, 0, stream>>>(bhist, boffs);
    bucket_scatter_kernel<<<NABLK, 256, 0, stream>>>(rows, cols, vals, boffs, staging);
    csr_build_kernel<<<NBUCK, 512, 0, stream>>>(boffs, staging, row_ptr, csr);

    const int NSB = N_NODES / 4;          // 12500
    const int NTB = BATCH / 4;            // 1024
    const int NDB = (N_NODES + 63) / 64;  // 782

    // layer 0
    spmm_kernel<<<NSB, 256, 0, stream>>>(row_ptr, csr, xhA, aggh, user, pos, neg, dots, NSB);
    dense_kernel<<<NDB, 256, 0, stream>>>(xhA, aggh, w1_w + 0 * 4096, w2_w + 0 * 4096,
                                          w1_b + 0 * DIM, w2_b + 0 * DIM, xhB);
    // layer 1 (+ dots1 tail on xhB)
    spmm_kernel<<<NSB + NTB, 256, 0, stream>>>(row_ptr, csr, xhB, aggh, user, pos, neg,
                                               dots + BATCH, NSB);
    dense_kernel<<<NDB, 256, 0, stream>>>(xhB, aggh, w1_w + 1 * 4096, w2_w + 1 * 4096,
                                          w1_b + 1 * DIM, w2_b + 1 * DIM, xhA);
    // layer 2 (+ dots2 tail on xhA)
    spmm_kernel<<<NSB + NTB, 256, 0, stream>>>(row_ptr, csr, xhA, aggh, user, pos, neg,
                                               dots + 2 * BATCH, NSB);
    dense_kernel<<<NDB, 256, 0, stream>>>(xhA, aggh, w1_w + 2 * 4096, w2_w + 2 * 4096,
                                          w1_b + 2 * DIM, w2_b + 2 * DIM, xhB);

    dots_loss_kernel<<<NTB, 256, 0, stream>>>(xhB, user, pos, neg, dots, out);
}

// Round 16
// 156.324 us; speedup vs baseline: 2.5740x; 1.1363x over previous
//
#include <hip/hip_runtime.h>
#include <hip/hip_fp16.h>
#include <math.h>

#define N_NODES 50000
#define EDGES   1250000
#define DIM     64
#define NLAYER  3
#define BATCH   4096
#define NSLOTS  (3 * BATCH)   // 12288 = user | pos | neg

#define NBUCK 196   // coarse buckets: bucket = row >> 8 (256 rows each)
#define RPB   256   // rows per bucket
#define NABLK 512   // phase-A blocks
#define BCAP  7424  // LDS bucket cache (58 KB)

typedef unsigned int uint32;
typedef _Float16 f16x8 __attribute__((ext_vector_type(8)));
typedef float f32x4 __attribute__((ext_vector_type(4)));

static __device__ __forceinline__ ushort f2h(float f) {
    return __half_as_ushort(__float2half(f));
}
static __device__ __forceinline__ float h2f(ushort u) {
    return __half2float(__ushort_as_half(u));
}

static __device__ __forceinline__ int slot_node(int slot,
                                                const int* __restrict__ user,
                                                const int* __restrict__ pos,
                                                const int* __restrict__ neg) {
    if (slot < BATCH) return user[slot];
    if (slot < 2 * BATCH) return pos[slot - BATCH];
    return neg[slot - 2 * BATCH];
}

// ---------------- histprep: bucket hist + f2h(emb) + dots0 ----------------
// blocks [0,512): hist; [512,3637): f2h; [3637,4661): dots0

#define HP_F2H   512
#define HP_DOTS  3637
#define HP_TOTAL 4661

__global__ __launch_bounds__(256) void histprep_kernel(const int* __restrict__ rows,
                                                       int* __restrict__ bhist,
                                                       const float* __restrict__ emb,
                                                       ushort* __restrict__ xh,
                                                       const int* __restrict__ user,
                                                       const int* __restrict__ pos,
                                                       const int* __restrict__ neg,
                                                       float* __restrict__ dots,
                                                       float* __restrict__ out) {
    __shared__ int h[NBUCK];
    int blk = blockIdx.x;
    int tid = threadIdx.x;
    if (blk < HP_F2H) {
        if (blk == 0 && tid == 0) out[0] = 0.f;
        for (int i = tid; i < NBUCK; i += 256) h[i] = 0;
        __syncthreads();
        int per = (EDGES + NABLK - 1) / NABLK;
        int e0 = blk * per;
        int e1 = min(e0 + per, EDGES);
        for (int e = e0 + tid; e < e1; e += 256)
            atomicAdd(&h[rows[e] >> 8], 1);
        __syncthreads();
        for (int i = tid; i < NBUCK; i += 256)
            bhist[(size_t)i * NABLK + blk] = h[i];
    } else if (blk < HP_DOTS) {
        int i = (blk - HP_F2H) * 256 + tid;     // < 800000 exactly
        float4 v = ((const float4*)emb)[i];
        ushort4 hh;
        hh.x = f2h(v.x); hh.y = f2h(v.y); hh.z = f2h(v.z); hh.w = f2h(v.w);
        ((ushort4*)xh)[i] = hh;
    } else {
        int lane = tid & 63;
        int i = (blk - HP_DOTS) * 4 + (tid >> 6);
        int ui = user[i], pi = pos[i], ni = neg[i];
        float u = emb[(size_t)ui * DIM + lane];
        float p = emb[(size_t)pi * DIM + lane];
        float n = emb[(size_t)ni * DIM + lane];
        float v = u * (p - n);
#pragma unroll
        for (int off = 32; off; off >>= 1) v += __shfl_xor(v, off);
        if (lane == 0) dots[i] = v;
    }
}

// ---------------- boffs: per-bucket parallel prefix ----------------

__global__ __launch_bounds__(512) void boffs_kernel(const int* __restrict__ bhist,
                                                    int* __restrict__ boffs) {
    __shared__ int sbase[256];
    __shared__ int wred[8];
    int b = blockIdx.x;
    int tid = threadIdx.x;
    int lane = tid & 63, wid = tid >> 6;

    int tot = 0;
    if (tid < NBUCK) {
        const int* p = bhist + (size_t)tid * NABLK;
        for (int k = 0; k < NABLK; ++k) tot += p[k];
    }
    int sB = tot;
    if (tid < 256) {
#pragma unroll
        for (int off = 1; off < 64; off <<= 1) {
            int tt = __shfl_up(sB, off);
            if (lane >= off) sB += tt;
        }
        if (lane == 63) wred[wid] = sB;
    }
    __syncthreads();
    if (tid == 0) {
        int a = 0;
#pragma unroll
        for (int i = 0; i < 4; ++i) { int tt = wred[i]; wred[i] = a; a += tt; }
    }
    __syncthreads();
    if (tid < 256) sbase[tid] = wred[wid] + sB - tot;
    __syncthreads();
    int base = sbase[b];
    __syncthreads();

    int v = bhist[(size_t)b * NABLK + tid];
    int s = v;
#pragma unroll
    for (int off = 1; off < 64; off <<= 1) {
        int tt = __shfl_up(s, off);
        if (lane >= off) s += tt;
    }
    if (lane == 63) wred[wid] = s;
    __syncthreads();
    if (tid == 0) {
        int a = 0;
#pragma unroll
        for (int i = 0; i < 8; ++i) { int tt = wred[i]; wred[i] = a; a += tt; }
    }
    __syncthreads();
    boffs[(size_t)b * NABLK + tid] = base + wred[wid] + s - v;
}

// ---------------- Phase A3: scatter edges into bucket staging ----------------

__global__ __launch_bounds__(256) void bucket_scatter_kernel(const int* __restrict__ rows,
                                                             const int* __restrict__ cols,
                                                             const float* __restrict__ vals,
                                                             const int* __restrict__ boffs,
                                                             int2* __restrict__ staging) {
    __shared__ int cur[NBUCK];
    for (int t = threadIdx.x; t < NBUCK; t += 256)
        cur[t] = boffs[(size_t)t * NABLK + blockIdx.x];
    __syncthreads();
    int per = (EDGES + NABLK - 1) / NABLK;
    int e0 = blockIdx.x * per;
    int e1 = min(e0 + per, EDGES);
    for (int e = e0 + threadIdx.x; e < e1; e += 256) {
        int r = rows[e];
        int p = atomicAdd(&cur[r >> 8], 1);
        staging[p] = make_int2(((r & 255) << 16) | cols[e], __float_as_int(vals[e]));
    }
}

// ---------------- Phase B: LDS-cached bucket -> row_ptr + 4-byte CSR ----------

__global__ __launch_bounds__(512) void csr_build_kernel(const int* __restrict__ boffs,
                                                        const int2* __restrict__ staging,
                                                        int* __restrict__ row_ptr,
                                                        uint32* __restrict__ csr) {
    __shared__ int2 sedge[BCAP];
    __shared__ int rcur[RPB];
    __shared__ int wred[4];
    int b = blockIdx.x;
    int base = boffs[(size_t)b * NABLK];
    int end = (b == NBUCK - 1) ? EDGES : boffs[(size_t)(b + 1) * NABLK];
    int cnt = end - base;
    bool inlds = (cnt <= BCAP);
    int tid = threadIdx.x;
    int lane = tid & 63, wid = tid >> 6;
    if (tid < RPB) rcur[tid] = 0;
    __syncthreads();
    if (inlds) {
        for (int p = tid; p < cnt; p += 512) {
            int2 e = staging[base + p];
            sedge[p] = e;
            atomicAdd(&rcur[e.x >> 16], 1);
        }
    } else {
        for (int p = base + tid; p < end; p += 512)
            atomicAdd(&rcur[staging[p].x >> 16], 1);
    }
    __syncthreads();
    int v = 0, s = 0;
    if (tid < RPB) {
        v = rcur[tid];
        s = v;
#pragma unroll
        for (int off = 1; off < 64; off <<= 1) {
            int t = __shfl_up(s, off);
            if (lane >= off) s += t;
        }
        if (lane == 63) wred[wid] = s;
    }
    __syncthreads();
    if (tid == 0) {
        int a = 0;
#pragma unroll
        for (int i = 0; i < 4; ++i) { int t = wred[i]; wred[i] = a; a += t; }
    }
    __syncthreads();
    if (tid < RPB) {
        int excl = wred[wid] + s - v;
        rcur[tid] = base + excl;
        int row = b * RPB + tid;
        if (row < N_NODES) row_ptr[row] = base + excl;
    }
    if (b == NBUCK - 1 && tid == 0) row_ptr[N_NODES] = EDGES;
    __syncthreads();
    if (inlds) {
        for (int p = tid; p < cnt; p += 512) {
            int2 e = sedge[p];
            int pos = atomicAdd(&rcur[e.x >> 16], 1);
            csr[pos] = ((uint32)(e.x & 0xFFFF) << 16) | (uint32)f2h(__int_as_float(e.y));
        }
    } else {
        for (int p = base + tid; p < end; p += 512) {
            int2 e = staging[p];
            int pos = atomicAdd(&rcur[e.x >> 16], 1);
            csr[pos] = ((uint32)(e.x & 0xFFFF) << 16) | (uint32)f2h(__int_as_float(e.y));
        }
    }
}

// ---------------- SpMM core (shared by full and slot variants) ----------------

static __device__ __forceinline__ void spmm_row(const uint32* __restrict__ csr,
                                                const ushort* __restrict__ xh,
                                                int p0, int p1, int g, int sl,
                                                float* a) {
#define SPMM_ACC(E, X)                                                     \
    {                                                                      \
        float vv = h2f((ushort)((E) & 0xFFFF));                            \
        a[0] += vv * h2f((ushort)((X).x & 0xFFFF));                        \
        a[1] += vv * h2f((ushort)((X).x >> 16));                           \
        a[2] += vv * h2f((ushort)((X).y & 0xFFFF));                        \
        a[3] += vv * h2f((ushort)((X).y >> 16));                           \
        a[4] += vv * h2f((ushort)((X).z & 0xFFFF));                        \
        a[5] += vv * h2f((ushort)((X).z >> 16));                           \
        a[6] += vv * h2f((ushort)((X).w & 0xFFFF));                        \
        a[7] += vv * h2f((ushort)((X).w >> 16));                           \
    }
    int p = p0;
    for (; p + 32 <= p1; p += 32) {
        uint32 e0 = csr[p + g];
        uint32 e1 = csr[p + 8 + g];
        uint32 e2 = csr[p + 16 + g];
        uint32 e3 = csr[p + 24 + g];
        uint4 x0 = *(const uint4*)(xh + (size_t)(e0 >> 16) * DIM + sl * 8);
        uint4 x1 = *(const uint4*)(xh + (size_t)(e1 >> 16) * DIM + sl * 8);
        uint4 x2 = *(const uint4*)(xh + (size_t)(e2 >> 16) * DIM + sl * 8);
        uint4 x3 = *(const uint4*)(xh + (size_t)(e3 >> 16) * DIM + sl * 8);
        SPMM_ACC(e0, x0);
        SPMM_ACC(e1, x1);
        SPMM_ACC(e2, x2);
        SPMM_ACC(e3, x3);
    }
    for (; p + 8 <= p1; p += 8) {
        uint32 ea = csr[p + g];
        uint4 xa = *(const uint4*)(xh + (size_t)(ea >> 16) * DIM + sl * 8);
        SPMM_ACC(ea, xa);
    }
    if (p + g < p1) {
        uint32 ea = csr[p + g];
        uint4 xa = *(const uint4*)(xh + (size_t)(ea >> 16) * DIM + sl * 8);
        SPMM_ACC(ea, xa);
    }
#undef SPMM_ACC
#pragma unroll
    for (int m = 8; m <= 32; m <<= 1) {
        a[0] += __shfl_xor(a[0], m); a[1] += __shfl_xor(a[1], m);
        a[2] += __shfl_xor(a[2], m); a[3] += __shfl_xor(a[3], m);
        a[4] += __shfl_xor(a[4], m); a[5] += __shfl_xor(a[5], m);
        a[6] += __shfl_xor(a[6], m); a[7] += __shfl_xor(a[7], m);
    }
}

static __device__ __forceinline__ void spmm_store(ushort* dst, const float* a, int lane) {
    if (lane < 8) {
        ushort t[8];
        t[0] = f2h(a[0]); t[1] = f2h(a[1]); t[2] = f2h(a[2]); t[3] = f2h(a[3]);
        t[4] = f2h(a[4]); t[5] = f2h(a[5]); t[6] = f2h(a[6]); t[7] = f2h(a[7]);
        *(uint4*)(dst + lane * 8) = *(uint4*)t;
    }
}

static __device__ __forceinline__ void dots_tail(const ushort* __restrict__ xh,
                                                 const int* __restrict__ user,
                                                 const int* __restrict__ pos,
                                                 const int* __restrict__ neg,
                                                 float* __restrict__ dots,
                                                 int i, int lane) {
    int ui = user[i], pi = pos[i], ni = neg[i];
    float u = h2f(xh[(size_t)ui * DIM + lane]);
    float p = h2f(xh[(size_t)pi * DIM + lane]);
    float n = h2f(xh[(size_t)ni * DIM + lane]);
    float v = u * (p - n);
#pragma unroll
    for (int off = 32; off; off >>= 1) v += __shfl_xor(v, off);
    if (lane == 0) dots[i] = v;
}

// ---------------- SpMM full: one wave per node row; optional dots tail ----------

__global__ __launch_bounds__(256) void spmm_kernel(const int* __restrict__ row_ptr,
                                                   const uint32* __restrict__ csr,
                                                   const ushort* __restrict__ xh,
                                                   ushort* __restrict__ aggh,
                                                   const int* __restrict__ user,
                                                   const int* __restrict__ pos,
                                                   const int* __restrict__ neg,
                                                   float* __restrict__ dots,
                                                   int nsb) {
    int lane = threadIdx.x & 63;
    if ((int)blockIdx.x >= nsb) {
        int i = (blockIdx.x - nsb) * 4 + (threadIdx.x >> 6);
        dots_tail(xh, user, pos, neg, dots, i, lane);
        return;
    }
    int row = blockIdx.x * 4 + (threadIdx.x >> 6);
    int p0 = row_ptr[row], p1 = row_ptr[row + 1];
    float a[8] = {};
    spmm_row(csr, xh, p0, p1, lane >> 3, lane & 7, a);
    spmm_store(aggh + (size_t)row * DIM, a, lane);
}

// ---------------- SpMM slots: one wave per batch slot (layer 2 only) ----------

__global__ __launch_bounds__(256) void spmm_slots_kernel(const int* __restrict__ row_ptr,
                                                         const uint32* __restrict__ csr,
                                                         const ushort* __restrict__ xh,
                                                         ushort* __restrict__ aggh_slot,
                                                         const int* __restrict__ user,
                                                         const int* __restrict__ pos,
                                                         const int* __restrict__ neg,
                                                         float* __restrict__ dots,
                                                         int nsb) {
    int lane = threadIdx.x & 63;
    if ((int)blockIdx.x >= nsb) {
        int i = (blockIdx.x - nsb) * 4 + (threadIdx.x >> 6);
        dots_tail(xh, user, pos, neg, dots, i, lane);
        return;
    }
    int slot = blockIdx.x * 4 + (threadIdx.x >> 6);
    int node = slot_node(slot, user, pos, neg);
    int p0 = row_ptr[node], p1 = row_ptr[node + 1];
    float a[8] = {};
    spmm_row(csr, xh, p0, p1, lane >> 3, lane & 7, a);
    spmm_store(aggh_slot + (size_t)slot * DIM, a, lane);
}

// ---------------- Dense core: fp16 MFMA 16x16x32, f32 accumulate ----------
// IS_SLOT=0: rows = nodes n0..n0+63, x/agg indexed by node, out yh[node].
// IS_SLOT=1: rows = slots, x indexed by slot_node, agg/out indexed by slot.

template <int IS_SLOT>
static __device__ __forceinline__ void dense_body(const ushort* __restrict__ xh_in,
                                                  const ushort* __restrict__ aggh,
                                                  const float* __restrict__ w1,
                                                  const float* __restrict__ w2,
                                                  const float* __restrict__ b1,
                                                  const float* __restrict__ b2,
                                                  ushort* __restrict__ yh,
                                                  const int* __restrict__ user,
                                                  const int* __restrict__ pos,
                                                  const int* __restrict__ neg) {
    __shared__ ushort xs[64 * 64];
    __shared__ ushort xc[64 * 64];
    __shared__ ushort w1s[64 * 64];
    __shared__ ushort w2s[64 * 64];

    int tid = threadIdx.x;
    int n0 = blockIdx.x * 64;

    {
        int rr = tid >> 2;
        int jq = (tid & 3) << 4;
        int sw = rr & 7;
        int b0 = jq >> 3;
        int o0 = rr * 64 + (((b0 + 0) ^ sw) << 3);
        int o1 = rr * 64 + (((b0 + 1) ^ sw) << 3);

        {
            const float* w1r = w1 + rr * 64 + jq;
            const float* w2r = w2 + rr * 64 + jq;
            ushort t1[16], t2[16];
#pragma unroll
            for (int k = 0; k < 4; ++k) {
                float4 a = ((const float4*)w1r)[k];
                float4 b = ((const float4*)w2r)[k];
                t1[k * 4 + 0] = f2h(a.x); t1[k * 4 + 1] = f2h(a.y);
                t1[k * 4 + 2] = f2h(a.z); t1[k * 4 + 3] = f2h(a.w);
                t2[k * 4 + 0] = f2h(b.x); t2[k * 4 + 1] = f2h(b.y);
                t2[k * 4 + 2] = f2h(b.z); t2[k * 4 + 3] = f2h(b.w);
            }
            *(uint4*)&w1s[o0] = *(uint4*)&t1[0];
            *(uint4*)&w1s[o1] = *(uint4*)&t1[8];
            *(uint4*)&w2s[o0] = *(uint4*)&t2[0];
            *(uint4*)&w2s[o1] = *(uint4*)&t2[8];
        }
        {
            int rowid = n0 + rr;
            int xnode, arow;
            if (IS_SLOT) {
                xnode = slot_node(rowid, user, pos, neg);
                arow = rowid;
            } else {
                xnode = (rowid < N_NODES) ? rowid : (N_NODES - 1);
                arow = xnode;
            }
            const ushort* ar = aggh + (size_t)arow * DIM + jq;
            const ushort* xr = xh_in + (size_t)xnode * DIM + jq;
            ushort txs[16], txc[16];
#pragma unroll
            for (int k = 0; k < 2; ++k) {
                uint4 xv = ((const uint4*)xr)[k];
                uint4 av = ((const uint4*)ar)[k];
                uint32 xw[4] = {xv.x, xv.y, xv.z, xv.w};
                uint32 aw[4] = {av.x, av.y, av.z, av.w};
#pragma unroll
                for (int q = 0; q < 4; ++q) {
                    ushort xlo = (ushort)(xw[q] & 0xFFFF);
                    ushort xhi = (ushort)(xw[q] >> 16);
                    ushort alo = (ushort)(aw[q] & 0xFFFF);
                    ushort ahi = (ushort)(aw[q] >> 16);
                    int e = k * 8 + q * 2;
                    txc[e] = xlo; txc[e + 1] = xhi;
                    txs[e] = f2h(h2f(xlo) + h2f(alo));
                    txs[e + 1] = f2h(h2f(xhi) + h2f(ahi));
                }
            }
            *(uint4*)&xs[o0] = *(uint4*)&txs[0];
            *(uint4*)&xs[o1] = *(uint4*)&txs[8];
            *(uint4*)&xc[o0] = *(uint4*)&txc[0];
            *(uint4*)&xc[o1] = *(uint4*)&txc[8];
        }
    }
    __syncthreads();

    int lane = tid & 63, w = tid >> 6;
    int nb = w << 4;
    int lm = lane & 15;
    int le = lane >> 4;

    f16x8 axs[2], axc[2];
#pragma unroll
    for (int k = 0; k < 2; ++k) {
        int n = nb + lm;
        int blk = k * 4 + le;
        int off = n * 64 + ((blk ^ (n & 7)) << 3);
        axs[k] = *(const f16x8*)&xs[off];
        axc[k] = *(const f16x8*)&xc[off];
    }

#pragma unroll
    for (int dt = 0; dt < 4; ++dt) {
        int d = dt * 16 + lm;
        f16x8 bf1[2], bf2[2];
#pragma unroll
        for (int k = 0; k < 2; ++k) {
            int blk = k * 4 + le;
            int off = d * 64 + ((blk ^ (d & 7)) << 3);
            bf1[k] = *(const f16x8*)&w1s[off];
            bf2[k] = *(const f16x8*)&w2s[off];
        }
        f32x4 acc1 = {0.f, 0.f, 0.f, 0.f};
        f32x4 acc2 = {0.f, 0.f, 0.f, 0.f};
        acc1 = __builtin_amdgcn_mfma_f32_16x16x32_f16(axs[0], bf1[0], acc1, 0, 0, 0);
        acc1 = __builtin_amdgcn_mfma_f32_16x16x32_f16(axs[1], bf1[1], acc1, 0, 0, 0);
        acc2 = __builtin_amdgcn_mfma_f32_16x16x32_f16(axc[0], bf2[0], acc2, 0, 0, 0);
        acc2 = __builtin_amdgcn_mfma_f32_16x16x32_f16(axc[1], bf2[1], acc2, 0, 0, 0);

        float b1v = b1[d], b2v = b2[d];
        int bb = d >> 3;
#pragma unroll
        for (int i = 0; i < 4; ++i) {
            int nl = nb + (le << 2) + i;
            int rowid = n0 + nl;
            int off = nl * 64 + ((bb ^ (nl & 7)) << 3) + (d & 7);
            float ag = h2f(xs[off]) - h2f(xc[off]);
            float t = acc1[i] + b1v + ag * (acc2[i] + b2v);
            t = (t > 0.f) ? t : 0.01f * t;
            bool wr = IS_SLOT ? true : (rowid < N_NODES);
            if (wr) yh[(size_t)rowid * DIM + d] = f2h(t);
        }
    }
}

__global__ __launch_bounds__(256) void dense_kernel(const ushort* __restrict__ xh_in,
                                                    const ushort* __restrict__ aggh,
                                                    const float* __restrict__ w1,
                                                    const float* __restrict__ w2,
                                                    const float* __restrict__ b1,
                                                    const float* __restrict__ b2,
                                                    ushort* __restrict__ yh) {
    dense_body<0>(xh_in, aggh, w1, w2, b1, b2, yh, nullptr, nullptr, nullptr);
}

__global__ __launch_bounds__(256) void dense_slots_kernel(const ushort* __restrict__ xh_in,
                                                          const ushort* __restrict__ aggh_slot,
                                                          const float* __restrict__ w1,
                                                          const float* __restrict__ w2,
                                                          const float* __restrict__ b1,
                                                          const float* __restrict__ b2,
                                                          ushort* __restrict__ yh_slot,
                                                          const int* __restrict__ user,
                                                          const int* __restrict__ pos,
                                                          const int* __restrict__ neg) {
    dense_body<1>(xh_in, aggh_slot, w1, w2, b1, b2, yh_slot, user, pos, neg);
}

// ---------------- dots layer 3 (from slot rows, coalesced) + loss ----------------

__global__ __launch_bounds__(256) void dots_loss_kernel(const ushort* __restrict__ yh_slot,
                                                        const float* __restrict__ dots,
                                                        float* __restrict__ out) {
    __shared__ float part[4];
    int tid = threadIdx.x;
    int lane = tid & 63;
    int i = blockIdx.x * 4 + (tid >> 6);
    float u = h2f(yh_slot[(size_t)i * DIM + lane]);
    float p = h2f(yh_slot[(size_t)(BATCH + i) * DIM + lane]);
    float n = h2f(yh_slot[(size_t)(2 * BATCH + i) * DIM + lane]);
    float v = u * (p - n);
#pragma unroll
    for (int off = 32; off; off >>= 1) v += __shfl_xor(v, off);
    if (lane == 0) {
        float d = dots[i] + dots[BATCH + i] + dots[2 * BATCH + i] + v;
        part[tid >> 6] = fmaxf(-d, 0.f) + log1pf(expf(-fabsf(d)));
    }
    __syncthreads();
    if (tid == 0) atomicAdd(out, part[0] + part[1] + part[2] + part[3]);
}

// ---------------- Launch ----------------

extern "C" void kernel_launch(void* const* d_in, const int* in_sizes, int n_in,
                              void* d_out, int out_size, void* d_ws, size_t ws_size,
                              hipStream_t stream) {
    const float* emb  = (const float*)d_in[0];
    const float* w1_w = (const float*)d_in[1];
    const float* w1_b = (const float*)d_in[2];
    const float* w2_w = (const float*)d_in[3];
    const float* w2_b = (const float*)d_in[4];
    const float* vals = (const float*)d_in[5];
    const int* rows = (const int*)d_in[6];
    const int* cols = (const int*)d_in[7];
    const int* user = (const int*)d_in[8];
    const int* pos  = (const int*)d_in[9];
    const int* neg  = (const int*)d_in[10];
    float* out = (float*)d_out;

    char* w = (char*)d_ws;
    // 12.8 MB region: CSR staging first, then fp16 agg + slot buffers
    char* region = w;          w += (size_t)N_NODES * DIM * 4;
    ushort* aggh = (ushort*)region;
    int2* staging = (int2*)region;
    int* row_ptr = (int*)w;   w += (((size_t)(N_NODES + 1) * 4) + 255) / 256 * 256;
    uint32* csr  = (uint32*)w; w += (size_t)EDGES * 4;
    int* bhist   = (int*)w;   w += (size_t)NBUCK * NABLK * 4;
    int* boffs   = (int*)w;   w += (size_t)NBUCK * NABLK * 4;
    float* dots  = (float*)w; w += (size_t)3 * BATCH * 4;
    ushort* xhA  = (ushort*)w; w += (size_t)N_NODES * DIM * 2;
    ushort* xhB  = (ushort*)w; w += (size_t)N_NODES * DIM * 2;
    ushort* aggh_slot = (ushort*)w; w += (size_t)NSLOTS * DIM * 2;
    ushort* yh_slot   = (ushort*)w; w += (size_t)NSLOTS * DIM * 2;

    histprep_kernel<<<HP_TOTAL, 256, 0, stream>>>(rows, bhist, emb, xhA,
                                                  user, pos, neg, dots, out);
    boffs_kernel<<<NBUCK, 512, 0, stream>>>(bhist, boffs);
    bucket_scatter_kernel<<<NABLK, 256, 0, stream>>>(rows, cols, vals, boffs, staging);
    csr_build_kernel<<<NBUCK, 512, 0, stream>>>(boffs, staging, row_ptr, csr);

    const int NSB = N_NODES / 4;          // 12500
    const int NTB = BATCH / 4;            // 1024
    const int NDB = (N_NODES + 63) / 64;  // 782
    const int NSLB = NSLOTS / 4;          // 3072 slot-spmm blocks
    const int NSDB = NSLOTS / 64;         // 192 slot-dense blocks

    // layer 0: full spmm on xhA (emb mirror); dense -> xhB
    spmm_kernel<<<NSB, 256, 0, stream>>>(row_ptr, csr, xhA, aggh, user, pos, neg, dots, NSB);
    dense_kernel<<<NDB, 256, 0, stream>>>(xhA, aggh, w1_w + 0 * 4096, w2_w + 0 * 4096,
                                          w1_b + 0 * DIM, w2_b + 0 * DIM, xhB);
    // layer 1: full spmm on xhB (+ dots1 tail); dense -> xhA
    spmm_kernel<<<NSB + NTB, 256, 0, stream>>>(row_ptr, csr, xhB, aggh, user, pos, neg,
                                               dots + BATCH, NSB);
    dense_kernel<<<NDB, 256, 0, stream>>>(xhB, aggh, w1_w + 1 * 4096, w2_w + 1 * 4096,
                                          w1_b + 1 * DIM, w2_b + 1 * DIM, xhA);
    // layer 2 (slots only): spmm_slots on xhA (+ dots2 tail); dense_slots -> yh_slot
    spmm_slots_kernel<<<NSLB + NTB, 256, 0, stream>>>(row_ptr, csr, xhA, aggh_slot,
                                                      user, pos, neg, dots + 2 * BATCH, NSLB);
    dense_slots_kernel<<<NSDB, 256, 0, stream>>>(xhA, aggh_slot,
                                                 w1_w + 2 * 4096, w2_w + 2 * 4096,
                                                 w1_b + 2 * DIM, w2_b + 2 * DIM,
                                                 yh_slot, user, pos, neg);

    dots_loss_kernel<<<NTB, 256, 0, stream>>>(yh_slot, dots, out);
}

// Round 17
// 150.326 us; speedup vs baseline: 2.6767x; 1.0399x over previous
//
#include <hip/hip_runtime.h>
#include <hip/hip_fp16.h>
#include <math.h>

#define N_NODES 50000
#define EDGES   1250000
#define DIM     64
#define NLAYER  3
#define BATCH   4096
#define NSLOTS  (3 * BATCH)   // 12288 = user | pos | neg

#define NBUCK 196   // coarse buckets: bucket = row >> 8 (256 rows each)
#define RPB   256   // rows per bucket
#define NABLK 512   // scatter blocks
#define CAP_S 7424  // fixed staging capacity per bucket (mean 6400, +12.8 sigma)
#define BCAP  CAP_S // csr_build LDS cache = bucket capacity (58 KB)
#define PER_BLK ((EDGES + NABLK - 1) / NABLK)   // 2442 edges per scatter block

typedef unsigned int uint32;
typedef _Float16 f16x8 __attribute__((ext_vector_type(8)));
typedef float f32x4 __attribute__((ext_vector_type(4)));

static __device__ __forceinline__ ushort f2h(float f) {
    return __half_as_ushort(__float2half(f));
}
static __device__ __forceinline__ float h2f(ushort u) {
    return __half2float(__ushort_as_half(u));
}

static __device__ __forceinline__ int slot_node(int slot,
                                                const int* __restrict__ user,
                                                const int* __restrict__ pos,
                                                const int* __restrict__ neg) {
    if (slot < BATCH) return user[slot];
    if (slot < 2 * BATCH) return pos[slot - BATCH];
    return neg[slot - 2 * BATCH];
}

// ---------------- scatterprep: 1-pass bucket scatter + f2h(emb) + dots0 ----
// blocks [0,512): scatter (LDS-staged, self-hist, atomic run reservation);
// [512,3637): f2h; [3637,4661): dots0.

#define SP_F2H   512
#define SP_DOTS  3637
#define SP_TOTAL 4661

__global__ __launch_bounds__(256) void scatterprep_kernel(const int* __restrict__ rows,
                                                          const int* __restrict__ cols,
                                                          const float* __restrict__ vals,
                                                          int* __restrict__ gcur,
                                                          int2* __restrict__ staging,
                                                          const float* __restrict__ emb,
                                                          ushort* __restrict__ xh,
                                                          const int* __restrict__ user,
                                                          const int* __restrict__ pos,
                                                          const int* __restrict__ neg,
                                                          float* __restrict__ dots,
                                                          float* __restrict__ out) {
    __shared__ int2 sedge[PER_BLK];
    __shared__ int h[NBUCK];
    __shared__ int roff[NBUCK];
    int blk = blockIdx.x;
    int tid = threadIdx.x;
    if (blk < SP_F2H) {
        if (blk == 0 && tid == 0) out[0] = 0.f;
        for (int i = tid; i < NBUCK; i += 256) h[i] = 0;
        __syncthreads();
        int e0 = blk * PER_BLK;
        int e1 = min(e0 + PER_BLK, EDGES);
        int cnt = e1 - e0;
        // pass 1: load edges to LDS + local hist
        for (int i = tid; i < cnt; i += 256) {
            int e = e0 + i;
            int r = rows[e];
            sedge[i] = make_int2((r << 16) | cols[e], __float_as_int(vals[e]));
            atomicAdd(&h[r >> 8], 1);
        }
        __syncthreads();
        // pass 2: reserve runs in the global per-bucket cursors
        for (int t = tid; t < NBUCK; t += 256)
            roff[t] = t * CAP_S + atomicAdd(&gcur[t], h[t]);
        __syncthreads();
        // pass 3: scatter LDS -> staging runs
        for (int i = tid; i < cnt; i += 256) {
            int2 e = sedge[i];
            int bkt = ((uint32)e.x) >> 24;
            int p = atomicAdd(&roff[bkt], 1);
            if (p < (bkt + 1) * CAP_S)
                staging[p] = make_int2(e.x & 0x00FFFFFF, e.y);
        }
    } else if (blk < SP_DOTS) {
        int i = (blk - SP_F2H) * 256 + tid;     // < 800000 exactly
        float4 v = ((const float4*)emb)[i];
        ushort4 hh;
        hh.x = f2h(v.x); hh.y = f2h(v.y); hh.z = f2h(v.z); hh.w = f2h(v.w);
        ((ushort4*)xh)[i] = hh;
    } else {
        int lane = tid & 63;
        int i = (blk - SP_DOTS) * 4 + (tid >> 6);
        int ui = user[i], pi = pos[i], ni = neg[i];
        float u = emb[(size_t)ui * DIM + lane];
        float p = emb[(size_t)pi * DIM + lane];
        float n = emb[(size_t)ni * DIM + lane];
        float v = u * (p - n);
#pragma unroll
        for (int off = 32; off; off >>= 1) v += __shfl_xor(v, off);
        if (lane == 0) dots[i] = v;
    }
}

// ---------------- csr_build: self-scanned base + LDS-cached bucket ----------

__global__ __launch_bounds__(512) void csr_build_kernel(const int* __restrict__ gcur,
                                                        const int2* __restrict__ staging,
                                                        int* __restrict__ row_ptr,
                                                        uint32* __restrict__ csr) {
    __shared__ int2 sedge[BCAP];
    __shared__ int sbase[256];
    __shared__ int rcur[RPB];
    __shared__ int wred[4];
    int b = blockIdx.x;
    int tid = threadIdx.x;
    int lane = tid & 63, wid = tid >> 6;

    // exclusive scan of bucket counts -> csr base offsets
    int tot = (tid < NBUCK) ? gcur[tid] : 0;
    int sB = tot;
    if (tid < 256) {
#pragma unroll
        for (int off = 1; off < 64; off <<= 1) {
            int tt = __shfl_up(sB, off);
            if (lane >= off) sB += tt;
        }
        if (lane == 63) wred[wid] = sB;
    }
    __syncthreads();
    if (tid == 0) {
        int a = 0;
#pragma unroll
        for (int i = 0; i < 4; ++i) { int tt = wred[i]; wred[i] = a; a += tt; }
    }
    __syncthreads();
    if (tid < 256) sbase[tid] = wred[wid] + sB - tot;
    __syncthreads();
    int base = sbase[b];
    int cnt = (b == NBUCK - 1) ? (EDGES - sbase[NBUCK - 1]) : (sbase[b + 1] - sbase[b]);
    int sbeg = b * CAP_S;
    __syncthreads();   // wred reuse barrier

    if (tid < RPB) rcur[tid] = 0;
    __syncthreads();
    for (int p = tid; p < cnt; p += 512) {
        int2 e = staging[sbeg + p];
        sedge[p] = e;
        atomicAdd(&rcur[e.x >> 16], 1);
    }
    __syncthreads();
    int v = 0, s = 0;
    if (tid < RPB) {
        v = rcur[tid];
        s = v;
#pragma unroll
        for (int off = 1; off < 64; off <<= 1) {
            int t = __shfl_up(s, off);
            if (lane >= off) s += t;
        }
        if (lane == 63) wred[wid] = s;
    }
    __syncthreads();
    if (tid == 0) {
        int a = 0;
#pragma unroll
        for (int i = 0; i < 4; ++i) { int t = wred[i]; wred[i] = a; a += t; }
    }
    __syncthreads();
    if (tid < RPB) {
        int excl = wred[wid] + s - v;
        rcur[tid] = base + excl;
        int row = b * RPB + tid;
        if (row < N_NODES) row_ptr[row] = base + excl;
    }
    if (b == NBUCK - 1 && tid == 0) row_ptr[N_NODES] = EDGES;
    __syncthreads();
    for (int p = tid; p < cnt; p += 512) {
        int2 e = sedge[p];
        int pos = atomicAdd(&rcur[e.x >> 16], 1);
        csr[pos] = ((uint32)(e.x & 0xFFFF) << 16) | (uint32)f2h(__int_as_float(e.y));
    }
}

// ---------------- SpMM core (shared by full and slot variants) ----------------

static __device__ __forceinline__ void spmm_row(const uint32* __restrict__ csr,
                                                const ushort* __restrict__ xh,
                                                int p0, int p1, int g, int sl,
                                                float* a) {
#define SPMM_ACC(E, X)                                                     \
    {                                                                      \
        float vv = h2f((ushort)((E) & 0xFFFF));                            \
        a[0] += vv * h2f((ushort)((X).x & 0xFFFF));                        \
        a[1] += vv * h2f((ushort)((X).x >> 16));                           \
        a[2] += vv * h2f((ushort)((X).y & 0xFFFF));                        \
        a[3] += vv * h2f((ushort)((X).y >> 16));                           \
        a[4] += vv * h2f((ushort)((X).z & 0xFFFF));                        \
        a[5] += vv * h2f((ushort)((X).z >> 16));                           \
        a[6] += vv * h2f((ushort)((X).w & 0xFFFF));                        \
        a[7] += vv * h2f((ushort)((X).w >> 16));                           \
    }
    int p = p0;
    for (; p + 32 <= p1; p += 32) {
        uint32 e0 = csr[p + g];
        uint32 e1 = csr[p + 8 + g];
        uint32 e2 = csr[p + 16 + g];
        uint32 e3 = csr[p + 24 + g];
        uint4 x0 = *(const uint4*)(xh + (size_t)(e0 >> 16) * DIM + sl * 8);
        uint4 x1 = *(const uint4*)(xh + (size_t)(e1 >> 16) * DIM + sl * 8);
        uint4 x2 = *(const uint4*)(xh + (size_t)(e2 >> 16) * DIM + sl * 8);
        uint4 x3 = *(const uint4*)(xh + (size_t)(e3 >> 16) * DIM + sl * 8);
        SPMM_ACC(e0, x0);
        SPMM_ACC(e1, x1);
        SPMM_ACC(e2, x2);
        SPMM_ACC(e3, x3);
    }
    for (; p + 8 <= p1; p += 8) {
        uint32 ea = csr[p + g];
        uint4 xa = *(const uint4*)(xh + (size_t)(ea >> 16) * DIM + sl * 8);
        SPMM_ACC(ea, xa);
    }
    if (p + g < p1) {
        uint32 ea = csr[p + g];
        uint4 xa = *(const uint4*)(xh + (size_t)(ea >> 16) * DIM + sl * 8);
        SPMM_ACC(ea, xa);
    }
#undef SPMM_ACC
#pragma unroll
    for (int m = 8; m <= 32; m <<= 1) {
        a[0] += __shfl_xor(a[0], m); a[1] += __shfl_xor(a[1], m);
        a[2] += __shfl_xor(a[2], m); a[3] += __shfl_xor(a[3], m);
        a[4] += __shfl_xor(a[4], m); a[5] += __shfl_xor(a[5], m);
        a[6] += __shfl_xor(a[6], m); a[7] += __shfl_xor(a[7], m);
    }
}

static __device__ __forceinline__ void spmm_store(ushort* dst, const float* a, int lane) {
    if (lane < 8) {
        ushort t[8];
        t[0] = f2h(a[0]); t[1] = f2h(a[1]); t[2] = f2h(a[2]); t[3] = f2h(a[3]);
        t[4] = f2h(a[4]); t[5] = f2h(a[5]); t[6] = f2h(a[6]); t[7] = f2h(a[7]);
        *(uint4*)(dst + lane * 8) = *(uint4*)t;
    }
}

static __device__ __forceinline__ void dots_tail(const ushort* __restrict__ xh,
                                                 const int* __restrict__ user,
                                                 const int* __restrict__ pos,
                                                 const int* __restrict__ neg,
                                                 float* __restrict__ dots,
                                                 int i, int lane) {
    int ui = user[i], pi = pos[i], ni = neg[i];
    float u = h2f(xh[(size_t)ui * DIM + lane]);
    float p = h2f(xh[(size_t)pi * DIM + lane]);
    float n = h2f(xh[(size_t)ni * DIM + lane]);
    float v = u * (p - n);
#pragma unroll
    for (int off = 32; off; off >>= 1) v += __shfl_xor(v, off);
    if (lane == 0) dots[i] = v;
}

// ---------------- SpMM full: one wave per node row; optional dots tail ----------

__global__ __launch_bounds__(256) void spmm_kernel(const int* __restrict__ row_ptr,
                                                   const uint32* __restrict__ csr,
                                                   const ushort* __restrict__ xh,
                                                   ushort* __restrict__ aggh,
                                                   const int* __restrict__ user,
                                                   const int* __restrict__ pos,
                                                   const int* __restrict__ neg,
                                                   float* __restrict__ dots,
                                                   int nsb) {
    int lane = threadIdx.x & 63;
    if ((int)blockIdx.x >= nsb) {
        int i = (blockIdx.x - nsb) * 4 + (threadIdx.x >> 6);
        dots_tail(xh, user, pos, neg, dots, i, lane);
        return;
    }
    int row = blockIdx.x * 4 + (threadIdx.x >> 6);
    int p0 = row_ptr[row], p1 = row_ptr[row + 1];
    float a[8] = {};
    spmm_row(csr, xh, p0, p1, lane >> 3, lane & 7, a);
    spmm_store(aggh + (size_t)row * DIM, a, lane);
}

// ---------------- SpMM slots: one wave per batch slot (layer 2 only) ----------

__global__ __launch_bounds__(256) void spmm_slots_kernel(const int* __restrict__ row_ptr,
                                                         const uint32* __restrict__ csr,
                                                         const ushort* __restrict__ xh,
                                                         ushort* __restrict__ aggh_slot,
                                                         const int* __restrict__ user,
                                                         const int* __restrict__ pos,
                                                         const int* __restrict__ neg,
                                                         float* __restrict__ dots,
                                                         int nsb) {
    int lane = threadIdx.x & 63;
    if ((int)blockIdx.x >= nsb) {
        int i = (blockIdx.x - nsb) * 4 + (threadIdx.x >> 6);
        dots_tail(xh, user, pos, neg, dots, i, lane);
        return;
    }
    int slot = blockIdx.x * 4 + (threadIdx.x >> 6);
    int node = slot_node(slot, user, pos, neg);
    int p0 = row_ptr[node], p1 = row_ptr[node + 1];
    float a[8] = {};
    spmm_row(csr, xh, p0, p1, lane >> 3, lane & 7, a);
    spmm_store(aggh_slot + (size_t)slot * DIM, a, lane);
}

// ---------------- Dense core: fp16 MFMA 16x16x32, f32 accumulate ----------

template <int IS_SLOT>
static __device__ __forceinline__ void dense_body(const ushort* __restrict__ xh_in,
                                                  const ushort* __restrict__ aggh,
                                                  const float* __restrict__ w1,
                                                  const float* __restrict__ w2,
                                                  const float* __restrict__ b1,
                                                  const float* __restrict__ b2,
                                                  ushort* __restrict__ yh,
                                                  const int* __restrict__ user,
                                                  const int* __restrict__ pos,
                                                  const int* __restrict__ neg) {
    __shared__ ushort xs[64 * 64];
    __shared__ ushort xc[64 * 64];
    __shared__ ushort w1s[64 * 64];
    __shared__ ushort w2s[64 * 64];

    int tid = threadIdx.x;
    int n0 = blockIdx.x * 64;

    {
        int rr = tid >> 2;
        int jq = (tid & 3) << 4;
        int sw = rr & 7;
        int b0 = jq >> 3;
        int o0 = rr * 64 + (((b0 + 0) ^ sw) << 3);
        int o1 = rr * 64 + (((b0 + 1) ^ sw) << 3);

        {
            const float* w1r = w1 + rr * 64 + jq;
            const float* w2r = w2 + rr * 64 + jq;
            ushort t1[16], t2[16];
#pragma unroll
            for (int k = 0; k < 4; ++k) {
                float4 a = ((const float4*)w1r)[k];
                float4 b = ((const float4*)w2r)[k];
                t1[k * 4 + 0] = f2h(a.x); t1[k * 4 + 1] = f2h(a.y);
                t1[k * 4 + 2] = f2h(a.z); t1[k * 4 + 3] = f2h(a.w);
                t2[k * 4 + 0] = f2h(b.x); t2[k * 4 + 1] = f2h(b.y);
                t2[k * 4 + 2] = f2h(b.z); t2[k * 4 + 3] = f2h(b.w);
            }
            *(uint4*)&w1s[o0] = *(uint4*)&t1[0];
            *(uint4*)&w1s[o1] = *(uint4*)&t1[8];
            *(uint4*)&w2s[o0] = *(uint4*)&t2[0];
            *(uint4*)&w2s[o1] = *(uint4*)&t2[8];
        }
        {
            int rowid = n0 + rr;
            int xnode, arow;
            if (IS_SLOT) {
                xnode = slot_node(rowid, user, pos, neg);
                arow = rowid;
            } else {
                xnode = (rowid < N_NODES) ? rowid : (N_NODES - 1);
                arow = xnode;
            }
            const ushort* ar = aggh + (size_t)arow * DIM + jq;
            const ushort* xr = xh_in + (size_t)xnode * DIM + jq;
            ushort txs[16], txc[16];
#pragma unroll
            for (int k = 0; k < 2; ++k) {
                uint4 xv = ((const uint4*)xr)[k];
                uint4 av = ((const uint4*)ar)[k];
                uint32 xw[4] = {xv.x, xv.y, xv.z, xv.w};
                uint32 aw[4] = {av.x, av.y, av.z, av.w};
#pragma unroll
                for (int q = 0; q < 4; ++q) {
                    ushort xlo = (ushort)(xw[q] & 0xFFFF);
                    ushort xhi = (ushort)(xw[q] >> 16);
                    ushort alo = (ushort)(aw[q] & 0xFFFF);
                    ushort ahi = (ushort)(aw[q] >> 16);
                    int e = k * 8 + q * 2;
                    txc[e] = xlo; txc[e + 1] = xhi;
                    txs[e] = f2h(h2f(xlo) + h2f(alo));
                    txs[e + 1] = f2h(h2f(xhi) + h2f(ahi));
                }
            }
            *(uint4*)&xs[o0] = *(uint4*)&txs[0];
            *(uint4*)&xs[o1] = *(uint4*)&txs[8];
            *(uint4*)&xc[o0] = *(uint4*)&txc[0];
            *(uint4*)&xc[o1] = *(uint4*)&txc[8];
        }
    }
    __syncthreads();

    int lane = tid & 63, w = tid >> 6;
    int nb = w << 4;
    int lm = lane & 15;
    int le = lane >> 4;

    f16x8 axs[2], axc[2];
#pragma unroll
    for (int k = 0; k < 2; ++k) {
        int n = nb + lm;
        int blk = k * 4 + le;
        int off = n * 64 + ((blk ^ (n & 7)) << 3);
        axs[k] = *(const f16x8*)&xs[off];
        axc[k] = *(const f16x8*)&xc[off];
    }

#pragma unroll
    for (int dt = 0; dt < 4; ++dt) {
        int d = dt * 16 + lm;
        f16x8 bf1[2], bf2[2];
#pragma unroll
        for (int k = 0; k < 2; ++k) {
            int blk = k * 4 + le;
            int off = d * 64 + ((blk ^ (d & 7)) << 3);
            bf1[k] = *(const f16x8*)&w1s[off];
            bf2[k] = *(const f16x8*)&w2s[off];
        }
        f32x4 acc1 = {0.f, 0.f, 0.f, 0.f};
        f32x4 acc2 = {0.f, 0.f, 0.f, 0.f};
        acc1 = __builtin_amdgcn_mfma_f32_16x16x32_f16(axs[0], bf1[0], acc1, 0, 0, 0);
        acc1 = __builtin_amdgcn_mfma_f32_16x16x32_f16(axs[1], bf1[1], acc1, 0, 0, 0);
        acc2 = __builtin_amdgcn_mfma_f32_16x16x32_f16(axc[0], bf2[0], acc2, 0, 0, 0);
        acc2 = __builtin_amdgcn_mfma_f32_16x16x32_f16(axc[1], bf2[1], acc2, 0, 0, 0);

        float b1v = b1[d], b2v = b2[d];
        int bb = d >> 3;
#pragma unroll
        for (int i = 0; i < 4; ++i) {
            int nl = nb + (le << 2) + i;
            int rowid = n0 + nl;
            int off = nl * 64 + ((bb ^ (nl & 7)) << 3) + (d & 7);
            float ag = h2f(xs[off]) - h2f(xc[off]);
            float t = acc1[i] + b1v + ag * (acc2[i] + b2v);
            t = (t > 0.f) ? t : 0.01f * t;
            bool wr = IS_SLOT ? true : (rowid < N_NODES);
            if (wr) yh[(size_t)rowid * DIM + d] = f2h(t);
        }
    }
}

__global__ __launch_bounds__(256) void dense_kernel(const ushort* __restrict__ xh_in,
                                                    const ushort* __restrict__ aggh,
                                                    const float* __restrict__ w1,
                                                    const float* __restrict__ w2,
                                                    const float* __restrict__ b1,
                                                    const float* __restrict__ b2,
                                                    ushort* __restrict__ yh) {
    dense_body<0>(xh_in, aggh, w1, w2, b1, b2, yh, nullptr, nullptr, nullptr);
}

__global__ __launch_bounds__(256) void dense_slots_kernel(const ushort* __restrict__ xh_in,
                                                          const ushort* __restrict__ aggh_slot,
                                                          const float* __restrict__ w1,
                                                          const float* __restrict__ w2,
                                                          const float* __restrict__ b1,
                                                          const float* __restrict__ b2,
                                                          ushort* __restrict__ yh_slot,
                                                          const int* __restrict__ user,
                                                          const int* __restrict__ pos,
                                                          const int* __restrict__ neg) {
    dense_body<1>(xh_in, aggh_slot, w1, w2, b1, b2, yh_slot, user, pos, neg);
}

// ---------------- dots layer 3 (from slot rows, coalesced) + loss ----------------

__global__ __launch_bounds__(256) void dots_loss_kernel(const ushort* __restrict__ yh_slot,
                                                        const float* __restrict__ dots,
                                                        float* __restrict__ out) {
    __shared__ float part[4];
    int tid = threadIdx.x;
    int lane = tid & 63;
    int i = blockIdx.x * 4 + (tid >> 6);
    float u = h2f(yh_slot[(size_t)i * DIM + lane]);
    float p = h2f(yh_slot[(size_t)(BATCH + i) * DIM + lane]);
    float n = h2f(yh_slot[(size_t)(2 * BATCH + i) * DIM + lane]);
    float v = u * (p - n);
#pragma unroll
    for (int off = 32; off; off >>= 1) v += __shfl_xor(v, off);
    if (lane == 0) {
        float d = dots[i] + dots[BATCH + i] + dots[2 * BATCH + i] + v;
        part[tid >> 6] = fmaxf(-d, 0.f) + log1pf(expf(-fabsf(d)));
    }
    __syncthreads();
    if (tid == 0) atomicAdd(out, part[0] + part[1] + part[2] + part[3]);
}

// ---------------- Launch ----------------

extern "C" void kernel_launch(void* const* d_in, const int* in_sizes, int n_in,
                              void* d_out, int out_size, void* d_ws, size_t ws_size,
                              hipStream_t stream) {
    const float* emb  = (const float*)d_in[0];
    const float* w1_w = (const float*)d_in[1];
    const float* w1_b = (const float*)d_in[2];
    const float* w2_w = (const float*)d_in[3];
    const float* w2_b = (const float*)d_in[4];
    const float* vals = (const float*)d_in[5];
    const int* rows = (const int*)d_in[6];
    const int* cols = (const int*)d_in[7];
    const int* user = (const int*)d_in[8];
    const int* pos  = (const int*)d_in[9];
    const int* neg  = (const int*)d_in[10];
    float* out = (float*)d_out;

    char* w = (char*)d_ws;
    // 11.64 MB staging region (196 x 7424 x 8B), aliased with fp16 agg (6.4 MB)
    char* region = w;          w += (size_t)NBUCK * CAP_S * 8;
    ushort* aggh = (ushort*)region;
    int2* staging = (int2*)region;
    int* row_ptr = (int*)w;   w += (((size_t)(N_NODES + 1) * 4) + 255) / 256 * 256;
    uint32* csr  = (uint32*)w; w += (size_t)EDGES * 4;
    int* gcur    = (int*)w;   w += 256 * 4;
    float* dots  = (float*)w; w += (size_t)3 * BATCH * 4;
    ushort* xhA  = (ushort*)w; w += (size_t)N_NODES * DIM * 2;
    ushort* xhB  = (ushort*)w; w += (size_t)N_NODES * DIM * 2;
    ushort* aggh_slot = (ushort*)w; w += (size_t)NSLOTS * DIM * 2;
    ushort* yh_slot   = (ushort*)w; w += (size_t)NSLOTS * DIM * 2;

    hipMemsetAsync(gcur, 0, 256 * 4, stream);

    scatterprep_kernel<<<SP_TOTAL, 256, 0, stream>>>(rows, cols, vals, gcur, staging,
                                                     emb, xhA, user, pos, neg, dots, out);
    csr_build_kernel<<<NBUCK, 512, 0, stream>>>(gcur, staging, row_ptr, csr);

    const int NSB = N_NODES / 4;          // 12500
    const int NTB = BATCH / 4;            // 1024
    const int NDB = (N_NODES + 63) / 64;  // 782
    const int NSLB = NSLOTS / 4;          // 3072
    const int NSDB = NSLOTS / 64;         // 192

    // layer 0: full spmm on xhA (emb mirror); dense -> xhB
    spmm_kernel<<<NSB, 256, 0, stream>>>(row_ptr, csr, xhA, aggh, user, pos, neg, dots, NSB);
    dense_kernel<<<NDB, 256, 0, stream>>>(xhA, aggh, w1_w + 0 * 4096, w2_w + 0 * 4096,
                                          w1_b + 0 * DIM, w2_b + 0 * DIM, xhB);
    // layer 1: full spmm on xhB (+ dots1 tail); dense -> xhA
    spmm_kernel<<<NSB + NTB, 256, 0, stream>>>(row_ptr, csr, xhB, aggh, user, pos, neg,
                                               dots + BATCH, NSB);
    dense_kernel<<<NDB, 256, 0, stream>>>(xhB, aggh, w1_w + 1 * 4096, w2_w + 1 * 4096,
                                          w1_b + 1 * DIM, w2_b + 1 * DIM, xhA);
    // layer 2 (slots only): spmm_slots on xhA (+ dots2 tail); dense_slots -> yh_slot
    spmm_slots_kernel<<<NSLB + NTB, 256, 0, stream>>>(row_ptr, csr, xhA, aggh_slot,
                                                      user, pos, neg, dots + 2 * BATCH, NSLB);
    dense_slots_kernel<<<NSDB, 256, 0, stream>>>(xhA, aggh_slot,
                                                 w1_w + 2 * 4096, w2_w + 2 * 4096,
                                                 w1_b + 2 * DIM, w2_b + 2 * DIM,
                                                 yh_slot, user, pos, neg);

    dots_loss_kernel<<<NTB, 256, 0, stream>>>(yh_slot, dots, out);
}

// Round 18
// 143.983 us; speedup vs baseline: 2.7946x; 1.0441x over previous
//
#include <hip/hip_runtime.h>
#include <hip/hip_fp16.h>
#include <math.h>

#define N_NODES 50000
#define EDGES   1250000
#define DIM     64
#define NLAYER  3
#define BATCH   4096
#define NSLOTS  (3 * BATCH)   // 12288 = user | pos | neg

#define NBUCK 196   // coarse buckets: bucket = row >> 8 (256 rows each)
#define RPB   256   // rows per bucket
#define NABLK 512   // scatter blocks
#define CAP_S 7424  // fixed staging capacity per bucket
#define BCAP  CAP_S
#define PER_BLK ((EDGES + NABLK - 1) / NABLK)   // 2442 edges per scatter block

typedef unsigned int uint32;
typedef _Float16 f16x8 __attribute__((ext_vector_type(8)));
typedef float f32x4 __attribute__((ext_vector_type(4)));

static __device__ __forceinline__ ushort f2h(float f) {
    return __half_as_ushort(__float2half(f));
}
static __device__ __forceinline__ float h2f(ushort u) {
    return __half2float(__ushort_as_half(u));
}
static __device__ __forceinline__ float b2f(uint32 w, int k) {
    return (float)(int)(char)(w >> (8 * k));
}
static __device__ __forceinline__ char fq(float v, float inv_scale) {
    float q = rintf(v * inv_scale);
    q = fminf(fmaxf(q, -127.f), 127.f);
    return (char)(int)q;
}

static __device__ __forceinline__ int slot_node(int slot,
                                                const int* __restrict__ user,
                                                const int* __restrict__ pos,
                                                const int* __restrict__ neg) {
    if (slot < BATCH) return user[slot];
    if (slot < 2 * BATCH) return pos[slot - BATCH];
    return neg[slot - 2 * BATCH];
}

// ---------------- scatterprep: 1-pass bucket scatter + quantize(emb) + dots0 ----
// blocks [0,512): scatter; [512,13012): quantize emb rows; [13012,14036): dots0.

#define SP_QNT   512
#define SP_DOTS  13012
#define SP_TOTAL 14036

__global__ __launch_bounds__(256) void scatterprep_kernel(const int* __restrict__ rows,
                                                          const int* __restrict__ cols,
                                                          const float* __restrict__ vals,
                                                          int* __restrict__ gcur,
                                                          int2* __restrict__ staging,
                                                          const float* __restrict__ emb,
                                                          char* __restrict__ xq,
                                                          float* __restrict__ xscale,
                                                          const int* __restrict__ user,
                                                          const int* __restrict__ pos,
                                                          const int* __restrict__ neg,
                                                          float* __restrict__ dots,
                                                          float* __restrict__ out) {
    __shared__ int2 sedge[PER_BLK];
    __shared__ int h[NBUCK];
    __shared__ int roff[NBUCK];
    int blk = blockIdx.x;
    int tid = threadIdx.x;
    if (blk < SP_QNT) {
        if (blk == 0 && tid == 0) out[0] = 0.f;
        for (int i = tid; i < NBUCK; i += 256) h[i] = 0;
        __syncthreads();
        int e0 = blk * PER_BLK;
        int e1 = min(e0 + PER_BLK, EDGES);
        int cnt = e1 - e0;
        for (int i = tid; i < cnt; i += 256) {
            int e = e0 + i;
            int r = rows[e];
            sedge[i] = make_int2((r << 16) | cols[e], __float_as_int(vals[e]));
            atomicAdd(&h[r >> 8], 1);
        }
        __syncthreads();
        for (int t = tid; t < NBUCK; t += 256)
            roff[t] = t * CAP_S + atomicAdd(&gcur[t], h[t]);
        __syncthreads();
        for (int i = tid; i < cnt; i += 256) {
            int2 e = sedge[i];
            int bkt = ((uint32)e.x) >> 24;
            int p = atomicAdd(&roff[bkt], 1);
            if (p < (bkt + 1) * CAP_S)
                staging[p] = make_int2(e.x & 0x00FFFFFF, e.y);
        }
    } else if (blk < SP_DOTS) {
        int lane = tid & 63;
        int row = (blk - SP_QNT) * 4 + (tid >> 6);   // < 50000 exactly
        float v = emb[(size_t)row * DIM + lane];
        float m = fabsf(v);
#pragma unroll
        for (int off = 32; off; off >>= 1) m = fmaxf(m, __shfl_xor(m, off));
        float scale = fmaxf(m, 1e-8f) * (1.f / 127.f);
        xq[(size_t)row * DIM + lane] = fq(v, 127.f / fmaxf(m, 1e-8f));
        if (lane == 0) xscale[row] = scale;
    } else {
        int lane = tid & 63;
        int i = (blk - SP_DOTS) * 4 + (tid >> 6);
        int ui = user[i], pi = pos[i], ni = neg[i];
        float u = emb[(size_t)ui * DIM + lane];
        float p = emb[(size_t)pi * DIM + lane];
        float n = emb[(size_t)ni * DIM + lane];
        float v = u * (p - n);
#pragma unroll
        for (int off = 32; off; off >>= 1) v += __shfl_xor(v, off);
        if (lane == 0) dots[i] = v;
    }
}

// ---------------- csr_build: self-scanned base + LDS-cached bucket ----------

__global__ __launch_bounds__(512) void csr_build_kernel(const int* __restrict__ gcur,
                                                        const int2* __restrict__ staging,
                                                        int* __restrict__ row_ptr,
                                                        uint32* __restrict__ csr) {
    __shared__ int2 sedge[BCAP];
    __shared__ int sbase[256];
    __shared__ int rcur[RPB];
    __shared__ int wred[4];
    int b = blockIdx.x;
    int tid = threadIdx.x;
    int lane = tid & 63, wid = tid >> 6;

    int tot = (tid < NBUCK) ? gcur[tid] : 0;
    int sB = tot;
    if (tid < 256) {
#pragma unroll
        for (int off = 1; off < 64; off <<= 1) {
            int tt = __shfl_up(sB, off);
            if (lane >= off) sB += tt;
        }
        if (lane == 63) wred[wid] = sB;
    }
    __syncthreads();
    if (tid == 0) {
        int a = 0;
#pragma unroll
        for (int i = 0; i < 4; ++i) { int tt = wred[i]; wred[i] = a; a += tt; }
    }
    __syncthreads();
    if (tid < 256) sbase[tid] = wred[wid] + sB - tot;
    __syncthreads();
    int base = sbase[b];
    int cnt = (b == NBUCK - 1) ? (EDGES - sbase[NBUCK - 1]) : (sbase[b + 1] - sbase[b]);
    int sbeg = b * CAP_S;
    __syncthreads();

    if (tid < RPB) rcur[tid] = 0;
    __syncthreads();
    for (int p = tid; p < cnt; p += 512) {
        int2 e = staging[sbeg + p];
        sedge[p] = e;
        atomicAdd(&rcur[e.x >> 16], 1);
    }
    __syncthreads();
    int v = 0, s = 0;
    if (tid < RPB) {
        v = rcur[tid];
        s = v;
#pragma unroll
        for (int off = 1; off < 64; off <<= 1) {
            int t = __shfl_up(s, off);
            if (lane >= off) s += t;
        }
        if (lane == 63) wred[wid] = s;
    }
    __syncthreads();
    if (tid == 0) {
        int a = 0;
#pragma unroll
        for (int i = 0; i < 4; ++i) { int t = wred[i]; wred[i] = a; a += t; }
    }
    __syncthreads();
    if (tid < RPB) {
        int excl = wred[wid] + s - v;
        rcur[tid] = base + excl;
        int row = b * RPB + tid;
        if (row < N_NODES) row_ptr[row] = base + excl;
    }
    if (b == NBUCK - 1 && tid == 0) row_ptr[N_NODES] = EDGES;
    __syncthreads();
    for (int p = tid; p < cnt; p += 512) {
        int2 e = sedge[p];
        int pos = atomicAdd(&rcur[e.x >> 16], 1);
        csr[pos] = ((uint32)(e.x & 0xFFFF) << 16) | (uint32)f2h(__int_as_float(e.y));
    }
}

// ---------------- SpMM core: int8 gather (64B/row) + per-row scale ----------

static __device__ __forceinline__ void spmm_row(const uint32* __restrict__ csr,
                                                const char* __restrict__ xq,
                                                const float* __restrict__ xscale,
                                                int p0, int p1, int g, int sl,
                                                float* a) {
#define SPMM_ACC(E, X)                                                     \
    {                                                                      \
        int c_ = (E) >> 16;                                                \
        float vv = h2f((ushort)((E) & 0xFFFF)) * xscale[c_];               \
        a[0] += vv * b2f((X).x, 0);                                        \
        a[1] += vv * b2f((X).x, 1);                                        \
        a[2] += vv * b2f((X).x, 2);                                        \
        a[3] += vv * b2f((X).x, 3);                                        \
        a[4] += vv * b2f((X).y, 0);                                        \
        a[5] += vv * b2f((X).y, 1);                                        \
        a[6] += vv * b2f((X).y, 2);                                        \
        a[7] += vv * b2f((X).y, 3);                                        \
    }
    int p = p0;
    for (; p + 32 <= p1; p += 32) {
        uint32 e0 = csr[p + g];
        uint32 e1 = csr[p + 8 + g];
        uint32 e2 = csr[p + 16 + g];
        uint32 e3 = csr[p + 24 + g];
        uint2 x0 = *(const uint2*)(xq + (size_t)(e0 >> 16) * DIM + sl * 8);
        uint2 x1 = *(const uint2*)(xq + (size_t)(e1 >> 16) * DIM + sl * 8);
        uint2 x2 = *(const uint2*)(xq + (size_t)(e2 >> 16) * DIM + sl * 8);
        uint2 x3 = *(const uint2*)(xq + (size_t)(e3 >> 16) * DIM + sl * 8);
        SPMM_ACC(e0, x0);
        SPMM_ACC(e1, x1);
        SPMM_ACC(e2, x2);
        SPMM_ACC(e3, x3);
    }
    for (; p + 8 <= p1; p += 8) {
        uint32 ea = csr[p + g];
        uint2 xa = *(const uint2*)(xq + (size_t)(ea >> 16) * DIM + sl * 8);
        SPMM_ACC(ea, xa);
    }
    if (p + g < p1) {
        uint32 ea = csr[p + g];
        uint2 xa = *(const uint2*)(xq + (size_t)(ea >> 16) * DIM + sl * 8);
        SPMM_ACC(ea, xa);
    }
#undef SPMM_ACC
#pragma unroll
    for (int m = 8; m <= 32; m <<= 1) {
        a[0] += __shfl_xor(a[0], m); a[1] += __shfl_xor(a[1], m);
        a[2] += __shfl_xor(a[2], m); a[3] += __shfl_xor(a[3], m);
        a[4] += __shfl_xor(a[4], m); a[5] += __shfl_xor(a[5], m);
        a[6] += __shfl_xor(a[6], m); a[7] += __shfl_xor(a[7], m);
    }
}

static __device__ __forceinline__ void spmm_store(ushort* dst, const float* a, int lane) {
    if (lane < 8) {
        ushort t[8];
        t[0] = f2h(a[0]); t[1] = f2h(a[1]); t[2] = f2h(a[2]); t[3] = f2h(a[3]);
        t[4] = f2h(a[4]); t[5] = f2h(a[5]); t[6] = f2h(a[6]); t[7] = f2h(a[7]);
        *(uint4*)(dst + lane * 8) = *(uint4*)t;
    }
}

static __device__ __forceinline__ void dots_tail_q(const char* __restrict__ xq,
                                                   const float* __restrict__ xscale,
                                                   const int* __restrict__ user,
                                                   const int* __restrict__ pos,
                                                   const int* __restrict__ neg,
                                                   float* __restrict__ dots,
                                                   int i, int lane) {
    int ui = user[i], pi = pos[i], ni = neg[i];
    float u = (float)(int)xq[(size_t)ui * DIM + lane] * xscale[ui];
    float p = (float)(int)xq[(size_t)pi * DIM + lane] * xscale[pi];
    float n = (float)(int)xq[(size_t)ni * DIM + lane] * xscale[ni];
    float v = u * (p - n);
#pragma unroll
    for (int off = 32; off; off >>= 1) v += __shfl_xor(v, off);
    if (lane == 0) dots[i] = v;
}

// ---------------- SpMM full: one wave per node row; optional dots tail ----------

__global__ __launch_bounds__(256) void spmm_kernel(const int* __restrict__ row_ptr,
                                                   const uint32* __restrict__ csr,
                                                   const char* __restrict__ xq,
                                                   const float* __restrict__ xscale,
                                                   ushort* __restrict__ aggh,
                                                   const int* __restrict__ user,
                                                   const int* __restrict__ pos,
                                                   const int* __restrict__ neg,
                                                   float* __restrict__ dots,
                                                   int nsb) {
    int lane = threadIdx.x & 63;
    if ((int)blockIdx.x >= nsb) {
        int i = (blockIdx.x - nsb) * 4 + (threadIdx.x >> 6);
        dots_tail_q(xq, xscale, user, pos, neg, dots, i, lane);
        return;
    }
    int row = blockIdx.x * 4 + (threadIdx.x >> 6);
    int p0 = row_ptr[row], p1 = row_ptr[row + 1];
    float a[8] = {};
    spmm_row(csr, xq, xscale, p0, p1, lane >> 3, lane & 7, a);
    spmm_store(aggh + (size_t)row * DIM, a, lane);
}

// ---------------- SpMM slots: one wave per batch slot (layer 2 only) ----------

__global__ __launch_bounds__(256) void spmm_slots_kernel(const int* __restrict__ row_ptr,
                                                         const uint32* __restrict__ csr,
                                                         const char* __restrict__ xq,
                                                         const float* __restrict__ xscale,
                                                         ushort* __restrict__ aggh_slot,
                                                         const int* __restrict__ user,
                                                         const int* __restrict__ pos,
                                                         const int* __restrict__ neg,
                                                         float* __restrict__ dots,
                                                         int nsb) {
    int lane = threadIdx.x & 63;
    if ((int)blockIdx.x >= nsb) {
        int i = (blockIdx.x - nsb) * 4 + (threadIdx.x >> 6);
        dots_tail_q(xq, xscale, user, pos, neg, dots, i, lane);
        return;
    }
    int slot = blockIdx.x * 4 + (threadIdx.x >> 6);
    int node = slot_node(slot, user, pos, neg);
    int p0 = row_ptr[node], p1 = row_ptr[node + 1];
    float a[8] = {};
    spmm_row(csr, xq, xscale, p0, p1, lane >> 3, lane & 7, a);
    spmm_store(aggh_slot + (size_t)slot * DIM, a, lane);
}

// ---------------- Dense core: fp16 MFMA, int8 in / int8 out ----------

template <int IS_SLOT>
static __device__ __forceinline__ void dense_body(const char* __restrict__ xq_in,
                                                  const float* __restrict__ xscale_in,
                                                  const ushort* __restrict__ aggh,
                                                  const float* __restrict__ w1,
                                                  const float* __restrict__ w2,
                                                  const float* __restrict__ b1,
                                                  const float* __restrict__ b2,
                                                  char* __restrict__ yq,
                                                  float* __restrict__ yscale,
                                                  const int* __restrict__ user,
                                                  const int* __restrict__ pos,
                                                  const int* __restrict__ neg) {
    __shared__ ushort xs[64 * 64];
    __shared__ ushort xc[64 * 64];
    __shared__ ushort w1s[64 * 64];
    __shared__ ushort w2s[64 * 64];

    int tid = threadIdx.x;
    int n0 = blockIdx.x * 64;

    {
        int rr = tid >> 2;
        int jq = (tid & 3) << 4;
        int sw = rr & 7;
        int b0 = jq >> 3;
        int o0 = rr * 64 + (((b0 + 0) ^ sw) << 3);
        int o1 = rr * 64 + (((b0 + 1) ^ sw) << 3);

        {
            const float* w1r = w1 + rr * 64 + jq;
            const float* w2r = w2 + rr * 64 + jq;
            ushort t1[16], t2[16];
#pragma unroll
            for (int k = 0; k < 4; ++k) {
                float4 a = ((const float4*)w1r)[k];
                float4 b = ((const float4*)w2r)[k];
                t1[k * 4 + 0] = f2h(a.x); t1[k * 4 + 1] = f2h(a.y);
                t1[k * 4 + 2] = f2h(a.z); t1[k * 4 + 3] = f2h(a.w);
                t2[k * 4 + 0] = f2h(b.x); t2[k * 4 + 1] = f2h(b.y);
                t2[k * 4 + 2] = f2h(b.z); t2[k * 4 + 3] = f2h(b.w);
            }
            *(uint4*)&w1s[o0] = *(uint4*)&t1[0];
            *(uint4*)&w1s[o1] = *(uint4*)&t1[8];
            *(uint4*)&w2s[o0] = *(uint4*)&t2[0];
            *(uint4*)&w2s[o1] = *(uint4*)&t2[8];
        }
        {
            int rowid = n0 + rr;
            int xnode, arow;
            if (IS_SLOT) {
                xnode = slot_node(rowid, user, pos, neg);
                arow = rowid;
            } else {
                xnode = (rowid < N_NODES) ? rowid : (N_NODES - 1);
                arow = xnode;
            }
            float xsc = xscale_in[xnode];
            const ushort* ar = aggh + (size_t)arow * DIM + jq;
            uint4 qv = *(const uint4*)(xq_in + (size_t)xnode * DIM + jq);
            uint32 qw[4] = {qv.x, qv.y, qv.z, qv.w};
            ushort txs[16], txc[16];
#pragma unroll
            for (int q = 0; q < 4; ++q) {
#pragma unroll
                for (int k = 0; k < 4; ++k) {
                    int e = q * 4 + k;
                    float xv = b2f(qw[q], k) * xsc;
                    txc[e] = f2h(xv);
                    txs[e] = f2h(xv + h2f(ar[e]));
                }
            }
            *(uint4*)&xs[o0] = *(uint4*)&txs[0];
            *(uint4*)&xs[o1] = *(uint4*)&txs[8];
            *(uint4*)&xc[o0] = *(uint4*)&txc[0];
            *(uint4*)&xc[o1] = *(uint4*)&txc[8];
        }
    }
    __syncthreads();

    int lane = tid & 63, w = tid >> 6;
    int nb = w << 4;
    int lm = lane & 15;
    int le = lane >> 4;

    f16x8 axs[2], axc[2];
#pragma unroll
    for (int k = 0; k < 2; ++k) {
        int n = nb + lm;
        int blk = k * 4 + le;
        int off = n * 64 + ((blk ^ (n & 7)) << 3);
        axs[k] = *(const f16x8*)&xs[off];
        axc[k] = *(const f16x8*)&xc[off];
    }

    float tv[4][4];   // [dt][i]

#pragma unroll
    for (int dt = 0; dt < 4; ++dt) {
        int d = dt * 16 + lm;
        f16x8 bf1[2], bf2[2];
#pragma unroll
        for (int k = 0; k < 2; ++k) {
            int blk = k * 4 + le;
            int off = d * 64 + ((blk ^ (d & 7)) << 3);
            bf1[k] = *(const f16x8*)&w1s[off];
            bf2[k] = *(const f16x8*)&w2s[off];
        }
        f32x4 acc1 = {0.f, 0.f, 0.f, 0.f};
        f32x4 acc2 = {0.f, 0.f, 0.f, 0.f};
        acc1 = __builtin_amdgcn_mfma_f32_16x16x32_f16(axs[0], bf1[0], acc1, 0, 0, 0);
        acc1 = __builtin_amdgcn_mfma_f32_16x16x32_f16(axs[1], bf1[1], acc1, 0, 0, 0);
        acc2 = __builtin_amdgcn_mfma_f32_16x16x32_f16(axc[0], bf2[0], acc2, 0, 0, 0);
        acc2 = __builtin_amdgcn_mfma_f32_16x16x32_f16(axc[1], bf2[1], acc2, 0, 0, 0);

        float b1v = b1[d], b2v = b2[d];
        int bb = d >> 3;
#pragma unroll
        for (int i = 0; i < 4; ++i) {
            int nl = nb + (le << 2) + i;
            int off = nl * 64 + ((bb ^ (nl & 7)) << 3) + (d & 7);
            float ag = h2f(xs[off]) - h2f(xc[off]);
            float t = acc1[i] + b1v + ag * (acc2[i] + b2v);
            tv[dt][i] = (t > 0.f) ? t : 0.01f * t;
        }
    }

    // epilogue: per-node row max -> scale -> int8 quantize
#pragma unroll
    for (int i = 0; i < 4; ++i) {
        int nl = nb + (le << 2) + i;
        int rowid = n0 + nl;
        float m = fmaxf(fmaxf(fabsf(tv[0][i]), fabsf(tv[1][i])),
                        fmaxf(fabsf(tv[2][i]), fabsf(tv[3][i])));
#pragma unroll
        for (int off = 1; off < 16; off <<= 1) m = fmaxf(m, __shfl_xor(m, off));
        float mm = fmaxf(m, 1e-8f);
        float inv = 127.f / mm;
        bool wr = IS_SLOT ? true : (rowid < N_NODES);
        if (wr) {
            if (lm == 0) yscale[rowid] = mm * (1.f / 127.f);
#pragma unroll
            for (int dt = 0; dt < 4; ++dt)
                yq[(size_t)rowid * DIM + dt * 16 + lm] = fq(tv[dt][i], inv);
        }
    }
}

__global__ __launch_bounds__(256) void dense_kernel(const char* __restrict__ xq_in,
                                                    const float* __restrict__ xscale_in,
                                                    const ushort* __restrict__ aggh,
                                                    const float* __restrict__ w1,
                                                    const float* __restrict__ w2,
                                                    const float* __restrict__ b1,
                                                    const float* __restrict__ b2,
                                                    char* __restrict__ yq,
                                                    float* __restrict__ yscale) {
    dense_body<0>(xq_in, xscale_in, aggh, w1, w2, b1, b2, yq, yscale,
                  nullptr, nullptr, nullptr);
}

__global__ __launch_bounds__(256) void dense_slots_kernel(const char* __restrict__ xq_in,
                                                          const float* __restrict__ xscale_in,
                                                          const ushort* __restrict__ aggh_slot,
                                                          const float* __restrict__ w1,
                                                          const float* __restrict__ w2,
                                                          const float* __restrict__ b1,
                                                          const float* __restrict__ b2,
                                                          char* __restrict__ yq_slot,
                                                          float* __restrict__ yscale_slot,
                                                          const int* __restrict__ user,
                                                          const int* __restrict__ pos,
                                                          const int* __restrict__ neg) {
    dense_body<1>(xq_in, xscale_in, aggh_slot, w1, w2, b1, b2, yq_slot, yscale_slot,
                  user, pos, neg);
}

// ---------------- dots layer 3 (from slot rows, coalesced) + loss ----------------

__global__ __launch_bounds__(256) void dots_loss_kernel(const char* __restrict__ yq_slot,
                                                        const float* __restrict__ yscale_slot,
                                                        const float* __restrict__ dots,
                                                        float* __restrict__ out) {
    __shared__ float part[4];
    int tid = threadIdx.x;
    int lane = tid & 63;
    int i = blockIdx.x * 4 + (tid >> 6);
    float su = yscale_slot[i];
    float sp = yscale_slot[BATCH + i];
    float sn = yscale_slot[2 * BATCH + i];
    float u = (float)(int)yq_slot[(size_t)i * DIM + lane] * su;
    float p = (float)(int)yq_slot[(size_t)(BATCH + i) * DIM + lane] * sp;
    float n = (float)(int)yq_slot[(size_t)(2 * BATCH + i) * DIM + lane] * sn;
    float v = u * (p - n);
#pragma unroll
    for (int off = 32; off; off >>= 1) v += __shfl_xor(v, off);
    if (lane == 0) {
        float d = dots[i] + dots[BATCH + i] + dots[2 * BATCH + i] + v;
        part[tid >> 6] = fmaxf(-d, 0.f) + log1pf(expf(-fabsf(d)));
    }
    __syncthreads();
    if (tid == 0) atomicAdd(out, part[0] + part[1] + part[2] + part[3]);
}

// ---------------- Launch ----------------

extern "C" void kernel_launch(void* const* d_in, const int* in_sizes, int n_in,
                              void* d_out, int out_size, void* d_ws, size_t ws_size,
                              hipStream_t stream) {
    const float* emb  = (const float*)d_in[0];
    const float* w1_w = (const float*)d_in[1];
    const float* w1_b = (const float*)d_in[2];
    const float* w2_w = (const float*)d_in[3];
    const float* w2_b = (const float*)d_in[4];
    const float* vals = (const float*)d_in[5];
    const int* rows = (const int*)d_in[6];
    const int* cols = (const int*)d_in[7];
    const int* user = (const int*)d_in[8];
    const int* pos  = (const int*)d_in[9];
    const int* neg  = (const int*)d_in[10];
    float* out = (float*)d_out;

    char* w = (char*)d_ws;
    // 11.64 MB staging region, aliased with fp16 agg (6.4 MB)
    char* region = w;          w += (size_t)NBUCK * CAP_S * 8;
    ushort* aggh = (ushort*)region;
    int2* staging = (int2*)region;
    int* row_ptr = (int*)w;   w += (((size_t)(N_NODES + 1) * 4) + 255) / 256 * 256;
    uint32* csr  = (uint32*)w; w += (size_t)EDGES * 4;
    int* gcur    = (int*)w;   w += 256 * 4;
    float* dots  = (float*)w; w += (size_t)3 * BATCH * 4;
    char* xqA    = (char*)w;  w += (size_t)N_NODES * DIM;
    char* xqB    = (char*)w;  w += (size_t)N_NODES * DIM;
    float* xscA  = (float*)w; w += (size_t)N_NODES * 4;
    float* xscB  = (float*)w; w += (size_t)N_NODES * 4;
    ushort* aggh_slot = (ushort*)w; w += (size_t)NSLOTS * DIM * 2;
    char* yq_slot     = (char*)w;   w += (size_t)NSLOTS * DIM;
    float* ysc_slot   = (float*)w;  w += (size_t)NSLOTS * 4;

    hipMemsetAsync(gcur, 0, 256 * 4, stream);

    scatterprep_kernel<<<SP_TOTAL, 256, 0, stream>>>(rows, cols, vals, gcur, staging,
                                                     emb, xqA, xscA,
                                                     user, pos, neg, dots, out);
    csr_build_kernel<<<NBUCK, 512, 0, stream>>>(gcur, staging, row_ptr, csr);

    const int NSB = N_NODES / 4;          // 12500
    const int NTB = BATCH / 4;            // 1024
    const int NDB = (N_NODES + 63) / 64;  // 782
    const int NSLB = NSLOTS / 4;          // 3072
    const int NSDB = NSLOTS / 64;         // 192

    // layer 0: full spmm on xqA (emb mirror); dense -> xqB
    spmm_kernel<<<NSB, 256, 0, stream>>>(row_ptr, csr, xqA, xscA, aggh,
                                         user, pos, neg, dots, NSB);
    dense_kernel<<<NDB, 256, 0, stream>>>(xqA, xscA, aggh,
                                          w1_w + 0 * 4096, w2_w + 0 * 4096,
                                          w1_b + 0 * DIM, w2_b + 0 * DIM, xqB, xscB);
    // layer 1: full spmm on xqB (+ dots1 tail); dense -> xqA
    spmm_kernel<<<NSB + NTB, 256, 0, stream>>>(row_ptr, csr, xqB, xscB, aggh,
                                               user, pos, neg, dots + BATCH, NSB);
    dense_kernel<<<NDB, 256, 0, stream>>>(xqB, xscB, aggh,
                                          w1_w + 1 * 4096, w2_w + 1 * 4096,
                                          w1_b + 1 * DIM, w2_b + 1 * DIM, xqA, xscA);
    // layer 2 (slots only): spmm_slots on xqA (+ dots2 tail); dense_slots -> yq_slot
    spmm_slots_kernel<<<NSLB + NTB, 256, 0, stream>>>(row_ptr, csr, xqA, xscA, aggh_slot,
                                                      user, pos, neg, dots + 2 * BATCH, NSLB);
    dense_slots_kernel<<<NSDB, 256, 0, stream>>>(xqA, xscA, aggh_slot,
                                                 w1_w + 2 * 4096, w2_w + 2 * 4096,
                                                 w1_b + 2 * DIM, w2_b + 2 * DIM,
                                                 yq_slot, ysc_slot, user, pos, neg);

    dots_loss_kernel<<<NTB, 256, 0, stream>>>(yq_slot, ysc_slot, dots, out);
}